// Round 4
// baseline (2397.822 us; speedup 1.0000x reference)
//
#include <hip/hip_runtime.h>

#define B_ 8
#define H_ 8
#define DM 512
#define DH 64
#define LMAX 2048
#define COUT 2

typedef __attribute__((ext_vector_type(8))) short frag8;
typedef __attribute__((ext_vector_type(4))) float f32x4;

typedef __attribute__((address_space(1))) const unsigned int guint;
typedef __attribute__((address_space(3))) unsigned int luint;
__device__ __forceinline__ void dma16(const short* g, short* l) {
  __builtin_amdgcn_global_load_lds((guint*)g, (luint*)l, 16, 0, 0);
}

__device__ __forceinline__ short f2bf(float v) {
  unsigned u = __float_as_uint(v);
  unsigned r = (u + 0x7fffu + ((u >> 16) & 1u)) >> 16;   // RNE
  return (short)r;
}
__device__ __forceinline__ float bf2f(short s) {
  return __uint_as_float(((unsigned)(unsigned short)s) << 16);
}
// bf16x3 split of one f32 value — identical chain to wsplit (bitwise-same planes)
__device__ __forceinline__ void split3(float v, short* p0, short* p1, short* p2, size_t i) {
  short h0 = f2bf(v);
  float r1 = v - bf2f(h0);
  short h1 = f2bf(r1);
  float r2 = r1 - bf2f(h1);
  p0[i] = h0; p1[i] = h1; p2[i] = f2bf(r2);
}

// ---------------- JAX threefry2x32 ----------------
__device__ __forceinline__ void tf2x32(unsigned k0, unsigned k1, unsigned x0, unsigned x1,
                                       unsigned& o0, unsigned& o1) {
  unsigned ks2 = k0 ^ k1 ^ 0x1BD11BDAu;
  x0 += k0; x1 += k1;
#define RND(r) { x0 += x1; x1 = (x1 << r) | (x1 >> (32 - r)); x1 ^= x0; }
  RND(13) RND(15) RND(26) RND(6)  x0 += k1;  x1 += ks2 + 1u;
  RND(17) RND(29) RND(16) RND(24) x0 += ks2; x1 += k0 + 2u;
  RND(13) RND(15) RND(26) RND(6)  x0 += k0;  x1 += k1 + 3u;
  RND(17) RND(29) RND(16) RND(24) x0 += k1;  x1 += ks2 + 4u;
  RND(13) RND(15) RND(26) RND(6)  x0 += ks2; x1 += k0 + 5u;
#undef RND
  o0 = x0; o1 = x1;
}

// VERIFIED (R7, absmax 0.0): Variant B partitionable. DO NOT TOUCH.
__global__ void idx_kernel(int* __restrict__ idxArr, int L, int U, int layer) {
  int p = blockIdx.x * 256 + threadIdx.x;
  int half = L * U;
  if (p >= half) return;
  unsigned fk0, fk1, k20, k21, o0, o1;
  tf2x32(0u, 42u, 0u, (unsigned)layer, fk0, fk1);
  tf2x32(fk0, fk1, 0u, 1u, k20, k21);
  tf2x32(k20, k21, 0u, (unsigned)p, o0, o1);
  idxArr[p] = (int)((o0 ^ o1) & (unsigned)(L - 1));
}

// ---------------- token embed + positional encoding (+fused X-plane split) ----------------
__global__ void embed_kernel(const float* __restrict__ xe, const float* __restrict__ tw,
                             float* __restrict__ X, short* __restrict__ P0,
                             short* __restrict__ P1, short* __restrict__ P2) {
  int i = blockIdx.x * 256 + threadIdx.x;
  int c = i % DM;
  int l = (i / DM) % LMAX;
  int b = i / (DM * LMAX);
  int lm = (l + LMAX - 1) & (LMAX - 1);
  int lp = (l + 1) & (LMAX - 1);
  const float* xb = xe + b * LMAX;
  float tok = tw[c * 3 + 0] * xb[lm] + tw[c * 3 + 1] * xb[l] + tw[c * 3 + 2] * xb[lp];
  float freq = expf(-(float)(c & ~1) * (9.210340371976184f / 512.0f));
  float ang = (float)l * freq;
  float pe = (c & 1) ? cosf(ang) : sinf(ang);
  float v = tok + pe;
  X[i] = v;
  split3(v, P0, P1, P2, (size_t)i);
}

// ---------------- split f32 -> 3 bf16 planes (weights + FF1 activations) ----------------
__global__ void wsplit_kernel(const float* __restrict__ W, short* __restrict__ P0,
                              short* __restrict__ P1, short* __restrict__ P2, int n) {
  int i = blockIdx.x * 256 + threadIdx.x;
  if (i >= n) return;
  split3(W[i], P0, P1, P2, (size_t)i);
}

// conv weight transpose + split: Pt[n][tap*512+k] = split(w[n][k][tap])
__global__ void wt3_kernel(const float* __restrict__ w, short* __restrict__ P0,
                           short* __restrict__ P1, short* __restrict__ P2) {
  int i = blockIdx.x * 256 + threadIdx.x;   // 512*1536
  int n = i / 1536, r = i - n * 1536, tap = r >> 9, k = r & 511;
  float v = w[((size_t)n * DM + k) * 3 + tap];
  split3(v, P0, P1, P2, (size_t)i);
}

// ---------------- bf16x3-split MFMA GEMM, DMA staging (m97-style) ----------------
// BM=BN=128, BK=32, 4 waves (2x2 of 64x64). A AND B staged from pre-split bf16
// planes via global_load_lds width=16 (48 x 1KB chunks/iter). 6 of 9 products.
template <int ACT, int QKV, int ACC, int CONV>
__global__ __launch_bounds__(256) void mgemm(const short* __restrict__ A0g,
                                             const short* __restrict__ A1g,
                                             const short* __restrict__ A2g,
                                             const short* __restrict__ W0g,
                                             const short* __restrict__ W1g,
                                             const short* __restrict__ W2g,
                                             const float* __restrict__ bias,
                                             float* __restrict__ C, int L, int Ktot) {
  __shared__ short A0[128 * 32], A1[128 * 32], A2[128 * 32];
  __shared__ short B0[128 * 32], B1[128 * 32], B2[128 * 32];
  int tid = threadIdx.x;
  int lane = tid & 63, wave = tid >> 6;
  int crow = lane >> 2, ckq = lane & 3;     // DMA: 16 rows x 4 k-groups per chunk
  // XCD-aware swizzle: each XCD gets one m-row phase, iterating n fastest.
  int gx = gridDim.x;
  int flat = blockIdx.y * gx + blockIdx.x;
  int mB, nB;
  if ((gridDim.y & 7) == 0) {
    int phase = flat & 7, sup = flat >> 3;
    nB = sup % gx;
    mB = phase + 8 * (sup / gx);
  } else {
    nB = blockIdx.x; mB = blockIdx.y;
  }
  int n0 = nB * 128, m0 = mB * 128;
  int wm = (wave >> 1) * 64, wn = (wave & 1) * 64;
  f32x4 acc[4][4] = {};
  int lrow = lane & 15, lq = lane >> 4;

  for (int k0 = 0; k0 < Ktot; k0 += 32) {
    int tap = 0, kcol = k0;
    if (CONV) { tap = k0 >> 9; kcol = k0 & 511; }
#pragma unroll
    for (int q = 0; q < 6; ++q) {
      int gc = wave * 6 + q;               // 0..23
      int pl = gc >> 3, c = gc & 7;
      int grow = m0 + c * 16 + crow;
      const short* gp;
      if (CONV) {
        int b = grow / L, l = grow - b * L;
        int le = l + tap - 1;
        le = (le < 0) ? le + L : (le >= L ? le - L : le);
        gp = ((size_t)(b * L + le) * DM + kcol + ckq * 8) +
             (pl == 0 ? A0g : pl == 1 ? A1g : A2g);
      } else {
        gp = ((size_t)grow * DM + k0 + ckq * 8) +
             (pl == 0 ? A0g : pl == 1 ? A1g : A2g);
      }
      short* lp = (pl == 0 ? A0 : pl == 1 ? A1 : A2) + c * 512;
      dma16(gp, lp);
    }
#pragma unroll
    for (int q = 0; q < 6; ++q) {
      int gc = wave * 6 + q;
      int pl = gc >> 3, c = gc & 7;
      int grow = n0 + c * 16 + crow;
      const short* gp = ((size_t)grow * Ktot + k0 + ckq * 8) +
                        (pl == 0 ? W0g : pl == 1 ? W1g : W2g);
      short* lp = (pl == 0 ? B0 : pl == 1 ? B1 : B2) + c * 512;
      dma16(gp, lp);
    }
    __syncthreads();
    frag8 a0f[4], a1f[4], a2f[4];
#pragma unroll
    for (int ti = 0; ti < 4; ++ti) {
      int off = (wm + ti * 16 + lrow) * 32 + lq * 8;
      a0f[ti] = *(const frag8*)&A0[off];
      a1f[ti] = *(const frag8*)&A1[off];
      a2f[ti] = *(const frag8*)&A2[off];
    }
#pragma unroll
    for (int tj = 0; tj < 4; ++tj) {
      int off = (wn + tj * 16 + lrow) * 32 + lq * 8;
      frag8 b0 = *(const frag8*)&B0[off];
      frag8 b1 = *(const frag8*)&B1[off];
      frag8 b2 = *(const frag8*)&B2[off];
#pragma unroll
      for (int ti = 0; ti < 4; ++ti) {
        f32x4 ac = acc[ti][tj];
        ac = __builtin_amdgcn_mfma_f32_16x16x32_bf16(a1f[ti], b1, ac, 0, 0, 0);
        ac = __builtin_amdgcn_mfma_f32_16x16x32_bf16(a0f[ti], b2, ac, 0, 0, 0);
        ac = __builtin_amdgcn_mfma_f32_16x16x32_bf16(a2f[ti], b0, ac, 0, 0, 0);
        ac = __builtin_amdgcn_mfma_f32_16x16x32_bf16(a0f[ti], b1, ac, 0, 0, 0);
        ac = __builtin_amdgcn_mfma_f32_16x16x32_bf16(a1f[ti], b0, ac, 0, 0, 0);
        ac = __builtin_amdgcn_mfma_f32_16x16x32_bf16(a0f[ti], b0, ac, 0, 0, 0);
        acc[ti][tj] = ac;
      }
    }
    __syncthreads();
  }
  // epilogue: C/D map col=lane&15, row=(lane>>4)*4+reg
#pragma unroll
  for (int ti = 0; ti < 4; ++ti) {
#pragma unroll
    for (int tj = 0; tj < 4; ++tj) {
#pragma unroll
      for (int r = 0; r < 4; ++r) {
        int row = m0 + wm + ti * 16 + lq * 4 + r;
        int col = n0 + wn + tj * 16 + lrow;
        float v = acc[ti][tj][r];
        if (!CONV) v += bias[col];
        if (ACT) v = 0.5f * v * (1.0f + erff(v * 0.70710678118654752f));
        if (QKV) {
          int b = row / L, l = row - b * L;
          int h = col >> 6, d = col & 63;
          C[(((size_t)b * H_ + h) * L + l) * DH + d] = v;
        } else if (ACC) {
          C[(size_t)row * DM + col] += v;
        } else {
          C[(size_t)row * DM + col] = v;
        }
      }
    }
  }
}

// ---------------- conv epilogue: BN + ELU ----------------
__global__ void bnelu_kernel(float* __restrict__ Y, const float* __restrict__ cb,
                             const float* __restrict__ g, const float* __restrict__ be) {
  int i = blockIdx.x * 256 + threadIdx.x;
  int c = i % DM;
  const float invs = 0.9999950000374997f;  // 1/sqrt(1+1e-5)
  float z = Y[i] + cb[c];
  z = z * invs * g[c] + be[c];
  Y[i] = z > 0.f ? z : expm1f(z);
}

// ---------------- qkM: lane=(dchunk,sample), 3 shuffles per 8-sample pass ----------------
// R4: at structural roofline. R1-R3 probes (C prefetch / asm-in-loop / single
// asm batch) all measured EXACTLY 164µs — time is invariant to per-wave load
// scheduling => bound by divergent-VMEM lane-issue (10 gather instrs x 64
// lane-slots/CU-cycle = 136µs floor + overhead = 164µs). Reverted to clean R0.
template <int U>
__global__ void qkM_t(const float* __restrict__ Q, const float* __restrict__ Kd,
                      const int* __restrict__ idxArr, float* __restrict__ Mout, int L) {
  int lane = threadIdx.x & 63, wv = threadIdx.x >> 6;
  int row = blockIdx.x * 4 + wv;
  int l = row % L, bh = row / L;
  int u = lane & 7, dc = lane >> 3;       // sample slot, d-chunk
  const float* Qb = Q + ((size_t)bh * L + l) * DH + dc * 8;
  float4 q0 = *(const float4*)(Qb);
  float4 q1 = *(const float4*)(Qb + 4);
  const float* Kb = Kd + (size_t)bh * L * DH;
  const int* ip = idxArr + l * U;
  const int NP = (U + 7) / 8;
  float mx = -1e30f, sm = 0.f;
#pragma unroll
  for (int p = 0; p < NP; ++p) {
    int s = p * 8 + u;
    bool valid = (s < U);
    int ki = ip[valid ? s : 0];
    const float* kr = Kb + (size_t)ki * DH + dc * 8;
    float4 k0 = *(const float4*)(kr);
    float4 k1 = *(const float4*)(kr + 4);
    float d = q0.x * k0.x + q0.y * k0.y + q0.z * k0.z + q0.w * k0.w +
              q1.x * k1.x + q1.y * k1.y + q1.z * k1.z + q1.w * k1.w;
    d += __shfl_xor(d, 8, 64);
    d += __shfl_xor(d, 16, 64);
    d += __shfl_xor(d, 32, 64);
    if (valid) { mx = fmaxf(mx, d); sm += d; }
  }
#pragma unroll
  for (int o = 1; o <= 4; o <<= 1) {
    mx = fmaxf(mx, __shfl_xor(mx, o, 64));
    sm += __shfl_xor(sm, o, 64);
  }
  if (lane == 0) Mout[row] = mx - sm / (float)U;
}

// ---------------- top-U per bh ----------------
__global__ void topk_kernel(const float* __restrict__ M, int* __restrict__ top, int L, int U) {
  __shared__ float vals[LMAX];
  __shared__ float rv[256];
  __shared__ int ri[256];
  int bh = blockIdx.x, tid = threadIdx.x;
  for (int j = tid; j < L; j += 256) vals[j] = M[(size_t)bh * L + j];
  __syncthreads();
  for (int u = 0; u < U; ++u) {
    float bv = -1e30f; int bi = L;
    for (int j = tid; j < L; j += 256) {
      float v = vals[j];
      if (v > bv) { bv = v; bi = j; }
    }
    rv[tid] = bv; ri[tid] = bi;
    __syncthreads();
    for (int s = 128; s >= 1; s >>= 1) {
      if (tid < s) {
        float ov = rv[tid + s]; int oi = ri[tid + s];
        if (ov > rv[tid] || (ov == rv[tid] && oi < ri[tid])) { rv[tid] = ov; ri[tid] = oi; }
      }
      __syncthreads();
    }
    if (tid == 0) { top[bh * U + u] = ri[0]; vals[ri[0]] = -1e30f; }
    __syncthreads();
  }
}

// ---------------- v mean over L per (bh,d) ----------------
__global__ void vmean_kernel(const float* __restrict__ V, float* __restrict__ VM, int L) {
  __shared__ float red[256];
  int bh = blockIdx.x, tid = threadIdx.x, d = tid & 63, sq = tid >> 6;
  float s = 0.f;
  for (int l = sq; l < L; l += 4) s += V[((size_t)bh * L + l) * DH + d];
  red[tid] = s;
  __syncthreads();
  if (sq == 0) VM[bh * DH + d] = (red[d] + red[d + 64] + red[d + 128] + red[d + 192]) / (float)L;
}

// ---------------- fill ctx planes with v-mean (fused split; f32 T no longer written) --------
__global__ void fill_kernel(const float* __restrict__ VM, short* __restrict__ P0,
                            short* __restrict__ P1, short* __restrict__ P2, int L) {
  size_t i = (size_t)blockIdx.x * 256 + threadIdx.x;
  int c = (int)(i % DM);
  int b = (int)(i / ((size_t)L * DM));
  split3(VM[b * DM + c], P0, P1, P2, i);
}

// ---------------- flash-style attention for selected queries ----------------
// R4: 16 queries/block (2 sequential 8-query sub-rounds per staged K/V tile)
// -> K/V staging traffic cut 5/3 (nch 5->3). Per-query tile order and
// expressions identical to the 8-query version -> bitwise identical.
// Epilogue writes bf16x3 planes directly (fused wsplit; same f32 value).
__global__ __launch_bounds__(256) void attn_fused(const float* __restrict__ Q,
                                                  const float* __restrict__ Kd,
                                                  const float* __restrict__ V,
                                                  const int* __restrict__ top,
                                                  short* __restrict__ OP0,
                                                  short* __restrict__ OP1,
                                                  short* __restrict__ OP2,
                                                  int L, int U) {
  __shared__ float Qs[16][64];
  __shared__ float Kt[64][65];
  __shared__ float Vs[64][68];
  __shared__ float ps[8][64];
  __shared__ int lst[16];
  int nch = (U + 15) >> 4;
  int bh = blockIdx.x / nch, ch = blockIdx.x - bh * nch;
  int u0g = ch * 16;
  int qn = U - u0g; if (qn > 16) qn = 16;
  int tid = threadIdx.x, lane = tid & 63, wv = tid >> 6;
  if (tid < qn) lst[tid] = top[bh * U + u0g + tid];
  __syncthreads();
  for (int idx = tid; idx < qn * 64; idx += 256) {
    int u = idx >> 6, d = idx & 63;
    Qs[u][d] = Q[((size_t)bh * L + lst[u]) * DH + d];
  }
  __syncthreads();
  int ua = wv, ub = wv + 4;
  bool hA0 = (ua < qn), hB0 = (ub < qn);
  bool hA1 = (8 + ua < qn), hB1 = (8 + ub < qn);
  float m0a = -1e30f, l0a = 0.f, o0a = 0.f;
  float m0b = -1e30f, l0b = 0.f, o0b = 0.f;
  float m1a = -1e30f, l1a = 0.f, o1a = 0.f;
  float m1b = -1e30f, l1b = 0.f, o1b = 0.f;
  const float* Kbase = Kd + (size_t)bh * L * DH;
  const float* Vbase = V + (size_t)bh * L * DH;
  for (int t0 = 0; t0 < L; t0 += 64) {
#pragma unroll
    for (int it = 0; it < 4; ++it) {
      int idx = tid + it * 256;
      int j = idx >> 4, d4 = (idx & 15) * 4;
      float4 kv = *(const float4*)(Kbase + (size_t)(t0 + j) * DH + d4);
      Kt[d4 + 0][j] = kv.x; Kt[d4 + 1][j] = kv.y;
      Kt[d4 + 2][j] = kv.z; Kt[d4 + 3][j] = kv.w;
      *(float4*)&Vs[j][d4] = *(const float4*)(Vbase + (size_t)(t0 + j) * DH + d4);
    }
    __syncthreads();
#define SUBSTEP(QA, QB, mA, lA, oA, mB, lB, oB, HA, HB)                        \
    {                                                                          \
      float s0 = 0.f, s1 = 0.f;                                                \
      _Pragma("unroll 16")                                                     \
      for (int d = 0; d < 64; ++d) {                                           \
        float kd = Kt[d][lane];                                                \
        s0 += kd * Qs[QA][d];                                                  \
        s1 += kd * Qs[QB][d];                                                  \
      }                                                                        \
      s0 *= 0.125f; s1 *= 0.125f;                                              \
      if (HA) {                                                                \
        float tm = s0;                                                         \
        _Pragma("unroll")                                                      \
        for (int o = 32; o >= 1; o >>= 1) tm = fmaxf(tm, __shfl_xor(tm, o, 64)); \
        float nm = fmaxf(mA, tm);                                              \
        float alpha = expf(mA - nm);                                           \
        float p = expf(s0 - nm);                                               \
        float tsum = p;                                                        \
        _Pragma("unroll")                                                      \
        for (int o = 32; o >= 1; o >>= 1) tsum += __shfl_xor(tsum, o, 64);     \
        lA = lA * alpha + tsum;                                                \
        mA = nm;                                                               \
        ps[ua][lane] = p;                                                      \
        oA *= alpha;                                                           \
      }                                                                        \
      if (HB) {                                                                \
        float tm = s1;                                                         \
        _Pragma("unroll")                                                      \
        for (int o = 32; o >= 1; o >>= 1) tm = fmaxf(tm, __shfl_xor(tm, o, 64)); \
        float nm = fmaxf(mB, tm);                                              \
        float alpha = expf(mB - nm);                                           \
        float p = expf(s1 - nm);                                               \
        float tsum = p;                                                        \
        _Pragma("unroll")                                                      \
        for (int o = 32; o >= 1; o >>= 1) tsum += __shfl_xor(tsum, o, 64);     \
        lB = lB * alpha + tsum;                                                \
        mB = nm;                                                               \
        ps[ub][lane] = p;                                                      \
        oB *= alpha;                                                           \
      }                                                                        \
      if (HA) {                                                                \
        _Pragma("unroll 16")                                                   \
        for (int j = 0; j < 64; ++j) oA += ps[ua][j] * Vs[j][lane];            \
      }                                                                        \
      if (HB) {                                                                \
        _Pragma("unroll 16")                                                   \
        for (int j = 0; j < 64; ++j) oB += ps[ub][j] * Vs[j][lane];            \
      }                                                                        \
    }
    SUBSTEP(ua, ub, m0a, l0a, o0a, m0b, l0b, o0b, hA0, hB0)
    SUBSTEP(8 + ua, 8 + ub, m1a, l1a, o1a, m1b, l1b, o1b, hA1, hB1)
#undef SUBSTEP
    __syncthreads();
  }
  int b = bh / H_, h = bh - b * H_;
  if (hA0) {
    size_t i = ((size_t)b * L + lst[ua]) * DM + h * DH + lane;
    split3(o0a / l0a, OP0, OP1, OP2, i);
  }
  if (hB0) {
    size_t i = ((size_t)b * L + lst[ub]) * DM + h * DH + lane;
    split3(o0b / l0b, OP0, OP1, OP2, i);
  }
  if (hA1) {
    size_t i = ((size_t)b * L + lst[8 + ua]) * DM + h * DH + lane;
    split3(o1a / l1a, OP0, OP1, OP2, i);
  }
  if (hB1) {
    size_t i = ((size_t)b * L + lst[8 + ub]) * DM + h * DH + lane;
    split3(o1b / l1b, OP0, OP1, OP2, i);
  }
}

// ---------------- x = LayerNorm(x) in place (+optional fused plane split) ----------------
__global__ void ln_kernel(float* __restrict__ X, const float* __restrict__ g,
                          const float* __restrict__ be, short* __restrict__ P0,
                          short* __restrict__ P1, short* __restrict__ P2) {
  __shared__ float red[256];
  int row = blockIdx.x, tid = threadIdx.x;
  size_t base = (size_t)row * DM;
  float t0 = X[base + tid];
  float t1 = X[base + tid + 256];
  red[tid] = t0 + t1;
  __syncthreads();
  for (int s = 128; s >= 1; s >>= 1) { if (tid < s) red[tid] += red[tid + s]; __syncthreads(); }
  float mu = red[0] / 512.0f;
  __syncthreads();
  float d0 = t0 - mu, d1 = t1 - mu;
  red[tid] = d0 * d0 + d1 * d1;
  __syncthreads();
  for (int s = 128; s >= 1; s >>= 1) { if (tid < s) red[tid] += red[tid + s]; __syncthreads(); }
  float rstd = 1.0f / sqrtf(red[0] / 512.0f + 1e-5f);
  float v0 = d0 * rstd * g[tid] + be[tid];
  float v1 = d1 * rstd * g[tid + 256] + be[tid + 256];
  X[base + tid] = v0;
  X[base + tid + 256] = v1;
  if (P0) {
    split3(v0, P0, P1, P2, base + tid);
    split3(v1, P0, P1, P2, base + tid + 256);
  }
}

// ---------------- maxpool k=3 s=2 pad=1 along L (+fused plane split) ----------------
__global__ void pool_kernel(const float* __restrict__ Y, float* __restrict__ X, int L2,
                            short* __restrict__ P0, short* __restrict__ P1,
                            short* __restrict__ P2) {
  int i = blockIdx.x * 256 + threadIdx.x;
  int c = i % DM;
  int t = (i / DM) % L2;
  int b = i / (DM * L2);
  int L = L2 * 2;
  const float* yb = Y + (size_t)b * L * DM + c;
  float m = fmaxf(yb[(size_t)(2 * t) * DM], yb[(size_t)(2 * t + 1) * DM]);
  if (t > 0) m = fmaxf(m, yb[(size_t)(2 * t - 1) * DM]);
  X[i] = m;
  split3(m, P0, P1, P2, (size_t)i);
}

// ---------------- column max, 2-stage ----------------
__global__ void colmax1_kernel(const float* __restrict__ X, float* __restrict__ P, int L) {
  int nlc = L >> 6;
  int bl = blockIdx.x;
  int b = bl / nlc, lc = bl % nlc;
  const float* xb = X + ((size_t)b * L + lc * 64) * DM;
  for (int c = threadIdx.x; c < DM; c += 256) {
    float m = -1e30f;
    for (int r = 0; r < 64; ++r) m = fmaxf(m, xb[(size_t)r * DM + c]);
    P[((size_t)b * nlc + lc) * DM + c] = m;
  }
}
__global__ void colmax2_kernel(const float* __restrict__ P, float* __restrict__ mc, int nlc) {
  int i = blockIdx.x * 256 + threadIdx.x;
  int b = i / DM, c = i % DM;
  float m = -1e30f;
  for (int lc = 0; lc < nlc; ++lc) m = fmaxf(m, P[((size_t)b * nlc + lc) * DM + c]);
  mc[i] = m;
}

// ---------------- final projection ----------------
__global__ void proj_kernel(const float* __restrict__ mc, const float* __restrict__ pw,
                            const float* __restrict__ pb, float* __restrict__ out) {
  __shared__ float red[256];
  int bo = blockIdx.x, b = bo / COUT, o = bo % COUT, tid = threadIdx.x;
  float s = mc[b * DM + tid] * pw[o * DM + tid] +
            mc[b * DM + tid + 256] * pw[o * DM + tid + 256];
  red[tid] = s;
  __syncthreads();
  for (int st = 128; st >= 1; st >>= 1) { if (tid < st) red[tid] += red[tid + st]; __syncthreads(); }
  if (tid == 0) out[bo] = red[0] + pb[o];
}

extern "C" void kernel_launch(void* const* d_in, const int* in_sizes, int n_in,
                              void* d_out, int out_size, void* d_ws, size_t ws_size,
                              hipStream_t stream) {
  (void)in_sizes; (void)n_in; (void)out_size;
  const float* xe   = (const float*)d_in[0];
  const float* tw   = (const float*)d_in[1];
  const float* Wq   = (const float*)d_in[2];
  const float* Wk   = (const float*)d_in[3];
  const float* Wv   = (const float*)d_in[4];
  const float* Wo   = (const float*)d_in[5];
  const float* bq   = (const float*)d_in[6];
  const float* bk   = (const float*)d_in[7];
  const float* bv   = (const float*)d_in[8];
  const float* bo   = (const float*)d_in[9];
  const float* W1   = (const float*)d_in[10];
  const float* b1   = (const float*)d_in[11];
  const float* W2   = (const float*)d_in[12];
  const float* b2   = (const float*)d_in[13];
  const float* ln1g = (const float*)d_in[14];
  const float* ln1b = (const float*)d_in[15];
  const float* ln2g = (const float*)d_in[16];
  const float* ln2b = (const float*)d_in[17];
  const float* dcw  = (const float*)d_in[18];
  const float* dcb  = (const float*)d_in[19];
  const float* bng  = (const float*)d_in[20];
  const float* bnb  = (const float*)d_in[21];
  const float* lnfg = (const float*)d_in[22];
  const float* lnfb = (const float*)d_in[23];
  const float* pw   = (const float*)d_in[24];
  const float* pb   = (const float*)d_in[25];
  float* out = (float*)d_out;

  float* Wf = (float*)d_ws;
  const size_t NB  = (size_t)B_ * LMAX * DM;             // 8,388,608 floats
  const size_t NHB = (size_t)H_ * LMAX * DH;             // 1,048,576 floats
  const size_t S_IDX = 81920, S_MV = 131072, S_TOP = 4096, S_VM = 4096,
               S_MC = 4096, S_P = 32768;
  const size_t PLANE  = (size_t)512 * 1536;              // weight plane (shorts)
  const size_t APLANE = NB;                              // activation plane (shorts)
  const size_t S_WP = 3 * PLANE / 2 + 1024;              // floats
  const size_t S_AP = 3 * APLANE / 2 + 1024;             // floats
  const size_t SMALL = S_IDX + S_MV + S_TOP + S_VM + S_MC + S_P + S_WP + S_AP + 1024;

  int g = 8;
  while (g > 1 && (2 * NB + 3 * (size_t)g * NHB + SMALL) * 4 > ws_size) g >>= 1;

  float* X  = Wf;
  float* T  = X + NB;
  float* Q  = T + NB;
  float* K  = Q + (size_t)g * NHB;
  float* V  = K + (size_t)g * NHB;
  float* SM = V + (size_t)g * NHB;
  int*   IDX = (int*)SM;
  float* Mv  = SM + S_IDX;
  int*   TOP = (int*)(Mv + S_MV);
  float* VM  = Mv + S_MV + S_TOP;
  float* MC  = VM + S_VM;
  float* P   = MC + S_MC;
  short* WP0 = (short*)(P + S_P);
  short* WP1 = WP0 + PLANE;
  short* WP2 = WP1 + PLANE;
  short* AP0 = (short*)((float*)(P + S_P) + S_WP);
  short* AP1 = AP0 + APLANE;
  short* AP2 = AP1 + APLANE;

  // embed writes X f32 + X-planes (fused split for layer-0 QKV inputs)
  embed_kernel<<<B_ * LMAX * DM / 256, 256, 0, stream>>>(xe, tw, X, AP0, AP1, AP2);

  int L = LMAX;
  for (int i = 0; i < 3; ++i) {
    int U = (i == 0) ? 40 : 35;
    size_t wOff = (size_t)i * DM * DM;
    int ng = B_ / g;
    int nch = (U + 15) >> 4;
    const int NW = DM * DM;

    idx_kernel<<<(L * U + 255) / 256, 256, 0, stream>>>(IDX, L, U, i);

    for (int gb = 0; gb < ng; ++gb) {
      size_t aoff = (size_t)gb * g * L * DM;
      int Mg = g * L * DM;
      (void)Mg;
      dim3 gq(DM / 128, g * L / 128);
      // A-planes of X already present (embed/pool fused split)
      wsplit_kernel<<<NW / 256, 256, 0, stream>>>(Wq + wOff, WP0, WP1, WP2, NW);
      mgemm<0, 1, 0, 0><<<gq, 256, 0, stream>>>(AP0 + aoff, AP1 + aoff, AP2 + aoff,
                                                WP0, WP1, WP2, bq + i * DM, Q, L, DM);
      wsplit_kernel<<<NW / 256, 256, 0, stream>>>(Wk + wOff, WP0, WP1, WP2, NW);
      mgemm<0, 1, 0, 0><<<gq, 256, 0, stream>>>(AP0 + aoff, AP1 + aoff, AP2 + aoff,
                                                WP0, WP1, WP2, bk + i * DM, K, L, DM);
      wsplit_kernel<<<NW / 256, 256, 0, stream>>>(Wv + wOff, WP0, WP1, WP2, NW);
      mgemm<0, 1, 0, 0><<<gq, 256, 0, stream>>>(AP0 + aoff, AP1 + aoff, AP2 + aoff,
                                                WP0, WP1, WP2, bv + i * DM, V, L, DM);
      if (U == 40) qkM_t<40><<<g * H_ * L / 4, 256, 0, stream>>>(Q, K, IDX, Mv, L);
      else         qkM_t<35><<<g * H_ * L / 4, 256, 0, stream>>>(Q, K, IDX, Mv, L);
      topk_kernel<<<g * H_, 256, 0, stream>>>(Mv, TOP, L, U);
      vmean_kernel<<<g * H_, 256, 0, stream>>>(V, VM, L);
      // ctx planes: fill with v-mean splits, attn overwrites selected rows
      fill_kernel<<<(unsigned)((size_t)g * L * DM / 256), 256, 0, stream>>>(
          VM, AP0 + aoff, AP1 + aoff, AP2 + aoff, L);
      attn_fused<<<g * H_ * nch, 256, 0, stream>>>(Q, K, V, TOP, AP0 + aoff,
                                                   AP1 + aoff, AP2 + aoff, L, U);
    }

    int Mf = B_ * L * DM;
    dim3 gf(DM / 128, B_ * L / 128);
    // Wo: A = ctx planes (fill/attn fused split)
    wsplit_kernel<<<NW / 256, 256, 0, stream>>>(Wo + wOff, WP0, WP1, WP2, NW);
    mgemm<0, 0, 1, 0><<<gf, 256, 0, stream>>>(AP0, AP1, AP2, WP0, WP1, WP2,
                                              bo + i * DM, X, L, DM);
    // ln1 fused: writes X + X-planes for FF1
    ln_kernel<<<B_ * L, 256, 0, stream>>>(X, ln1g + i * DM, ln1b + i * DM, AP0, AP1, AP2);
    wsplit_kernel<<<NW / 256, 256, 0, stream>>>(W1 + wOff, WP0, WP1, WP2, NW);
    mgemm<1, 0, 0, 0><<<gf, 256, 0, stream>>>(AP0, AP1, AP2, WP0, WP1, WP2,
                                              b1 + i * DM, T, L, DM);
    // split gelu output (can't fuse: reads+writes same plane buffers)
    wsplit_kernel<<<Mf / 256, 256, 0, stream>>>(T, AP0, AP1, AP2, Mf);
    wsplit_kernel<<<NW / 256, 256, 0, stream>>>(W2 + wOff, WP0, WP1, WP2, NW);
    mgemm<0, 0, 1, 0><<<gf, 256, 0, stream>>>(AP0, AP1, AP2, WP0, WP1, WP2,
                                              b2 + i * DM, X, L, DM);
    // ln2 fused: planes only needed when a conv layer follows
    if (i < 2) {
      ln_kernel<<<B_ * L, 256, 0, stream>>>(X, ln2g + i * DM, ln2b + i * DM, AP0, AP1, AP2);
      wt3_kernel<<<DM * 1536 / 256, 256, 0, stream>>>(dcw + (size_t)i * DM * DM * 3,
                                                      WP0, WP1, WP2);
      mgemm<0, 0, 0, 1><<<gf, 256, 0, stream>>>(AP0, AP1, AP2, WP0, WP1, WP2,
                                                nullptr, T, L, 1536);
      bnelu_kernel<<<B_ * L * DM / 256, 256, 0, stream>>>(T, dcb + i * DM, bng + i * DM,
                                                          bnb + i * DM);
      L >>= 1;
      // pool fused: writes X + X-planes for next layer's QKV
      pool_kernel<<<B_ * L * DM / 256, 256, 0, stream>>>(T, X, L, AP0, AP1, AP2);
    } else {
      ln_kernel<<<B_ * L, 256, 0, stream>>>(X, ln2g + i * DM, ln2b + i * DM,
                                            nullptr, nullptr, nullptr);
    }
  }

  ln_kernel<<<B_ * L, 256, 0, stream>>>(X, lnfg, lnfb, nullptr, nullptr, nullptr);
  colmax1_kernel<<<B_ * (L >> 6), 256, 0, stream>>>(X, P, L);
  colmax2_kernel<<<B_ * DM / 256, 256, 0, stream>>>(P, MC, L >> 6);
  proj_kernel<<<B_ * COUT, 256, 0, stream>>>(MC, pw, pb, out);
}

// Round 5
// 2280.138 us; speedup vs baseline: 1.0516x; 1.0516x over previous
//
#include <hip/hip_runtime.h>

#define B_ 8
#define H_ 8
#define DM 512
#define DH 64
#define LMAX 2048
#define COUT 2

typedef __attribute__((ext_vector_type(8))) short frag8;
typedef __attribute__((ext_vector_type(4))) float f32x4;

typedef __attribute__((address_space(1))) const unsigned int guint;
typedef __attribute__((address_space(3))) unsigned int luint;
__device__ __forceinline__ void dma16(const short* g, short* l) {
  __builtin_amdgcn_global_load_lds((guint*)g, (luint*)l, 16, 0, 0);
}

__device__ __forceinline__ short f2bf(float v) {
  unsigned u = __float_as_uint(v);
  unsigned r = (u + 0x7fffu + ((u >> 16) & 1u)) >> 16;   // RNE
  return (short)r;
}
__device__ __forceinline__ float bf2f(short s) {
  return __uint_as_float(((unsigned)(unsigned short)s) << 16);
}
// bf16x3 split of one f32 value — identical chain to wsplit (bitwise-same planes)
__device__ __forceinline__ void split3(float v, short* p0, short* p1, short* p2, size_t i) {
  short h0 = f2bf(v);
  float r1 = v - bf2f(h0);
  short h1 = f2bf(r1);
  float r2 = r1 - bf2f(h1);
  p0[i] = h0; p1[i] = h1; p2[i] = f2bf(r2);
}

// ---------------- JAX threefry2x32 ----------------
__device__ __forceinline__ void tf2x32(unsigned k0, unsigned k1, unsigned x0, unsigned x1,
                                       unsigned& o0, unsigned& o1) {
  unsigned ks2 = k0 ^ k1 ^ 0x1BD11BDAu;
  x0 += k0; x1 += k1;
#define RND(r) { x0 += x1; x1 = (x1 << r) | (x1 >> (32 - r)); x1 ^= x0; }
  RND(13) RND(15) RND(26) RND(6)  x0 += k1;  x1 += ks2 + 1u;
  RND(17) RND(29) RND(16) RND(24) x0 += ks2; x1 += k0 + 2u;
  RND(13) RND(15) RND(26) RND(6)  x0 += k0;  x1 += k1 + 3u;
  RND(17) RND(29) RND(16) RND(24) x0 += k1;  x1 += ks2 + 4u;
  RND(13) RND(15) RND(26) RND(6)  x0 += ks2; x1 += k0 + 5u;
#undef RND
  o0 = x0; o1 = x1;
}

// VERIFIED (R7, absmax 0.0): Variant B partitionable. DO NOT TOUCH.
__global__ void idx_kernel(int* __restrict__ idxArr, int L, int U, int layer) {
  int p = blockIdx.x * 256 + threadIdx.x;
  int half = L * U;
  if (p >= half) return;
  unsigned fk0, fk1, k20, k21, o0, o1;
  tf2x32(0u, 42u, 0u, (unsigned)layer, fk0, fk1);
  tf2x32(fk0, fk1, 0u, 1u, k20, k21);
  tf2x32(k20, k21, 0u, (unsigned)p, o0, o1);
  idxArr[p] = (int)((o0 ^ o1) & (unsigned)(L - 1));
}

// ---------------- token embed + positional encoding (+fused X-plane split) ----------------
__global__ void embed_kernel(const float* __restrict__ xe, const float* __restrict__ tw,
                             float* __restrict__ X, short* __restrict__ P0,
                             short* __restrict__ P1, short* __restrict__ P2) {
  int i = blockIdx.x * 256 + threadIdx.x;
  int c = i % DM;
  int l = (i / DM) % LMAX;
  int b = i / (DM * LMAX);
  int lm = (l + LMAX - 1) & (LMAX - 1);
  int lp = (l + 1) & (LMAX - 1);
  const float* xb = xe + b * LMAX;
  float tok = tw[c * 3 + 0] * xb[lm] + tw[c * 3 + 1] * xb[l] + tw[c * 3 + 2] * xb[lp];
  float freq = expf(-(float)(c & ~1) * (9.210340371976184f / 512.0f));
  float ang = (float)l * freq;
  float pe = (c & 1) ? cosf(ang) : sinf(ang);
  float v = tok + pe;
  X[i] = v;
  split3(v, P0, P1, P2, (size_t)i);
}

// ---------------- split f32 -> 3 bf16 planes (weights + FF1 activations) ----------------
__global__ void wsplit_kernel(const float* __restrict__ W, short* __restrict__ P0,
                              short* __restrict__ P1, short* __restrict__ P2, int n) {
  int i = blockIdx.x * 256 + threadIdx.x;
  if (i >= n) return;
  split3(W[i], P0, P1, P2, (size_t)i);
}

// conv weight transpose + split: Pt[n][tap*512+k] = split(w[n][k][tap])
__global__ void wt3_kernel(const float* __restrict__ w, short* __restrict__ P0,
                           short* __restrict__ P1, short* __restrict__ P2) {
  int i = blockIdx.x * 256 + threadIdx.x;   // 512*1536
  int n = i / 1536, r = i - n * 1536, tap = r >> 9, k = r & 511;
  float v = w[((size_t)n * DM + k) * 3 + tap];
  split3(v, P0, P1, P2, (size_t)i);
}

// ---------------- bf16x3-split MFMA GEMM, DMA staging (m97-style) ----------------
// BM=BN=128, BK=32, 4 waves (2x2 of 64x64). A AND B staged from pre-split bf16
// planes via global_load_lds width=16 (48 x 1KB chunks/iter). 6 of 9 products.
template <int ACT, int QKV, int ACC, int CONV>
__global__ __launch_bounds__(256) void mgemm(const short* __restrict__ A0g,
                                             const short* __restrict__ A1g,
                                             const short* __restrict__ A2g,
                                             const short* __restrict__ W0g,
                                             const short* __restrict__ W1g,
                                             const short* __restrict__ W2g,
                                             const float* __restrict__ bias,
                                             float* __restrict__ C, int L, int Ktot) {
  __shared__ short A0[128 * 32], A1[128 * 32], A2[128 * 32];
  __shared__ short B0[128 * 32], B1[128 * 32], B2[128 * 32];
  int tid = threadIdx.x;
  int lane = tid & 63, wave = tid >> 6;
  int crow = lane >> 2, ckq = lane & 3;     // DMA: 16 rows x 4 k-groups per chunk
  // XCD-aware swizzle: each XCD gets one m-row phase, iterating n fastest.
  int gx = gridDim.x;
  int flat = blockIdx.y * gx + blockIdx.x;
  int mB, nB;
  if ((gridDim.y & 7) == 0) {
    int phase = flat & 7, sup = flat >> 3;
    nB = sup % gx;
    mB = phase + 8 * (sup / gx);
  } else {
    nB = blockIdx.x; mB = blockIdx.y;
  }
  int n0 = nB * 128, m0 = mB * 128;
  int wm = (wave >> 1) * 64, wn = (wave & 1) * 64;
  f32x4 acc[4][4] = {};
  int lrow = lane & 15, lq = lane >> 4;

  for (int k0 = 0; k0 < Ktot; k0 += 32) {
    int tap = 0, kcol = k0;
    if (CONV) { tap = k0 >> 9; kcol = k0 & 511; }
#pragma unroll
    for (int q = 0; q < 6; ++q) {
      int gc = wave * 6 + q;               // 0..23
      int pl = gc >> 3, c = gc & 7;
      int grow = m0 + c * 16 + crow;
      const short* gp;
      if (CONV) {
        int b = grow / L, l = grow - b * L;
        int le = l + tap - 1;
        le = (le < 0) ? le + L : (le >= L ? le - L : le);
        gp = ((size_t)(b * L + le) * DM + kcol + ckq * 8) +
             (pl == 0 ? A0g : pl == 1 ? A1g : A2g);
      } else {
        gp = ((size_t)grow * DM + k0 + ckq * 8) +
             (pl == 0 ? A0g : pl == 1 ? A1g : A2g);
      }
      short* lp = (pl == 0 ? A0 : pl == 1 ? A1 : A2) + c * 512;
      dma16(gp, lp);
    }
#pragma unroll
    for (int q = 0; q < 6; ++q) {
      int gc = wave * 6 + q;
      int pl = gc >> 3, c = gc & 7;
      int grow = n0 + c * 16 + crow;
      const short* gp = ((size_t)grow * Ktot + k0 + ckq * 8) +
                        (pl == 0 ? W0g : pl == 1 ? W1g : W2g);
      short* lp = (pl == 0 ? B0 : pl == 1 ? B1 : B2) + c * 512;
      dma16(gp, lp);
    }
    __syncthreads();
    frag8 a0f[4], a1f[4], a2f[4];
#pragma unroll
    for (int ti = 0; ti < 4; ++ti) {
      int off = (wm + ti * 16 + lrow) * 32 + lq * 8;
      a0f[ti] = *(const frag8*)&A0[off];
      a1f[ti] = *(const frag8*)&A1[off];
      a2f[ti] = *(const frag8*)&A2[off];
    }
#pragma unroll
    for (int tj = 0; tj < 4; ++tj) {
      int off = (wn + tj * 16 + lrow) * 32 + lq * 8;
      frag8 b0 = *(const frag8*)&B0[off];
      frag8 b1 = *(const frag8*)&B1[off];
      frag8 b2 = *(const frag8*)&B2[off];
#pragma unroll
      for (int ti = 0; ti < 4; ++ti) {
        f32x4 ac = acc[ti][tj];
        ac = __builtin_amdgcn_mfma_f32_16x16x32_bf16(a1f[ti], b1, ac, 0, 0, 0);
        ac = __builtin_amdgcn_mfma_f32_16x16x32_bf16(a0f[ti], b2, ac, 0, 0, 0);
        ac = __builtin_amdgcn_mfma_f32_16x16x32_bf16(a2f[ti], b0, ac, 0, 0, 0);
        ac = __builtin_amdgcn_mfma_f32_16x16x32_bf16(a0f[ti], b1, ac, 0, 0, 0);
        ac = __builtin_amdgcn_mfma_f32_16x16x32_bf16(a1f[ti], b0, ac, 0, 0, 0);
        ac = __builtin_amdgcn_mfma_f32_16x16x32_bf16(a0f[ti], b0, ac, 0, 0, 0);
        acc[ti][tj] = ac;
      }
    }
    __syncthreads();
  }
  // epilogue: C/D map col=lane&15, row=(lane>>4)*4+reg
#pragma unroll
  for (int ti = 0; ti < 4; ++ti) {
#pragma unroll
    for (int tj = 0; tj < 4; ++tj) {
#pragma unroll
      for (int r = 0; r < 4; ++r) {
        int row = m0 + wm + ti * 16 + lq * 4 + r;
        int col = n0 + wn + tj * 16 + lrow;
        float v = acc[ti][tj][r];
        if (!CONV) v += bias[col];
        if (ACT) v = 0.5f * v * (1.0f + erff(v * 0.70710678118654752f));
        if (QKV) {
          int b = row / L, l = row - b * L;
          int h = col >> 6, d = col & 63;
          C[(((size_t)b * H_ + h) * L + l) * DH + d] = v;
        } else if (ACC) {
          C[(size_t)row * DM + col] += v;
        } else {
          C[(size_t)row * DM + col] = v;
        }
      }
    }
  }
}

// ---------------- conv epilogue: BN + ELU ----------------
__global__ void bnelu_kernel(float* __restrict__ Y, const float* __restrict__ cb,
                             const float* __restrict__ g, const float* __restrict__ be) {
  int i = blockIdx.x * 256 + threadIdx.x;
  int c = i % DM;
  const float invs = 0.9999950000374997f;  // 1/sqrt(1+1e-5)
  float z = Y[i] + cb[c];
  z = z * invs * g[c] + be[c];
  Y[i] = z > 0.f ? z : expm1f(z);
}

// ---------------- qkM: lane=(dchunk,sample), 3 shuffles per 8-sample pass ----------------
// At structural roofline (R1-R3 probes: time invariant to load scheduling =>
// divergent-VMEM lane-issue bound, ~136µs floor + overhead = 164µs). Clean R0.
template <int U>
__global__ void qkM_t(const float* __restrict__ Q, const float* __restrict__ Kd,
                      const int* __restrict__ idxArr, float* __restrict__ Mout, int L) {
  int lane = threadIdx.x & 63, wv = threadIdx.x >> 6;
  int row = blockIdx.x * 4 + wv;
  int l = row % L, bh = row / L;
  int u = lane & 7, dc = lane >> 3;       // sample slot, d-chunk
  const float* Qb = Q + ((size_t)bh * L + l) * DH + dc * 8;
  float4 q0 = *(const float4*)(Qb);
  float4 q1 = *(const float4*)(Qb + 4);
  const float* Kb = Kd + (size_t)bh * L * DH;
  const int* ip = idxArr + l * U;
  const int NP = (U + 7) / 8;
  float mx = -1e30f, sm = 0.f;
#pragma unroll
  for (int p = 0; p < NP; ++p) {
    int s = p * 8 + u;
    bool valid = (s < U);
    int ki = ip[valid ? s : 0];
    const float* kr = Kb + (size_t)ki * DH + dc * 8;
    float4 k0 = *(const float4*)(kr);
    float4 k1 = *(const float4*)(kr + 4);
    float d = q0.x * k0.x + q0.y * k0.y + q0.z * k0.z + q0.w * k0.w +
              q1.x * k1.x + q1.y * k1.y + q1.z * k1.z + q1.w * k1.w;
    d += __shfl_xor(d, 8, 64);
    d += __shfl_xor(d, 16, 64);
    d += __shfl_xor(d, 32, 64);
    if (valid) { mx = fmaxf(mx, d); sm += d; }
  }
#pragma unroll
  for (int o = 1; o <= 4; o <<= 1) {
    mx = fmaxf(mx, __shfl_xor(mx, o, 64));
    sm += __shfl_xor(sm, o, 64);
  }
  if (lane == 0) Mout[row] = mx - sm / (float)U;
}

// ---------------- top-U per bh ----------------
__global__ void topk_kernel(const float* __restrict__ M, int* __restrict__ top, int L, int U) {
  __shared__ float vals[LMAX];
  __shared__ float rv[256];
  __shared__ int ri[256];
  int bh = blockIdx.x, tid = threadIdx.x;
  for (int j = tid; j < L; j += 256) vals[j] = M[(size_t)bh * L + j];
  __syncthreads();
  for (int u = 0; u < U; ++u) {
    float bv = -1e30f; int bi = L;
    for (int j = tid; j < L; j += 256) {
      float v = vals[j];
      if (v > bv) { bv = v; bi = j; }
    }
    rv[tid] = bv; ri[tid] = bi;
    __syncthreads();
    for (int s = 128; s >= 1; s >>= 1) {
      if (tid < s) {
        float ov = rv[tid + s]; int oi = ri[tid + s];
        if (ov > rv[tid] || (ov == rv[tid] && oi < ri[tid])) { rv[tid] = ov; ri[tid] = oi; }
      }
      __syncthreads();
    }
    if (tid == 0) { top[bh * U + u] = ri[0]; vals[ri[0]] = -1e30f; }
    __syncthreads();
  }
}

// ---------------- v mean over L per (bh,d) ----------------
__global__ void vmean_kernel(const float* __restrict__ V, float* __restrict__ VM, int L) {
  __shared__ float red[256];
  int bh = blockIdx.x, tid = threadIdx.x, d = tid & 63, sq = tid >> 6;
  float s = 0.f;
  for (int l = sq; l < L; l += 4) s += V[((size_t)bh * L + l) * DH + d];
  red[tid] = s;
  __syncthreads();
  if (sq == 0) VM[bh * DH + d] = (red[d] + red[d + 64] + red[d + 128] + red[d + 192]) / (float)L;
}

// ---------------- fill ctx planes with v-mean (fused split) ----------------
__global__ void fill_kernel(const float* __restrict__ VM, short* __restrict__ P0,
                            short* __restrict__ P1, short* __restrict__ P2, int L) {
  size_t i = (size_t)blockIdx.x * 256 + threadIdx.x;
  int c = (int)(i % DM);
  int b = (int)(i / ((size_t)L * DM));
  split3(VM[b * DM + c], P0, P1, P2, i);
}

// ---------------- flash-style attention for selected queries ----------------
// R5: R4's 16q/192-block version tanked occupancy (7.8%, 64 CUs idle) —
// latency-bound, not BW-bound (HBM 6.7%). Back to 8q chunks (320 blocks) and
// widen to 512 threads / 8 waves, ONE query per wave (was 2/wave): 2560 resident
// waves (~10/CU), per-wave serial work halved. Per-query arithmetic chain is
// textually identical to the original per-query half -> bitwise identical.
// Epilogue keeps fused bf16x3 plane split.
__global__ __launch_bounds__(512) void attn_fused(const float* __restrict__ Q,
                                                  const float* __restrict__ Kd,
                                                  const float* __restrict__ V,
                                                  const int* __restrict__ top,
                                                  short* __restrict__ OP0,
                                                  short* __restrict__ OP1,
                                                  short* __restrict__ OP2,
                                                  int L, int U) {
  __shared__ float Qs[8][64];
  __shared__ float Kt[64][65];
  __shared__ float Vs[64][68];
  __shared__ float ps[8][64];
  __shared__ int lst[8];
  int nch = (U + 7) >> 3;
  int bh = blockIdx.x / nch, ch = blockIdx.x - bh * nch;
  int u0g = ch * 8;
  int qn = U - u0g; if (qn > 8) qn = 8;
  int tid = threadIdx.x, lane = tid & 63, wv = tid >> 6;
  if (tid < qn) lst[tid] = top[bh * U + u0g + tid];
  __syncthreads();
  if (tid < qn * 64) {
    int u = tid >> 6, d = tid & 63;
    Qs[u][d] = Q[((size_t)bh * L + lst[u]) * DH + d];
  }
  __syncthreads();
  int ua = wv;                       // one query per wave
  bool hasA = ua < qn;
  float m0 = -1e30f, l0 = 0.f, o0 = 0.f;
  const float* Kbase = Kd + (size_t)bh * L * DH;
  const float* Vbase = V + (size_t)bh * L * DH;
  for (int t0 = 0; t0 < L; t0 += 64) {
#pragma unroll
    for (int it = 0; it < 2; ++it) {
      int idx = tid + it * 512;
      int j = idx >> 4, d4 = (idx & 15) * 4;
      float4 kv = *(const float4*)(Kbase + (size_t)(t0 + j) * DH + d4);
      Kt[d4 + 0][j] = kv.x; Kt[d4 + 1][j] = kv.y;
      Kt[d4 + 2][j] = kv.z; Kt[d4 + 3][j] = kv.w;
      *(float4*)&Vs[j][d4] = *(const float4*)(Vbase + (size_t)(t0 + j) * DH + d4);
    }
    __syncthreads();
    float s0 = 0.f;
#pragma unroll 16
    for (int d = 0; d < 64; ++d) {
      float kd = Kt[d][lane];
      s0 += kd * Qs[ua & 7][d];
    }
    s0 *= 0.125f;
    if (hasA) {
      float tm = s0;
#pragma unroll
      for (int o = 32; o >= 1; o >>= 1) tm = fmaxf(tm, __shfl_xor(tm, o, 64));
      float nm = fmaxf(m0, tm);
      float alpha = expf(m0 - nm);
      float p = expf(s0 - nm);
      float tsum = p;
#pragma unroll
      for (int o = 32; o >= 1; o >>= 1) tsum += __shfl_xor(tsum, o, 64);
      l0 = l0 * alpha + tsum;
      m0 = nm;
      ps[ua][lane] = p;
      o0 *= alpha;
#pragma unroll 16
      for (int j = 0; j < 64; ++j) o0 += ps[ua][j] * Vs[j][lane];
    }
    __syncthreads();
  }
  int b = bh / H_, h = bh - b * H_;
  if (hasA) {
    size_t i = ((size_t)b * L + lst[ua]) * DM + h * DH + lane;
    split3(o0 / l0, OP0, OP1, OP2, i);
  }
}

// ---------------- x = LayerNorm(x) in place (+optional fused plane split) ----------------
__global__ void ln_kernel(float* __restrict__ X, const float* __restrict__ g,
                          const float* __restrict__ be, short* __restrict__ P0,
                          short* __restrict__ P1, short* __restrict__ P2) {
  __shared__ float red[256];
  int row = blockIdx.x, tid = threadIdx.x;
  size_t base = (size_t)row * DM;
  float t0 = X[base + tid];
  float t1 = X[base + tid + 256];
  red[tid] = t0 + t1;
  __syncthreads();
  for (int s = 128; s >= 1; s >>= 1) { if (tid < s) red[tid] += red[tid + s]; __syncthreads(); }
  float mu = red[0] / 512.0f;
  __syncthreads();
  float d0 = t0 - mu, d1 = t1 - mu;
  red[tid] = d0 * d0 + d1 * d1;
  __syncthreads();
  for (int s = 128; s >= 1; s >>= 1) { if (tid < s) red[tid] += red[tid + s]; __syncthreads(); }
  float rstd = 1.0f / sqrtf(red[0] / 512.0f + 1e-5f);
  float v0 = d0 * rstd * g[tid] + be[tid];
  float v1 = d1 * rstd * g[tid + 256] + be[tid + 256];
  X[base + tid] = v0;
  X[base + tid + 256] = v1;
  if (P0) {
    split3(v0, P0, P1, P2, base + tid);
    split3(v1, P0, P1, P2, base + tid + 256);
  }
}

// ---------------- maxpool k=3 s=2 pad=1 along L (+fused plane split) ----------------
__global__ void pool_kernel(const float* __restrict__ Y, float* __restrict__ X, int L2,
                            short* __restrict__ P0, short* __restrict__ P1,
                            short* __restrict__ P2) {
  int i = blockIdx.x * 256 + threadIdx.x;
  int c = i % DM;
  int t = (i / DM) % L2;
  int b = i / (DM * L2);
  int L = L2 * 2;
  const float* yb = Y + (size_t)b * L * DM + c;
  float m = fmaxf(yb[(size_t)(2 * t) * DM], yb[(size_t)(2 * t + 1) * DM]);
  if (t > 0) m = fmaxf(m, yb[(size_t)(2 * t - 1) * DM]);
  X[i] = m;
  split3(m, P0, P1, P2, (size_t)i);
}

// ---------------- column max, 2-stage ----------------
__global__ void colmax1_kernel(const float* __restrict__ X, float* __restrict__ P, int L) {
  int nlc = L >> 6;
  int bl = blockIdx.x;
  int b = bl / nlc, lc = bl % nlc;
  const float* xb = X + ((size_t)b * L + lc * 64) * DM;
  for (int c = threadIdx.x; c < DM; c += 256) {
    float m = -1e30f;
    for (int r = 0; r < 64; ++r) m = fmaxf(m, xb[(size_t)r * DM + c]);
    P[((size_t)b * nlc + lc) * DM + c] = m;
  }
}
__global__ void colmax2_kernel(const float* __restrict__ P, float* __restrict__ mc, int nlc) {
  int i = blockIdx.x * 256 + threadIdx.x;
  int b = i / DM, c = i % DM;
  float m = -1e30f;
  for (int lc = 0; lc < nlc; ++lc) m = fmaxf(m, P[((size_t)b * nlc + lc) * DM + c]);
  mc[i] = m;
}

// ---------------- final projection ----------------
__global__ void proj_kernel(const float* __restrict__ mc, const float* __restrict__ pw,
                            const float* __restrict__ pb, float* __restrict__ out) {
  __shared__ float red[256];
  int bo = blockIdx.x, b = bo / COUT, o = bo % COUT, tid = threadIdx.x;
  float s = mc[b * DM + tid] * pw[o * DM + tid] +
            mc[b * DM + tid + 256] * pw[o * DM + tid + 256];
  red[tid] = s;
  __syncthreads();
  for (int st = 128; st >= 1; st >>= 1) { if (tid < st) red[tid] += red[tid + st]; __syncthreads(); }
  if (tid == 0) out[bo] = red[0] + pb[o];
}

extern "C" void kernel_launch(void* const* d_in, const int* in_sizes, int n_in,
                              void* d_out, int out_size, void* d_ws, size_t ws_size,
                              hipStream_t stream) {
  (void)in_sizes; (void)n_in; (void)out_size;
  const float* xe   = (const float*)d_in[0];
  const float* tw   = (const float*)d_in[1];
  const float* Wq   = (const float*)d_in[2];
  const float* Wk   = (const float*)d_in[3];
  const float* Wv   = (const float*)d_in[4];
  const float* Wo   = (const float*)d_in[5];
  const float* bq   = (const float*)d_in[6];
  const float* bk   = (const float*)d_in[7];
  const float* bv   = (const float*)d_in[8];
  const float* bo   = (const float*)d_in[9];
  const float* W1   = (const float*)d_in[10];
  const float* b1   = (const float*)d_in[11];
  const float* W2   = (const float*)d_in[12];
  const float* b2   = (const float*)d_in[13];
  const float* ln1g = (const float*)d_in[14];
  const float* ln1b = (const float*)d_in[15];
  const float* ln2g = (const float*)d_in[16];
  const float* ln2b = (const float*)d_in[17];
  const float* dcw  = (const float*)d_in[18];
  const float* dcb  = (const float*)d_in[19];
  const float* bng  = (const float*)d_in[20];
  const float* bnb  = (const float*)d_in[21];
  const float* lnfg = (const float*)d_in[22];
  const float* lnfb = (const float*)d_in[23];
  const float* pw   = (const float*)d_in[24];
  const float* pb   = (const float*)d_in[25];
  float* out = (float*)d_out;

  float* Wf = (float*)d_ws;
  const size_t NB  = (size_t)B_ * LMAX * DM;             // 8,388,608 floats
  const size_t NHB = (size_t)H_ * LMAX * DH;             // 1,048,576 floats
  const size_t S_IDX = 81920, S_MV = 131072, S_TOP = 4096, S_VM = 4096,
               S_MC = 4096, S_P = 32768;
  const size_t PLANE  = (size_t)512 * 1536;              // weight plane (shorts)
  const size_t APLANE = NB;                              // activation plane (shorts)
  const size_t S_WP = 3 * PLANE / 2 + 1024;              // floats
  const size_t S_AP = 3 * APLANE / 2 + 1024;             // floats
  const size_t SMALL = S_IDX + S_MV + S_TOP + S_VM + S_MC + S_P + S_WP + S_AP + 1024;

  int g = 8;
  while (g > 1 && (2 * NB + 3 * (size_t)g * NHB + SMALL) * 4 > ws_size) g >>= 1;

  float* X  = Wf;
  float* T  = X + NB;
  float* Q  = T + NB;
  float* K  = Q + (size_t)g * NHB;
  float* V  = K + (size_t)g * NHB;
  float* SM = V + (size_t)g * NHB;
  int*   IDX = (int*)SM;
  float* Mv  = SM + S_IDX;
  int*   TOP = (int*)(Mv + S_MV);
  float* VM  = Mv + S_MV + S_TOP;
  float* MC  = VM + S_VM;
  float* P   = MC + S_MC;
  short* WP0 = (short*)(P + S_P);
  short* WP1 = WP0 + PLANE;
  short* WP2 = WP1 + PLANE;
  short* AP0 = (short*)((float*)(P + S_P) + S_WP);
  short* AP1 = AP0 + APLANE;
  short* AP2 = AP1 + APLANE;

  // embed writes X f32 + X-planes (fused split for layer-0 QKV inputs)
  embed_kernel<<<B_ * LMAX * DM / 256, 256, 0, stream>>>(xe, tw, X, AP0, AP1, AP2);

  int L = LMAX;
  for (int i = 0; i < 3; ++i) {
    int U = (i == 0) ? 40 : 35;
    size_t wOff = (size_t)i * DM * DM;
    int ng = B_ / g;
    int nch = (U + 7) >> 3;
    const int NW = DM * DM;

    idx_kernel<<<(L * U + 255) / 256, 256, 0, stream>>>(IDX, L, U, i);

    for (int gb = 0; gb < ng; ++gb) {
      size_t aoff = (size_t)gb * g * L * DM;
      dim3 gq(DM / 128, g * L / 128);
      // A-planes of X already present (embed/pool fused split)
      wsplit_kernel<<<NW / 256, 256, 0, stream>>>(Wq + wOff, WP0, WP1, WP2, NW);
      mgemm<0, 1, 0, 0><<<gq, 256, 0, stream>>>(AP0 + aoff, AP1 + aoff, AP2 + aoff,
                                                WP0, WP1, WP2, bq + i * DM, Q, L, DM);
      wsplit_kernel<<<NW / 256, 256, 0, stream>>>(Wk + wOff, WP0, WP1, WP2, NW);
      mgemm<0, 1, 0, 0><<<gq, 256, 0, stream>>>(AP0 + aoff, AP1 + aoff, AP2 + aoff,
                                                WP0, WP1, WP2, bk + i * DM, K, L, DM);
      wsplit_kernel<<<NW / 256, 256, 0, stream>>>(Wv + wOff, WP0, WP1, WP2, NW);
      mgemm<0, 1, 0, 0><<<gq, 256, 0, stream>>>(AP0 + aoff, AP1 + aoff, AP2 + aoff,
                                                WP0, WP1, WP2, bv + i * DM, V, L, DM);
      if (U == 40) qkM_t<40><<<g * H_ * L / 4, 256, 0, stream>>>(Q, K, IDX, Mv, L);
      else         qkM_t<35><<<g * H_ * L / 4, 256, 0, stream>>>(Q, K, IDX, Mv, L);
      topk_kernel<<<g * H_, 256, 0, stream>>>(Mv, TOP, L, U);
      vmean_kernel<<<g * H_, 256, 0, stream>>>(V, VM, L);
      // ctx planes: fill with v-mean splits, attn overwrites selected rows
      fill_kernel<<<(unsigned)((size_t)g * L * DM / 256), 256, 0, stream>>>(
          VM, AP0 + aoff, AP1 + aoff, AP2 + aoff, L);
      attn_fused<<<g * H_ * nch, 512, 0, stream>>>(Q, K, V, TOP, AP0 + aoff,
                                                   AP1 + aoff, AP2 + aoff, L, U);
    }

    int Mf = B_ * L * DM;
    dim3 gf(DM / 128, B_ * L / 128);
    // Wo: A = ctx planes (fill/attn fused split)
    wsplit_kernel<<<NW / 256, 256, 0, stream>>>(Wo + wOff, WP0, WP1, WP2, NW);
    mgemm<0, 0, 1, 0><<<gf, 256, 0, stream>>>(AP0, AP1, AP2, WP0, WP1, WP2,
                                              bo + i * DM, X, L, DM);
    // ln1 fused: writes X + X-planes for FF1
    ln_kernel<<<B_ * L, 256, 0, stream>>>(X, ln1g + i * DM, ln1b + i * DM, AP0, AP1, AP2);
    wsplit_kernel<<<NW / 256, 256, 0, stream>>>(W1 + wOff, WP0, WP1, WP2, NW);
    mgemm<1, 0, 0, 0><<<gf, 256, 0, stream>>>(AP0, AP1, AP2, WP0, WP1, WP2,
                                              b1 + i * DM, T, L, DM);
    // split gelu output (can't fuse: reads+writes same plane buffers)
    wsplit_kernel<<<Mf / 256, 256, 0, stream>>>(T, AP0, AP1, AP2, Mf);
    wsplit_kernel<<<NW / 256, 256, 0, stream>>>(W2 + wOff, WP0, WP1, WP2, NW);
    mgemm<0, 0, 1, 0><<<gf, 256, 0, stream>>>(AP0, AP1, AP2, WP0, WP1, WP2,
                                              b2 + i * DM, X, L, DM);
    // ln2 fused: planes only needed when a conv layer follows
    if (i < 2) {
      ln_kernel<<<B_ * L, 256, 0, stream>>>(X, ln2g + i * DM, ln2b + i * DM, AP0, AP1, AP2);
      wt3_kernel<<<DM * 1536 / 256, 256, 0, stream>>>(dcw + (size_t)i * DM * DM * 3,
                                                      WP0, WP1, WP2);
      mgemm<0, 0, 0, 1><<<gf, 256, 0, stream>>>(AP0, AP1, AP2, WP0, WP1, WP2,
                                                nullptr, T, L, 1536);
      bnelu_kernel<<<B_ * L * DM / 256, 256, 0, stream>>>(T, dcb + i * DM, bng + i * DM,
                                                          bnb + i * DM);
      L >>= 1;
      // pool fused: writes X + X-planes for next layer's QKV
      pool_kernel<<<B_ * L * DM / 256, 256, 0, stream>>>(T, X, L, AP0, AP1, AP2);
    } else {
      ln_kernel<<<B_ * L, 256, 0, stream>>>(X, ln2g + i * DM, ln2b + i * DM,
                                            nullptr, nullptr, nullptr);
    }
  }

  ln_kernel<<<B_ * L, 256, 0, stream>>>(X, lnfg, lnfb, nullptr, nullptr, nullptr);
  colmax1_kernel<<<B_ * (L >> 6), 256, 0, stream>>>(X, P, L);
  colmax2_kernel<<<B_ * DM / 256, 256, 0, stream>>>(P, MC, L >> 6);
  proj_kernel<<<B_ * COUT, 256, 0, stream>>>(MC, pw, pb, out);
}

// Round 6
// 2166.917 us; speedup vs baseline: 1.1066x; 1.0522x over previous
//
#include <hip/hip_runtime.h>

#define B_ 8
#define H_ 8
#define DM 512
#define DH 64
#define LMAX 2048
#define COUT 2

typedef __attribute__((ext_vector_type(8))) short frag8;
typedef __attribute__((ext_vector_type(4))) float f32x4;

typedef __attribute__((address_space(1))) const unsigned int guint;
typedef __attribute__((address_space(3))) unsigned int luint;
__device__ __forceinline__ void dma16(const short* g, short* l) {
  __builtin_amdgcn_global_load_lds((guint*)g, (luint*)l, 16, 0, 0);
}

__device__ __forceinline__ short f2bf(float v) {
  unsigned u = __float_as_uint(v);
  unsigned r = (u + 0x7fffu + ((u >> 16) & 1u)) >> 16;   // RNE
  return (short)r;
}
__device__ __forceinline__ float bf2f(short s) {
  return __uint_as_float(((unsigned)(unsigned short)s) << 16);
}
// bf16x3 split of one f32 value — identical chain to wsplit (bitwise-same planes)
__device__ __forceinline__ void split3(float v, short* p0, short* p1, short* p2, size_t i) {
  short h0 = f2bf(v);
  float r1 = v - bf2f(h0);
  short h1 = f2bf(r1);
  float r2 = r1 - bf2f(h1);
  p0[i] = h0; p1[i] = h1; p2[i] = f2bf(r2);
}

// ---------------- JAX threefry2x32 ----------------
__device__ __forceinline__ void tf2x32(unsigned k0, unsigned k1, unsigned x0, unsigned x1,
                                       unsigned& o0, unsigned& o1) {
  unsigned ks2 = k0 ^ k1 ^ 0x1BD11BDAu;
  x0 += k0; x1 += k1;
#define RND(r) { x0 += x1; x1 = (x1 << r) | (x1 >> (32 - r)); x1 ^= x0; }
  RND(13) RND(15) RND(26) RND(6)  x0 += k1;  x1 += ks2 + 1u;
  RND(17) RND(29) RND(16) RND(24) x0 += ks2; x1 += k0 + 2u;
  RND(13) RND(15) RND(26) RND(6)  x0 += k0;  x1 += k1 + 3u;
  RND(17) RND(29) RND(16) RND(24) x0 += k1;  x1 += ks2 + 4u;
  RND(13) RND(15) RND(26) RND(6)  x0 += ks2; x1 += k0 + 5u;
#undef RND
  o0 = x0; o1 = x1;
}

// VERIFIED (R7, absmax 0.0): Variant B partitionable. DO NOT TOUCH.
__global__ void idx_kernel(int* __restrict__ idxArr, int L, int U, int layer) {
  int p = blockIdx.x * 256 + threadIdx.x;
  int half = L * U;
  if (p >= half) return;
  unsigned fk0, fk1, k20, k21, o0, o1;
  tf2x32(0u, 42u, 0u, (unsigned)layer, fk0, fk1);
  tf2x32(fk0, fk1, 0u, 1u, k20, k21);
  tf2x32(k20, k21, 0u, (unsigned)p, o0, o1);
  idxArr[p] = (int)((o0 ^ o1) & (unsigned)(L - 1));
}

// ---------------- token embed + positional encoding (+fused X-plane split) ----------------
__global__ void embed_kernel(const float* __restrict__ xe, const float* __restrict__ tw,
                             float* __restrict__ X, short* __restrict__ P0,
                             short* __restrict__ P1, short* __restrict__ P2) {
  int i = blockIdx.x * 256 + threadIdx.x;
  int c = i % DM;
  int l = (i / DM) % LMAX;
  int b = i / (DM * LMAX);
  int lm = (l + LMAX - 1) & (LMAX - 1);
  int lp = (l + 1) & (LMAX - 1);
  const float* xb = xe + b * LMAX;
  float tok = tw[c * 3 + 0] * xb[lm] + tw[c * 3 + 1] * xb[l] + tw[c * 3 + 2] * xb[lp];
  float freq = expf(-(float)(c & ~1) * (9.210340371976184f / 512.0f));
  float ang = (float)l * freq;
  float pe = (c & 1) ? cosf(ang) : sinf(ang);
  float v = tok + pe;
  X[i] = v;
  split3(v, P0, P1, P2, (size_t)i);
}

// ---------------- split f32 -> 3 bf16 planes ----------------
__global__ void wsplit_kernel(const float* __restrict__ W, short* __restrict__ P0,
                              short* __restrict__ P1, short* __restrict__ P2, int n) {
  int i = blockIdx.x * 256 + threadIdx.x;
  if (i >= n) return;
  split3(W[i], P0, P1, P2, (size_t)i);
}

// conv weight transpose + split: Pt[n][tap*512+k] = split(w[n][k][tap])
__global__ void wt3_kernel(const float* __restrict__ w, short* __restrict__ P0,
                           short* __restrict__ P1, short* __restrict__ P2) {
  int i = blockIdx.x * 256 + threadIdx.x;   // 512*1536
  int n = i / 1536, r = i - n * 1536, tap = r >> 9, k = r & 511;
  float v = w[((size_t)n * DM + k) * 3 + tap];
  split3(v, P0, P1, P2, (size_t)i);
}

// bias concat bq||bk||bv for merged QKV GEMM
__global__ void bcat_kernel(const float* __restrict__ bq, const float* __restrict__ bk,
                            const float* __restrict__ bv, float* __restrict__ o) {
  int i = blockIdx.x * 256 + threadIdx.x;   // 1536
  o[i] = i < 512 ? bq[i] : (i < 1024 ? bk[i - 512] : bv[i - 1024]);
}

// ---------------- bf16x3-split MFMA GEMM, DMA staging (m97-style) ----------------
// BM=BN=128, BK=32, 4 waves (2x2 of 64x64). 6 of 9 products.
// R6: QKV merged into one N=1536 GEMM (same per-element MFMA sequence ->
// bitwise identical); BN=1 fuses bnelu into CONV epilogue (same value chain).
template <int ACT, int QKV, int ACC, int CONV, int BN>
__global__ __launch_bounds__(256) void mgemm(const short* __restrict__ A0g,
                                             const short* __restrict__ A1g,
                                             const short* __restrict__ A2g,
                                             const short* __restrict__ W0g,
                                             const short* __restrict__ W1g,
                                             const short* __restrict__ W2g,
                                             const float* __restrict__ bias,
                                             const float* __restrict__ bng,
                                             const float* __restrict__ bnbe,
                                             float* __restrict__ C, long qs,
                                             int L, int Ktot) {
  __shared__ short A0[128 * 32], A1[128 * 32], A2[128 * 32];
  __shared__ short B0[128 * 32], B1[128 * 32], B2[128 * 32];
  int tid = threadIdx.x;
  int lane = tid & 63, wave = tid >> 6;
  int crow = lane >> 2, ckq = lane & 3;     // DMA: 16 rows x 4 k-groups per chunk
  // XCD-aware swizzle: each XCD gets one m-row phase, iterating n fastest.
  int gx = gridDim.x;
  int flat = blockIdx.y * gx + blockIdx.x;
  int mB, nB;
  if ((gridDim.y & 7) == 0) {
    int phase = flat & 7, sup = flat >> 3;
    nB = sup % gx;
    mB = phase + 8 * (sup / gx);
  } else {
    nB = blockIdx.x; mB = blockIdx.y;
  }
  int n0 = nB * 128, m0 = mB * 128;
  int wm = (wave >> 1) * 64, wn = (wave & 1) * 64;
  f32x4 acc[4][4] = {};
  int lrow = lane & 15, lq = lane >> 4;

  for (int k0 = 0; k0 < Ktot; k0 += 32) {
    int tap = 0, kcol = k0;
    if (CONV) { tap = k0 >> 9; kcol = k0 & 511; }
#pragma unroll
    for (int q = 0; q < 6; ++q) {
      int gc = wave * 6 + q;               // 0..23
      int pl = gc >> 3, c = gc & 7;
      int grow = m0 + c * 16 + crow;
      const short* gp;
      if (CONV) {
        int b = grow / L, l = grow - b * L;
        int le = l + tap - 1;
        le = (le < 0) ? le + L : (le >= L ? le - L : le);
        gp = ((size_t)(b * L + le) * DM + kcol + ckq * 8) +
             (pl == 0 ? A0g : pl == 1 ? A1g : A2g);
      } else {
        gp = ((size_t)grow * DM + k0 + ckq * 8) +
             (pl == 0 ? A0g : pl == 1 ? A1g : A2g);
      }
      short* lp = (pl == 0 ? A0 : pl == 1 ? A1 : A2) + c * 512;
      dma16(gp, lp);
    }
#pragma unroll
    for (int q = 0; q < 6; ++q) {
      int gc = wave * 6 + q;
      int pl = gc >> 3, c = gc & 7;
      int grow = n0 + c * 16 + crow;
      const short* gp = ((size_t)grow * Ktot + k0 + ckq * 8) +
                        (pl == 0 ? W0g : pl == 1 ? W1g : W2g);
      short* lp = (pl == 0 ? B0 : pl == 1 ? B1 : B2) + c * 512;
      dma16(gp, lp);
    }
    __syncthreads();
    frag8 a0f[4], a1f[4], a2f[4];
#pragma unroll
    for (int ti = 0; ti < 4; ++ti) {
      int off = (wm + ti * 16 + lrow) * 32 + lq * 8;
      a0f[ti] = *(const frag8*)&A0[off];
      a1f[ti] = *(const frag8*)&A1[off];
      a2f[ti] = *(const frag8*)&A2[off];
    }
#pragma unroll
    for (int tj = 0; tj < 4; ++tj) {
      int off = (wn + tj * 16 + lrow) * 32 + lq * 8;
      frag8 b0 = *(const frag8*)&B0[off];
      frag8 b1 = *(const frag8*)&B1[off];
      frag8 b2 = *(const frag8*)&B2[off];
#pragma unroll
      for (int ti = 0; ti < 4; ++ti) {
        f32x4 ac = acc[ti][tj];
        ac = __builtin_amdgcn_mfma_f32_16x16x32_bf16(a1f[ti], b1, ac, 0, 0, 0);
        ac = __builtin_amdgcn_mfma_f32_16x16x32_bf16(a0f[ti], b2, ac, 0, 0, 0);
        ac = __builtin_amdgcn_mfma_f32_16x16x32_bf16(a2f[ti], b0, ac, 0, 0, 0);
        ac = __builtin_amdgcn_mfma_f32_16x16x32_bf16(a0f[ti], b1, ac, 0, 0, 0);
        ac = __builtin_amdgcn_mfma_f32_16x16x32_bf16(a1f[ti], b0, ac, 0, 0, 0);
        ac = __builtin_amdgcn_mfma_f32_16x16x32_bf16(a0f[ti], b0, ac, 0, 0, 0);
        acc[ti][tj] = ac;
      }
    }
    __syncthreads();
  }
  // epilogue: C/D map col=lane&15, row=(lane>>4)*4+reg
#pragma unroll
  for (int ti = 0; ti < 4; ++ti) {
#pragma unroll
    for (int tj = 0; tj < 4; ++tj) {
#pragma unroll
      for (int r = 0; r < 4; ++r) {
        int row = m0 + wm + ti * 16 + lq * 4 + r;
        int col = n0 + wn + tj * 16 + lrow;
        float v = acc[ti][tj][r];
        if (!CONV) v += bias[col];
        if (ACT) v = 0.5f * v * (1.0f + erff(v * 0.70710678118654752f));
        if (BN) {   // fused bnelu (same chain as old bnelu_kernel)
          const float invs = 0.9999950000374997f;  // 1/sqrt(1+1e-5)
          float z = v + bias[col];
          z = z * invs * bng[col] + bnbe[col];
          v = z > 0.f ? z : expm1f(z);
        }
        if (QKV) {  // merged: col in [0,1536), sel 0/1/2 -> Q/K/V (stride qs)
          int sel = col >> 9, cc = col & 511;
          int b = row / L, l = row - b * L;
          int h = cc >> 6, d = cc & 63;
          C[(size_t)sel * qs + (((size_t)b * H_ + h) * L + l) * DH + d] = v;
        } else if (ACC) {
          C[(size_t)row * DM + col] += v;
        } else {
          C[(size_t)row * DM + col] = v;
        }
      }
    }
  }
}

// ---------------- qkM: lane=(dchunk,sample), 3 shuffles per 8-sample pass ----------------
// At structural roofline (R1-R3 probes: time invariant to load scheduling =>
// divergent-VMEM lane-issue bound, ~136µs floor + overhead = 164µs). Clean R0.
template <int U>
__global__ void qkM_t(const float* __restrict__ Q, const float* __restrict__ Kd,
                      const int* __restrict__ idxArr, float* __restrict__ Mout, int L) {
  int lane = threadIdx.x & 63, wv = threadIdx.x >> 6;
  int row = blockIdx.x * 4 + wv;
  int l = row % L, bh = row / L;
  int u = lane & 7, dc = lane >> 3;       // sample slot, d-chunk
  const float* Qb = Q + ((size_t)bh * L + l) * DH + dc * 8;
  float4 q0 = *(const float4*)(Qb);
  float4 q1 = *(const float4*)(Qb + 4);
  const float* Kb = Kd + (size_t)bh * L * DH;
  const int* ip = idxArr + l * U;
  const int NP = (U + 7) / 8;
  float mx = -1e30f, sm = 0.f;
#pragma unroll
  for (int p = 0; p < NP; ++p) {
    int s = p * 8 + u;
    bool valid = (s < U);
    int ki = ip[valid ? s : 0];
    const float* kr = Kb + (size_t)ki * DH + dc * 8;
    float4 k0 = *(const float4*)(kr);
    float4 k1 = *(const float4*)(kr + 4);
    float d = q0.x * k0.x + q0.y * k0.y + q0.z * k0.z + q0.w * k0.w +
              q1.x * k1.x + q1.y * k1.y + q1.z * k1.z + q1.w * k1.w;
    d += __shfl_xor(d, 8, 64);
    d += __shfl_xor(d, 16, 64);
    d += __shfl_xor(d, 32, 64);
    if (valid) { mx = fmaxf(mx, d); sm += d; }
  }
#pragma unroll
  for (int o = 1; o <= 4; o <<= 1) {
    mx = fmaxf(mx, __shfl_xor(mx, o, 64));
    sm += __shfl_xor(sm, o, 64);
  }
  if (lane == 0) Mout[row] = mx - sm / (float)U;
}

// ---------------- top-U per bh ----------------
// R6: shfl-based argmax. The (max, min-index) operator is associative +
// commutative and compare-only -> any reduction order yields the identical
// selection sequence (bitwise-identical downstream). 8 barrier levels/iter -> 1.
__global__ void topk_kernel(const float* __restrict__ M, int* __restrict__ top, int L, int U) {
  __shared__ float vals[LMAX];
  __shared__ float wvv[4];
  __shared__ int wii[4];
  int bh = blockIdx.x, tid = threadIdx.x, lane = tid & 63, w = tid >> 6;
  for (int j = tid; j < L; j += 256) vals[j] = M[(size_t)bh * L + j];
  __syncthreads();
  for (int u = 0; u < U; ++u) {
    float bv = -1e30f; int bi = L;
    for (int j = tid; j < L; j += 256) {
      float v = vals[j];
      if (v > bv) { bv = v; bi = j; }
    }
#pragma unroll
    for (int o = 32; o >= 1; o >>= 1) {
      float ov = __shfl_xor(bv, o, 64);
      int oi = __shfl_xor(bi, o, 64);
      if (ov > bv || (ov == bv && oi < bi)) { bv = ov; bi = oi; }
    }
    if (lane == 0) { wvv[w] = bv; wii[w] = bi; }
    __syncthreads();
    if (tid == 0) {
#pragma unroll
      for (int k = 1; k < 4; ++k) {
        if (wvv[k] > bv || (wvv[k] == bv && wii[k] < bi)) { bv = wvv[k]; bi = wii[k]; }
      }
      top[bh * U + u] = bi;
      vals[bi] = -1e30f;
    }
    __syncthreads();
  }
}

// ---------------- v mean over L per (bh,d) ----------------
__global__ void vmean_kernel(const float* __restrict__ V, float* __restrict__ VM, int L) {
  __shared__ float red[256];
  int bh = blockIdx.x, tid = threadIdx.x, d = tid & 63, sq = tid >> 6;
  float s = 0.f;
  for (int l = sq; l < L; l += 4) s += V[((size_t)bh * L + l) * DH + d];
  red[tid] = s;
  __syncthreads();
  if (sq == 0) VM[bh * DH + d] = (red[d] + red[d + 64] + red[d + 128] + red[d + 192]) / (float)L;
}

// ---------------- fill ctx planes with v-mean (fused split) ----------------
__global__ void fill_kernel(const float* __restrict__ VM, short* __restrict__ P0,
                            short* __restrict__ P1, short* __restrict__ P2, int L) {
  size_t i = (size_t)blockIdx.x * 256 + threadIdx.x;
  int c = (int)(i % DM);
  int b = (int)(i / ((size_t)L * DM));
  split3(VM[b * DM + c], P0, P1, P2, i);
}

// ---------------- flash-style attention for selected queries ----------------
// R5 structure (verified): 512 threads / 8 waves, one query per wave, 8q chunks
// -> 320 blocks, ~10 waves/CU. Per-query chain bitwise identical to original.
__global__ __launch_bounds__(512) void attn_fused(const float* __restrict__ Q,
                                                  const float* __restrict__ Kd,
                                                  const float* __restrict__ V,
                                                  const int* __restrict__ top,
                                                  short* __restrict__ OP0,
                                                  short* __restrict__ OP1,
                                                  short* __restrict__ OP2,
                                                  int L, int U) {
  __shared__ float Qs[8][64];
  __shared__ float Kt[64][65];
  __shared__ float Vs[64][68];
  __shared__ float ps[8][64];
  __shared__ int lst[8];
  int nch = (U + 7) >> 3;
  int bh = blockIdx.x / nch, ch = blockIdx.x - bh * nch;
  int u0g = ch * 8;
  int qn = U - u0g; if (qn > 8) qn = 8;
  int tid = threadIdx.x, lane = tid & 63, wv = tid >> 6;
  if (tid < qn) lst[tid] = top[bh * U + u0g + tid];
  __syncthreads();
  if (tid < qn * 64) {
    int u = tid >> 6, d = tid & 63;
    Qs[u][d] = Q[((size_t)bh * L + lst[u]) * DH + d];
  }
  __syncthreads();
  int ua = wv;                       // one query per wave
  bool hasA = ua < qn;
  float m0 = -1e30f, l0 = 0.f, o0 = 0.f;
  const float* Kbase = Kd + (size_t)bh * L * DH;
  const float* Vbase = V + (size_t)bh * L * DH;
  for (int t0 = 0; t0 < L; t0 += 64) {
#pragma unroll
    for (int it = 0; it < 2; ++it) {
      int idx = tid + it * 512;
      int j = idx >> 4, d4 = (idx & 15) * 4;
      float4 kv = *(const float4*)(Kbase + (size_t)(t0 + j) * DH + d4);
      Kt[d4 + 0][j] = kv.x; Kt[d4 + 1][j] = kv.y;
      Kt[d4 + 2][j] = kv.z; Kt[d4 + 3][j] = kv.w;
      *(float4*)&Vs[j][d4] = *(const float4*)(Vbase + (size_t)(t0 + j) * DH + d4);
    }
    __syncthreads();
    float s0 = 0.f;
#pragma unroll 16
    for (int d = 0; d < 64; ++d) {
      float kd = Kt[d][lane];
      s0 += kd * Qs[ua & 7][d];
    }
    s0 *= 0.125f;
    if (hasA) {
      float tm = s0;
#pragma unroll
      for (int o = 32; o >= 1; o >>= 1) tm = fmaxf(tm, __shfl_xor(tm, o, 64));
      float nm = fmaxf(m0, tm);
      float alpha = expf(m0 - nm);
      float p = expf(s0 - nm);
      float tsum = p;
#pragma unroll
      for (int o = 32; o >= 1; o >>= 1) tsum += __shfl_xor(tsum, o, 64);
      l0 = l0 * alpha + tsum;
      m0 = nm;
      ps[ua][lane] = p;
      o0 *= alpha;
#pragma unroll 16
      for (int j = 0; j < 64; ++j) o0 += ps[ua][j] * Vs[j][lane];
    }
    __syncthreads();
  }
  int b = bh / H_, h = bh - b * H_;
  if (hasA) {
    size_t i = ((size_t)b * L + lst[ua]) * DM + h * DH + lane;
    split3(o0 / l0, OP0, OP1, OP2, i);
  }
}

// ---------------- x = LayerNorm(x) in place (+optional fused plane split) ----------------
__global__ void ln_kernel(float* __restrict__ X, const float* __restrict__ g,
                          const float* __restrict__ be, short* __restrict__ P0,
                          short* __restrict__ P1, short* __restrict__ P2) {
  __shared__ float red[256];
  int row = blockIdx.x, tid = threadIdx.x;
  size_t base = (size_t)row * DM;
  float t0 = X[base + tid];
  float t1 = X[base + tid + 256];
  red[tid] = t0 + t1;
  __syncthreads();
  for (int s = 128; s >= 1; s >>= 1) { if (tid < s) red[tid] += red[tid + s]; __syncthreads(); }
  float mu = red[0] / 512.0f;
  __syncthreads();
  float d0 = t0 - mu, d1 = t1 - mu;
  red[tid] = d0 * d0 + d1 * d1;
  __syncthreads();
  for (int s = 128; s >= 1; s >>= 1) { if (tid < s) red[tid] += red[tid + s]; __syncthreads(); }
  float rstd = 1.0f / sqrtf(red[0] / 512.0f + 1e-5f);
  float v0 = d0 * rstd * g[tid] + be[tid];
  float v1 = d1 * rstd * g[tid + 256] + be[tid + 256];
  X[base + tid] = v0;
  X[base + tid + 256] = v1;
  if (P0) {
    split3(v0, P0, P1, P2, base + tid);
    split3(v1, P0, P1, P2, base + tid + 256);
  }
}

// ---------------- maxpool k=3 s=2 pad=1 along L (+fused plane split) ----------------
__global__ void pool_kernel(const float* __restrict__ Y, float* __restrict__ X, int L2,
                            short* __restrict__ P0, short* __restrict__ P1,
                            short* __restrict__ P2) {
  int i = blockIdx.x * 256 + threadIdx.x;
  int c = i % DM;
  int t = (i / DM) % L2;
  int b = i / (DM * L2);
  int L = L2 * 2;
  const float* yb = Y + (size_t)b * L * DM + c;
  float m = fmaxf(yb[(size_t)(2 * t) * DM], yb[(size_t)(2 * t + 1) * DM]);
  if (t > 0) m = fmaxf(m, yb[(size_t)(2 * t - 1) * DM]);
  X[i] = m;
  split3(m, P0, P1, P2, (size_t)i);
}

// ---------------- column max, 2-stage ----------------
__global__ void colmax1_kernel(const float* __restrict__ X, float* __restrict__ P, int L) {
  int nlc = L >> 6;
  int bl = blockIdx.x;
  int b = bl / nlc, lc = bl % nlc;
  const float* xb = X + ((size_t)b * L + lc * 64) * DM;
  for (int c = threadIdx.x; c < DM; c += 256) {
    float m = -1e30f;
    for (int r = 0; r < 64; ++r) m = fmaxf(m, xb[(size_t)r * DM + c]);
    P[((size_t)b * nlc + lc) * DM + c] = m;
  }
}
__global__ void colmax2_kernel(const float* __restrict__ P, float* __restrict__ mc, int nlc) {
  int i = blockIdx.x * 256 + threadIdx.x;
  int b = i / DM, c = i % DM;
  float m = -1e30f;
  for (int lc = 0; lc < nlc; ++lc) m = fmaxf(m, P[((size_t)b * nlc + lc) * DM + c]);
  mc[i] = m;
}

// ---------------- final projection ----------------
__global__ void proj_kernel(const float* __restrict__ mc, const float* __restrict__ pw,
                            const float* __restrict__ pb, float* __restrict__ out) {
  __shared__ float red[256];
  int bo = blockIdx.x, b = bo / COUT, o = bo % COUT, tid = threadIdx.x;
  float s = mc[b * DM + tid] * pw[o * DM + tid] +
            mc[b * DM + tid + 256] * pw[o * DM + tid + 256];
  red[tid] = s;
  __syncthreads();
  for (int st = 128; st >= 1; st >>= 1) { if (tid < st) red[tid] += red[tid + st]; __syncthreads(); }
  if (tid == 0) out[bo] = red[0] + pb[o];
}

extern "C" void kernel_launch(void* const* d_in, const int* in_sizes, int n_in,
                              void* d_out, int out_size, void* d_ws, size_t ws_size,
                              hipStream_t stream) {
  (void)in_sizes; (void)n_in; (void)out_size;
  const float* xe   = (const float*)d_in[0];
  const float* tw   = (const float*)d_in[1];
  const float* Wq   = (const float*)d_in[2];
  const float* Wk   = (const float*)d_in[3];
  const float* Wv   = (const float*)d_in[4];
  const float* Wo   = (const float*)d_in[5];
  const float* bq   = (const float*)d_in[6];
  const float* bk   = (const float*)d_in[7];
  const float* bv   = (const float*)d_in[8];
  const float* bo   = (const float*)d_in[9];
  const float* W1   = (const float*)d_in[10];
  const float* b1   = (const float*)d_in[11];
  const float* W2   = (const float*)d_in[12];
  const float* b2   = (const float*)d_in[13];
  const float* ln1g = (const float*)d_in[14];
  const float* ln1b = (const float*)d_in[15];
  const float* ln2g = (const float*)d_in[16];
  const float* ln2b = (const float*)d_in[17];
  const float* dcw  = (const float*)d_in[18];
  const float* dcb  = (const float*)d_in[19];
  const float* bng  = (const float*)d_in[20];
  const float* bnb  = (const float*)d_in[21];
  const float* lnfg = (const float*)d_in[22];
  const float* lnfb = (const float*)d_in[23];
  const float* pw   = (const float*)d_in[24];
  const float* pb   = (const float*)d_in[25];
  float* out = (float*)d_out;

  float* Wf = (float*)d_ws;
  const size_t NB  = (size_t)B_ * LMAX * DM;             // 8,388,608 floats
  const size_t NHB = (size_t)H_ * LMAX * DH;             // 1,048,576 floats
  const size_t S_IDX = 81920, S_MV = 131072, S_TOP = 4096, S_VM = 4096,
               S_MC = 4096, S_BC = 2048, S_P = 32768;
  const size_t PLANE  = (size_t)512 * 1536;              // weight plane (shorts)
  const size_t APLANE = NB;                              // activation plane (shorts)
  const size_t S_WP = 3 * PLANE / 2 + 1024;              // floats
  const size_t S_AP = 3 * APLANE / 2 + 1024;             // floats
  const size_t SMALL = S_IDX + S_MV + S_TOP + S_VM + S_MC + S_BC + S_P + S_WP + S_AP + 1024;

  int g = 8;
  while (g > 1 && (2 * NB + 3 * (size_t)g * NHB + SMALL) * 4 > ws_size) g >>= 1;

  float* X  = Wf;
  float* T  = X + NB;
  float* Q  = T + NB;
  float* K  = Q + (size_t)g * NHB;
  float* V  = K + (size_t)g * NHB;
  float* SM = V + (size_t)g * NHB;
  int*   IDX = (int*)SM;
  float* Mv  = SM + S_IDX;
  int*   TOP = (int*)(Mv + S_MV);
  float* VM  = Mv + S_MV + S_TOP;
  float* MC  = VM + S_VM;
  float* BCAT = MC + S_MC;
  float* P   = BCAT + S_BC;
  short* WP0 = (short*)(P + S_P);
  short* WP1 = WP0 + PLANE;
  short* WP2 = WP1 + PLANE;
  short* AP0 = (short*)((float*)(P + S_P) + S_WP);
  short* AP1 = AP0 + APLANE;
  short* AP2 = AP1 + APLANE;

  // embed writes X f32 + X-planes (fused split for layer-0 QKV inputs)
  embed_kernel<<<B_ * LMAX * DM / 256, 256, 0, stream>>>(xe, tw, X, AP0, AP1, AP2);

  int L = LMAX;
  for (int i = 0; i < 3; ++i) {
    int U = (i == 0) ? 40 : 35;
    size_t wOff = (size_t)i * DM * DM;
    int ng = B_ / g;
    int nch = (U + 7) >> 3;
    const int NW = DM * DM;

    idx_kernel<<<(L * U + 255) / 256, 256, 0, stream>>>(IDX, L, U, i);

    for (int gb = 0; gb < ng; ++gb) {
      size_t aoff = (size_t)gb * g * L * DM;
      // merged QKV: weight planes [1536][512], bias concat, one GEMM
      bcat_kernel<<<6, 256, 0, stream>>>(bq + i * DM, bk + i * DM, bv + i * DM, BCAT);
      wsplit_kernel<<<NW / 256, 256, 0, stream>>>(Wq + wOff, WP0, WP1, WP2, NW);
      wsplit_kernel<<<NW / 256, 256, 0, stream>>>(Wk + wOff, WP0 + NW, WP1 + NW,
                                                  WP2 + NW, NW);
      wsplit_kernel<<<NW / 256, 256, 0, stream>>>(Wv + wOff, WP0 + 2 * NW, WP1 + 2 * NW,
                                                  WP2 + 2 * NW, NW);
      dim3 gq3(1536 / 128, g * L / 128);
      mgemm<0, 1, 0, 0, 0><<<gq3, 256, 0, stream>>>(
          AP0 + aoff, AP1 + aoff, AP2 + aoff, WP0, WP1, WP2, BCAT, nullptr, nullptr,
          Q, (long)((size_t)g * NHB), L, DM);
      if (U == 40) qkM_t<40><<<g * H_ * L / 4, 256, 0, stream>>>(Q, K, IDX, Mv, L);
      else         qkM_t<35><<<g * H_ * L / 4, 256, 0, stream>>>(Q, K, IDX, Mv, L);
      topk_kernel<<<g * H_, 256, 0, stream>>>(Mv, TOP, L, U);
      vmean_kernel<<<g * H_, 256, 0, stream>>>(V, VM, L);
      fill_kernel<<<(unsigned)((size_t)g * L * DM / 256), 256, 0, stream>>>(
          VM, AP0 + aoff, AP1 + aoff, AP2 + aoff, L);
      attn_fused<<<g * H_ * nch, 512, 0, stream>>>(Q, K, V, TOP, AP0 + aoff,
                                                   AP1 + aoff, AP2 + aoff, L, U);
    }

    int Mf = B_ * L * DM;
    dim3 gf(DM / 128, B_ * L / 128);
    // Wo: A = ctx planes (fill/attn fused split)
    wsplit_kernel<<<NW / 256, 256, 0, stream>>>(Wo + wOff, WP0, WP1, WP2, NW);
    mgemm<0, 0, 1, 0, 0><<<gf, 256, 0, stream>>>(AP0, AP1, AP2, WP0, WP1, WP2,
                                                 bo + i * DM, nullptr, nullptr,
                                                 X, 0, L, DM);
    // ln1 fused: writes X + X-planes for FF1
    ln_kernel<<<B_ * L, 256, 0, stream>>>(X, ln1g + i * DM, ln1b + i * DM, AP0, AP1, AP2);
    wsplit_kernel<<<NW / 256, 256, 0, stream>>>(W1 + wOff, WP0, WP1, WP2, NW);
    mgemm<1, 0, 0, 0, 0><<<gf, 256, 0, stream>>>(AP0, AP1, AP2, WP0, WP1, WP2,
                                                 b1 + i * DM, nullptr, nullptr,
                                                 T, 0, L, DM);
    // split gelu output (can't fuse: reads+writes same plane buffers)
    wsplit_kernel<<<Mf / 256, 256, 0, stream>>>(T, AP0, AP1, AP2, Mf);
    wsplit_kernel<<<NW / 256, 256, 0, stream>>>(W2 + wOff, WP0, WP1, WP2, NW);
    mgemm<0, 0, 1, 0, 0><<<gf, 256, 0, stream>>>(AP0, AP1, AP2, WP0, WP1, WP2,
                                                 b2 + i * DM, nullptr, nullptr,
                                                 X, 0, L, DM);
    if (i < 2) {
      // ln2 fused: planes for conv input
      ln_kernel<<<B_ * L, 256, 0, stream>>>(X, ln2g + i * DM, ln2b + i * DM, AP0, AP1, AP2);
      wt3_kernel<<<DM * 1536 / 256, 256, 0, stream>>>(dcw + (size_t)i * DM * DM * 3,
                                                      WP0, WP1, WP2);
      // conv GEMM with fused BN+ELU epilogue (bias arg = conv bias)
      mgemm<0, 0, 0, 1, 1><<<gf, 256, 0, stream>>>(AP0, AP1, AP2, WP0, WP1, WP2,
                                                   dcb + i * DM, bng + i * DM,
                                                   bnb + i * DM, T, 0, L, 1536);
      L >>= 1;
      // pool fused: writes X + X-planes for next layer's QKV
      pool_kernel<<<B_ * L * DM / 256, 256, 0, stream>>>(T, X, L, AP0, AP1, AP2);
    } else {
      ln_kernel<<<B_ * L, 256, 0, stream>>>(X, ln2g + i * DM, ln2b + i * DM,
                                            nullptr, nullptr, nullptr);
    }
  }

  ln_kernel<<<B_ * L, 256, 0, stream>>>(X, lnfg, lnfb, nullptr, nullptr, nullptr);
  colmax1_kernel<<<B_ * (L >> 6), 256, 0, stream>>>(X, P, L);
  colmax2_kernel<<<B_ * DM / 256, 256, 0, stream>>>(P, MC, L >> 6);
  proj_kernel<<<B_ * COUT, 256, 0, stream>>>(MC, pw, pb, out);
}

// Round 7
// 2134.634 us; speedup vs baseline: 1.1233x; 1.0151x over previous
//
#include <hip/hip_runtime.h>

#define B_ 8
#define H_ 8
#define DM 512
#define DH 64
#define LMAX 2048
#define COUT 2

typedef __attribute__((ext_vector_type(8))) short frag8;
typedef __attribute__((ext_vector_type(4))) float f32x4;

typedef __attribute__((address_space(1))) const unsigned int guint;
typedef __attribute__((address_space(3))) unsigned int luint;
__device__ __forceinline__ void dma16(const short* g, short* l) {
  __builtin_amdgcn_global_load_lds((guint*)g, (luint*)l, 16, 0, 0);
}

__device__ __forceinline__ short f2bf(float v) {
  unsigned u = __float_as_uint(v);
  unsigned r = (u + 0x7fffu + ((u >> 16) & 1u)) >> 16;   // RNE
  return (short)r;
}
__device__ __forceinline__ float bf2f(short s) {
  return __uint_as_float(((unsigned)(unsigned short)s) << 16);
}
// bf16x3 split of one f32 value — identical chain everywhere (bitwise-same planes)
__device__ __forceinline__ void split3(float v, short* p0, short* p1, short* p2, size_t i) {
  short h0 = f2bf(v);
  float r1 = v - bf2f(h0);
  short h1 = f2bf(r1);
  float r2 = r1 - bf2f(h1);
  p0[i] = h0; p1[i] = h1; p2[i] = f2bf(r2);
}

// ---------------- JAX threefry2x32 ----------------
__device__ __forceinline__ void tf2x32(unsigned k0, unsigned k1, unsigned x0, unsigned x1,
                                       unsigned& o0, unsigned& o1) {
  unsigned ks2 = k0 ^ k1 ^ 0x1BD11BDAu;
  x0 += k0; x1 += k1;
#define RND(r) { x0 += x1; x1 = (x1 << r) | (x1 >> (32 - r)); x1 ^= x0; }
  RND(13) RND(15) RND(26) RND(6)  x0 += k1;  x1 += ks2 + 1u;
  RND(17) RND(29) RND(16) RND(24) x0 += ks2; x1 += k0 + 2u;
  RND(13) RND(15) RND(26) RND(6)  x0 += k0;  x1 += k1 + 3u;
  RND(17) RND(29) RND(16) RND(24) x0 += k1;  x1 += ks2 + 4u;
  RND(13) RND(15) RND(26) RND(6)  x0 += ks2; x1 += k0 + 5u;
#undef RND
  o0 = x0; o1 = x1;
}

// VERIFIED (R7, absmax 0.0): Variant B partitionable. DO NOT TOUCH.
__global__ void idx_kernel(int* __restrict__ idxArr, int L, int U, int layer) {
  int p = blockIdx.x * 256 + threadIdx.x;
  int half = L * U;
  if (p >= half) return;
  unsigned fk0, fk1, k20, k21, o0, o1;
  tf2x32(0u, 42u, 0u, (unsigned)layer, fk0, fk1);
  tf2x32(fk0, fk1, 0u, 1u, k20, k21);
  tf2x32(k20, k21, 0u, (unsigned)p, o0, o1);
  idxArr[p] = (int)((o0 ^ o1) & (unsigned)(L - 1));
}

// ---------------- token embed + positional encoding (+fused X-plane split) ----------------
__global__ void embed_kernel(const float* __restrict__ xe, const float* __restrict__ tw,
                             float* __restrict__ X, short* __restrict__ P0,
                             short* __restrict__ P1, short* __restrict__ P2) {
  int i = blockIdx.x * 256 + threadIdx.x;
  int c = i % DM;
  int l = (i / DM) % LMAX;
  int b = i / (DM * LMAX);
  int lm = (l + LMAX - 1) & (LMAX - 1);
  int lp = (l + 1) & (LMAX - 1);
  const float* xb = xe + b * LMAX;
  float tok = tw[c * 3 + 0] * xb[lm] + tw[c * 3 + 1] * xb[l] + tw[c * 3 + 2] * xb[lp];
  float freq = expf(-(float)(c & ~1) * (9.210340371976184f / 512.0f));
  float ang = (float)l * freq;
  float pe = (c & 1) ? cosf(ang) : sinf(ang);
  float v = tok + pe;
  X[i] = v;
  split3(v, P0, P1, P2, (size_t)i);
}

// ---------------- split f32 -> 3 bf16 planes (Wo/W1/W2 weights) ----------------
__global__ void wsplit_kernel(const float* __restrict__ W, short* __restrict__ P0,
                              short* __restrict__ P1, short* __restrict__ P2, int n) {
  int i = blockIdx.x * 256 + threadIdx.x;
  if (i >= n) return;
  split3(W[i], P0, P1, P2, (size_t)i);
}

// R7: merged QKV weight split + bias concat (was bcat + 3 wsplits)
__global__ void wqkv_kernel(const float* __restrict__ Wq, const float* __restrict__ Wk,
                            const float* __restrict__ Wv, const float* __restrict__ bq,
                            const float* __restrict__ bk, const float* __restrict__ bv,
                            short* __restrict__ P0, short* __restrict__ P1,
                            short* __restrict__ P2, float* __restrict__ bcat) {
  int i = blockIdx.x * 256 + threadIdx.x;   // 3*512*512
  int n = i >> 9, k = i & 511;              // n in [0,1536)
  int sel = n >> 9, nn = n & 511;
  const float* W = sel == 0 ? Wq : sel == 1 ? Wk : Wv;
  split3(W[(size_t)nn * 512 + k], P0, P1, P2, (size_t)i);
  if (i < 1536) {
    const float* bs = i < 512 ? bq : i < 1024 ? bk : bv;
    bcat[i] = bs[i & 511];
  }
}

// conv weight transpose + split: Pt[n][tap*512+k] = split(w[n][k][tap])
__global__ void wt3_kernel(const float* __restrict__ w, short* __restrict__ P0,
                           short* __restrict__ P1, short* __restrict__ P2) {
  int i = blockIdx.x * 256 + threadIdx.x;   // 512*1536
  int n = i / 1536, r = i - n * 1536, tap = r >> 9, k = r & 511;
  float v = w[((size_t)n * DM + k) * 3 + tap];
  split3(v, P0, P1, P2, (size_t)i);
}

// ---------------- bf16x3-split MFMA GEMM, DMA staging (m97-style) ----------------
// BM=BN=128, BK=32, 4 waves (2x2 of 64x64). 6 of 9 products. Per-acc MFMA chain
// order is FIXED (bitwise contract). SOUT=1: epilogue writes bf16x3 planes
// (fused wsplit of gelu output) instead of f32 C.
template <int ACT, int QKV, int ACC, int CONV, int BN, int SOUT>
__global__ __launch_bounds__(256) void mgemm(const short* __restrict__ A0g,
                                             const short* __restrict__ A1g,
                                             const short* __restrict__ A2g,
                                             const short* __restrict__ W0g,
                                             const short* __restrict__ W1g,
                                             const short* __restrict__ W2g,
                                             const float* __restrict__ bias,
                                             const float* __restrict__ bng,
                                             const float* __restrict__ bnbe,
                                             short* __restrict__ OP0,
                                             short* __restrict__ OP1,
                                             short* __restrict__ OP2,
                                             float* __restrict__ C, long qs,
                                             int L, int Ktot) {
  __shared__ short A0[128 * 32], A1[128 * 32], A2[128 * 32];
  __shared__ short B0[128 * 32], B1[128 * 32], B2[128 * 32];
  int tid = threadIdx.x;
  int lane = tid & 63, wave = tid >> 6;
  int crow = lane >> 2, ckq = lane & 3;     // DMA: 16 rows x 4 k-groups per chunk
  // XCD-aware swizzle: each XCD gets one m-row phase, iterating n fastest.
  int gx = gridDim.x;
  int flat = blockIdx.y * gx + blockIdx.x;
  int mB, nB;
  if ((gridDim.y & 7) == 0) {
    int phase = flat & 7, sup = flat >> 3;
    nB = sup % gx;
    mB = phase + 8 * (sup / gx);
  } else {
    nB = blockIdx.x; mB = blockIdx.y;
  }
  int n0 = nB * 128, m0 = mB * 128;
  int wm = (wave >> 1) * 64, wn = (wave & 1) * 64;
  f32x4 acc[4][4] = {};
  int lrow = lane & 15, lq = lane >> 4;

  for (int k0 = 0; k0 < Ktot; k0 += 32) {
    int tap = 0, kcol = k0;
    if (CONV) { tap = k0 >> 9; kcol = k0 & 511; }
#pragma unroll
    for (int q = 0; q < 6; ++q) {
      int gc = wave * 6 + q;               // 0..23
      int pl = gc >> 3, c = gc & 7;
      int grow = m0 + c * 16 + crow;
      const short* gp;
      if (CONV) {
        int b = grow / L, l = grow - b * L;
        int le = l + tap - 1;
        le = (le < 0) ? le + L : (le >= L ? le - L : le);
        gp = ((size_t)(b * L + le) * DM + kcol + ckq * 8) +
             (pl == 0 ? A0g : pl == 1 ? A1g : A2g);
      } else {
        gp = ((size_t)grow * DM + k0 + ckq * 8) +
             (pl == 0 ? A0g : pl == 1 ? A1g : A2g);
      }
      short* lp = (pl == 0 ? A0 : pl == 1 ? A1 : A2) + c * 512;
      dma16(gp, lp);
    }
#pragma unroll
    for (int q = 0; q < 6; ++q) {
      int gc = wave * 6 + q;
      int pl = gc >> 3, c = gc & 7;
      int grow = n0 + c * 16 + crow;
      const short* gp = ((size_t)grow * Ktot + k0 + ckq * 8) +
                        (pl == 0 ? W0g : pl == 1 ? W1g : W2g);
      short* lp = (pl == 0 ? B0 : pl == 1 ? B1 : B2) + c * 512;
      dma16(gp, lp);
    }
    __syncthreads();
    frag8 a0f[4], a1f[4], a2f[4];
#pragma unroll
    for (int ti = 0; ti < 4; ++ti) {
      int off = (wm + ti * 16 + lrow) * 32 + lq * 8;
      a0f[ti] = *(const frag8*)&A0[off];
      a1f[ti] = *(const frag8*)&A1[off];
      a2f[ti] = *(const frag8*)&A2[off];
    }
#pragma unroll
    for (int tj = 0; tj < 4; ++tj) {
      int off = (wn + tj * 16 + lrow) * 32 + lq * 8;
      frag8 b0 = *(const frag8*)&B0[off];
      frag8 b1 = *(const frag8*)&B1[off];
      frag8 b2 = *(const frag8*)&B2[off];
#pragma unroll
      for (int ti = 0; ti < 4; ++ti) {
        f32x4 ac = acc[ti][tj];
        ac = __builtin_amdgcn_mfma_f32_16x16x32_bf16(a1f[ti], b1, ac, 0, 0, 0);
        ac = __builtin_amdgcn_mfma_f32_16x16x32_bf16(a0f[ti], b2, ac, 0, 0, 0);
        ac = __builtin_amdgcn_mfma_f32_16x16x32_bf16(a2f[ti], b0, ac, 0, 0, 0);
        ac = __builtin_amdgcn_mfma_f32_16x16x32_bf16(a0f[ti], b1, ac, 0, 0, 0);
        ac = __builtin_amdgcn_mfma_f32_16x16x32_bf16(a1f[ti], b0, ac, 0, 0, 0);
        ac = __builtin_amdgcn_mfma_f32_16x16x32_bf16(a0f[ti], b0, ac, 0, 0, 0);
        acc[ti][tj] = ac;
      }
    }
    __syncthreads();
  }
  // epilogue: C/D map col=lane&15, row=(lane>>4)*4+reg
#pragma unroll
  for (int ti = 0; ti < 4; ++ti) {
#pragma unroll
    for (int tj = 0; tj < 4; ++tj) {
#pragma unroll
      for (int r = 0; r < 4; ++r) {
        int row = m0 + wm + ti * 16 + lq * 4 + r;
        int col = n0 + wn + tj * 16 + lrow;
        float v = acc[ti][tj][r];
        if (!CONV) v += bias[col];
        if (ACT) v = 0.5f * v * (1.0f + erff(v * 0.70710678118654752f));
        if (BN) {   // fused bnelu (same chain as old bnelu_kernel)
          const float invs = 0.9999950000374997f;  // 1/sqrt(1+1e-5)
          float z = v + bias[col];
          z = z * invs * bng[col] + bnbe[col];
          v = z > 0.f ? z : expm1f(z);
        }
        if (SOUT) {  // fused wsplit of output (same v -> same chain)
          split3(v, OP0, OP1, OP2, (size_t)row * DM + col);
        } else if (QKV) {  // merged: col in [0,1536), sel 0/1/2 -> Q/K/V
          int sel = col >> 9, cc = col & 511;
          int b = row / L, l = row - b * L;
          int h = cc >> 6, d = cc & 63;
          C[(size_t)sel * qs + (((size_t)b * H_ + h) * L + l) * DH + d] = v;
        } else if (ACC) {
          C[(size_t)row * DM + col] += v;
        } else {
          C[(size_t)row * DM + col] = v;
        }
      }
    }
  }
}

// ---------------- qkM: lane=(dchunk,sample), 3 shuffles per 8-sample pass ----------------
// At structural roofline (R1-R3 probes: time invariant to load scheduling =>
// divergent-VMEM lane-issue bound, ~136µs floor + overhead = 164µs). Clean R0.
template <int U>
__global__ void qkM_t(const float* __restrict__ Q, const float* __restrict__ Kd,
                      const int* __restrict__ idxArr, float* __restrict__ Mout, int L) {
  int lane = threadIdx.x & 63, wv = threadIdx.x >> 6;
  int row = blockIdx.x * 4 + wv;
  int l = row % L, bh = row / L;
  int u = lane & 7, dc = lane >> 3;       // sample slot, d-chunk
  const float* Qb = Q + ((size_t)bh * L + l) * DH + dc * 8;
  float4 q0 = *(const float4*)(Qb);
  float4 q1 = *(const float4*)(Qb + 4);
  const float* Kb = Kd + (size_t)bh * L * DH;
  const int* ip = idxArr + l * U;
  const int NP = (U + 7) / 8;
  float mx = -1e30f, sm = 0.f;
#pragma unroll
  for (int p = 0; p < NP; ++p) {
    int s = p * 8 + u;
    bool valid = (s < U);
    int ki = ip[valid ? s : 0];
    const float* kr = Kb + (size_t)ki * DH + dc * 8;
    float4 k0 = *(const float4*)(kr);
    float4 k1 = *(const float4*)(kr + 4);
    float d = q0.x * k0.x + q0.y * k0.y + q0.z * k0.z + q0.w * k0.w +
              q1.x * k1.x + q1.y * k1.y + q1.z * k1.z + q1.w * k1.w;
    d += __shfl_xor(d, 8, 64);
    d += __shfl_xor(d, 16, 64);
    d += __shfl_xor(d, 32, 64);
    if (valid) { mx = fmaxf(mx, d); sm += d; }
  }
#pragma unroll
  for (int o = 1; o <= 4; o <<= 1) {
    mx = fmaxf(mx, __shfl_xor(mx, o, 64));
    sm += __shfl_xor(sm, o, 64);
  }
  if (lane == 0) Mout[row] = mx - sm / (float)U;
}

// ---------------- top-U per bh (shfl argmax; order-independent operator) ----------------
__global__ void topk_kernel(const float* __restrict__ M, int* __restrict__ top, int L, int U) {
  __shared__ float vals[LMAX];
  __shared__ float wvv[4];
  __shared__ int wii[4];
  int bh = blockIdx.x, tid = threadIdx.x, lane = tid & 63, w = tid >> 6;
  for (int j = tid; j < L; j += 256) vals[j] = M[(size_t)bh * L + j];
  __syncthreads();
  for (int u = 0; u < U; ++u) {
    float bv = -1e30f; int bi = L;
    for (int j = tid; j < L; j += 256) {
      float v = vals[j];
      if (v > bv) { bv = v; bi = j; }
    }
#pragma unroll
    for (int o = 32; o >= 1; o >>= 1) {
      float ov = __shfl_xor(bv, o, 64);
      int oi = __shfl_xor(bi, o, 64);
      if (ov > bv || (ov == bv && oi < bi)) { bv = ov; bi = oi; }
    }
    if (lane == 0) { wvv[w] = bv; wii[w] = bi; }
    __syncthreads();
    if (tid == 0) {
#pragma unroll
      for (int k = 1; k < 4; ++k) {
        if (wvv[k] > bv || (wvv[k] == bv && wii[k] < bi)) { bv = wvv[k]; bi = wii[k]; }
      }
      top[bh * U + u] = bi;
      vals[bi] = -1e30f;
    }
    __syncthreads();
  }
}

// ---------------- v mean over L per (bh,d) ----------------
__global__ void vmean_kernel(const float* __restrict__ V, float* __restrict__ VM, int L) {
  __shared__ float red[256];
  int bh = blockIdx.x, tid = threadIdx.x, d = tid & 63, sq = tid >> 6;
  float s = 0.f;
  for (int l = sq; l < L; l += 4) s += V[((size_t)bh * L + l) * DH + d];
  red[tid] = s;
  __syncthreads();
  if (sq == 0) VM[bh * DH + d] = (red[d] + red[d + 64] + red[d + 128] + red[d + 192]) / (float)L;
}

// ---------------- fill ctx planes with v-mean (fused split) ----------------
__global__ void fill_kernel(const float* __restrict__ VM, short* __restrict__ P0,
                            short* __restrict__ P1, short* __restrict__ P2, int L) {
  size_t i = (size_t)blockIdx.x * 256 + threadIdx.x;
  int c = (int)(i % DM);
  int b = (int)(i / ((size_t)L * DM));
  split3(VM[b * DM + c], P0, P1, P2, i);
}

// ---------------- flash-style attention for selected queries ----------------
// R5 structure + R7 T14 register-prefetch: next K/V tile issued into regs right
// after the stage barrier (sched_barrier(0) pins issue before compute), written
// to LDS next iteration. Same bytes, same tile order, same per-tile softmax
// chain -> bitwise identical.
__global__ __launch_bounds__(512) void attn_fused(const float* __restrict__ Q,
                                                  const float* __restrict__ Kd,
                                                  const float* __restrict__ V,
                                                  const int* __restrict__ top,
                                                  short* __restrict__ OP0,
                                                  short* __restrict__ OP1,
                                                  short* __restrict__ OP2,
                                                  int L, int U) {
  __shared__ float Qs[8][64];
  __shared__ float Kt[64][65];
  __shared__ float Vs[64][68];
  __shared__ float ps[8][64];
  __shared__ int lst[8];
  int nch = (U + 7) >> 3;
  int bh = blockIdx.x / nch, ch = blockIdx.x - bh * nch;
  int u0g = ch * 8;
  int qn = U - u0g; if (qn > 8) qn = 8;
  int tid = threadIdx.x, lane = tid & 63, wv = tid >> 6;
  if (tid < qn) lst[tid] = top[bh * U + u0g + tid];
  __syncthreads();
  if (tid < qn * 64) {
    int u = tid >> 6, d = tid & 63;
    Qs[u][d] = Q[((size_t)bh * L + lst[u]) * DH + d];
  }
  __syncthreads();
  int ua = wv;                       // one query per wave
  bool hasA = ua < qn;
  float m0 = -1e30f, l0 = 0.f, o0 = 0.f;
  const float* Kbase = Kd + (size_t)bh * L * DH;
  const float* Vbase = V + (size_t)bh * L * DH;
  int j0 = tid >> 4, d40 = (tid & 15) * 4;
  int j1 = j0 + 32;
  // prologue: prefetch tile 0 into registers
  float4 kra = *(const float4*)(Kbase + (size_t)j0 * DH + d40);
  float4 vra = *(const float4*)(Vbase + (size_t)j0 * DH + d40);
  float4 krb = *(const float4*)(Kbase + (size_t)j1 * DH + d40);
  float4 vrb = *(const float4*)(Vbase + (size_t)j1 * DH + d40);
  for (int t0 = 0; t0 < L; t0 += 64) {
    // write prefetched tile to LDS (prev compute finished at loop-end barrier)
    Kt[d40 + 0][j0] = kra.x; Kt[d40 + 1][j0] = kra.y;
    Kt[d40 + 2][j0] = kra.z; Kt[d40 + 3][j0] = kra.w;
    *(float4*)&Vs[j0][d40] = vra;
    Kt[d40 + 0][j1] = krb.x; Kt[d40 + 1][j1] = krb.y;
    Kt[d40 + 2][j1] = krb.z; Kt[d40 + 3][j1] = krb.w;
    *(float4*)&Vs[j1][d40] = vrb;
    __syncthreads();
    // issue next tile's loads (overlap with compute below)
    if (t0 + 64 < L) {
      kra = *(const float4*)(Kbase + (size_t)(t0 + 64 + j0) * DH + d40);
      vra = *(const float4*)(Vbase + (size_t)(t0 + 64 + j0) * DH + d40);
      krb = *(const float4*)(Kbase + (size_t)(t0 + 64 + j1) * DH + d40);
      vrb = *(const float4*)(Vbase + (size_t)(t0 + 64 + j1) * DH + d40);
    }
    __builtin_amdgcn_sched_barrier(0);
    float s0 = 0.f;
#pragma unroll 16
    for (int d = 0; d < 64; ++d) {
      float kd = Kt[d][lane];
      s0 += kd * Qs[ua & 7][d];
    }
    s0 *= 0.125f;
    if (hasA) {
      float tm = s0;
#pragma unroll
      for (int o = 32; o >= 1; o >>= 1) tm = fmaxf(tm, __shfl_xor(tm, o, 64));
      float nm = fmaxf(m0, tm);
      float alpha = expf(m0 - nm);
      float p = expf(s0 - nm);
      float tsum = p;
#pragma unroll
      for (int o = 32; o >= 1; o >>= 1) tsum += __shfl_xor(tsum, o, 64);
      l0 = l0 * alpha + tsum;
      m0 = nm;
      ps[ua][lane] = p;
      o0 *= alpha;
#pragma unroll 16
      for (int j = 0; j < 64; ++j) o0 += ps[ua][j] * Vs[j][lane];
    }
    __syncthreads();
  }
  int b = bh / H_, h = bh - b * H_;
  if (hasA) {
    size_t i = ((size_t)b * L + lst[ua]) * DM + h * DH + lane;
    split3(o0 / l0, OP0, OP1, OP2, i);
  }
}

// ---------------- x = LayerNorm(x) in place (+optional fused plane split) ----------------
__global__ void ln_kernel(float* __restrict__ X, const float* __restrict__ g,
                          const float* __restrict__ be, short* __restrict__ P0,
                          short* __restrict__ P1, short* __restrict__ P2) {
  __shared__ float red[256];
  int row = blockIdx.x, tid = threadIdx.x;
  size_t base = (size_t)row * DM;
  float t0 = X[base + tid];
  float t1 = X[base + tid + 256];
  red[tid] = t0 + t1;
  __syncthreads();
  for (int s = 128; s >= 1; s >>= 1) { if (tid < s) red[tid] += red[tid + s]; __syncthreads(); }
  float mu = red[0] / 512.0f;
  __syncthreads();
  float d0 = t0 - mu, d1 = t1 - mu;
  red[tid] = d0 * d0 + d1 * d1;
  __syncthreads();
  for (int s = 128; s >= 1; s >>= 1) { if (tid < s) red[tid] += red[tid + s]; __syncthreads(); }
  float rstd = 1.0f / sqrtf(red[0] / 512.0f + 1e-5f);
  float v0 = d0 * rstd * g[tid] + be[tid];
  float v1 = d1 * rstd * g[tid + 256] + be[tid + 256];
  X[base + tid] = v0;
  X[base + tid + 256] = v1;
  if (P0) {
    split3(v0, P0, P1, P2, base + tid);
    split3(v1, P0, P1, P2, base + tid + 256);
  }
}

// ---------------- maxpool k=3 s=2 pad=1 along L (+fused plane split) ----------------
__global__ void pool_kernel(const float* __restrict__ Y, float* __restrict__ X, int L2,
                            short* __restrict__ P0, short* __restrict__ P1,
                            short* __restrict__ P2) {
  int i = blockIdx.x * 256 + threadIdx.x;
  int c = i % DM;
  int t = (i / DM) % L2;
  int b = i / (DM * L2);
  int L = L2 * 2;
  const float* yb = Y + (size_t)b * L * DM + c;
  float m = fmaxf(yb[(size_t)(2 * t) * DM], yb[(size_t)(2 * t + 1) * DM]);
  if (t > 0) m = fmaxf(m, yb[(size_t)(2 * t - 1) * DM]);
  X[i] = m;
  split3(m, P0, P1, P2, (size_t)i);
}

// ---------------- column max, 2-stage ----------------
__global__ void colmax1_kernel(const float* __restrict__ X, float* __restrict__ P, int L) {
  int nlc = L >> 6;
  int bl = blockIdx.x;
  int b = bl / nlc, lc = bl % nlc;
  const float* xb = X + ((size_t)b * L + lc * 64) * DM;
  for (int c = threadIdx.x; c < DM; c += 256) {
    float m = -1e30f;
    for (int r = 0; r < 64; ++r) m = fmaxf(m, xb[(size_t)r * DM + c]);
    P[((size_t)b * nlc + lc) * DM + c] = m;
  }
}
__global__ void colmax2_kernel(const float* __restrict__ P, float* __restrict__ mc, int nlc) {
  int i = blockIdx.x * 256 + threadIdx.x;
  int b = i / DM, c = i % DM;
  float m = -1e30f;
  for (int lc = 0; lc < nlc; ++lc) m = fmaxf(m, P[((size_t)b * nlc + lc) * DM + c]);
  mc[i] = m;
}

// ---------------- final projection ----------------
__global__ void proj_kernel(const float* __restrict__ mc, const float* __restrict__ pw,
                            const float* __restrict__ pb, float* __restrict__ out) {
  __shared__ float red[256];
  int bo = blockIdx.x, b = bo / COUT, o = bo % COUT, tid = threadIdx.x;
  float s = mc[b * DM + tid] * pw[o * DM + tid] +
            mc[b * DM + tid + 256] * pw[o * DM + tid + 256];
  red[tid] = s;
  __syncthreads();
  for (int st = 128; st >= 1; st >>= 1) { if (tid < st) red[tid] += red[tid + st]; __syncthreads(); }
  if (tid == 0) out[bo] = red[0] + pb[o];
}

extern "C" void kernel_launch(void* const* d_in, const int* in_sizes, int n_in,
                              void* d_out, int out_size, void* d_ws, size_t ws_size,
                              hipStream_t stream) {
  (void)in_sizes; (void)n_in; (void)out_size;
  const float* xe   = (const float*)d_in[0];
  const float* tw   = (const float*)d_in[1];
  const float* Wq   = (const float*)d_in[2];
  const float* Wk   = (const float*)d_in[3];
  const float* Wv   = (const float*)d_in[4];
  const float* Wo   = (const float*)d_in[5];
  const float* bq   = (const float*)d_in[6];
  const float* bk   = (const float*)d_in[7];
  const float* bv   = (const float*)d_in[8];
  const float* bo   = (const float*)d_in[9];
  const float* W1   = (const float*)d_in[10];
  const float* b1   = (const float*)d_in[11];
  const float* W2   = (const float*)d_in[12];
  const float* b2   = (const float*)d_in[13];
  const float* ln1g = (const float*)d_in[14];
  const float* ln1b = (const float*)d_in[15];
  const float* ln2g = (const float*)d_in[16];
  const float* ln2b = (const float*)d_in[17];
  const float* dcw  = (const float*)d_in[18];
  const float* dcb  = (const float*)d_in[19];
  const float* bng  = (const float*)d_in[20];
  const float* bnb  = (const float*)d_in[21];
  const float* lnfg = (const float*)d_in[22];
  const float* lnfb = (const float*)d_in[23];
  const float* pw   = (const float*)d_in[24];
  const float* pb   = (const float*)d_in[25];
  float* out = (float*)d_out;

  float* Wf = (float*)d_ws;
  const size_t NB  = (size_t)B_ * LMAX * DM;             // 8,388,608 floats
  const size_t NHB = (size_t)H_ * LMAX * DH;             // 1,048,576 floats
  const size_t S_IDX = 81920, S_MV = 131072, S_TOP = 4096, S_VM = 4096,
               S_MC = 4096, S_BC = 2048, S_P = 32768;
  const size_t PLANE  = (size_t)512 * 1536;              // weight plane (shorts)
  const size_t APLANE = NB;                              // activation plane (shorts)
  const size_t S_WP = 3 * PLANE / 2 + 1024;              // floats
  const size_t S_AP = 3 * APLANE / 2 + 1024;             // floats
  const size_t SMALL = S_IDX + S_MV + S_TOP + S_VM + S_MC + S_BC + S_P + S_WP + S_AP + 1024;

  int g = 8;
  while (g > 1 && (2 * NB + 3 * (size_t)g * NHB + SMALL) * 4 > ws_size) g >>= 1;

  float* X  = Wf;
  float* T  = X + NB;
  float* Q  = T + NB;
  float* K  = Q + (size_t)g * NHB;
  float* V  = K + (size_t)g * NHB;
  float* SM = V + (size_t)g * NHB;
  int*   IDX = (int*)SM;
  float* Mv  = SM + S_IDX;
  int*   TOP = (int*)(Mv + S_MV);
  float* VM  = Mv + S_MV + S_TOP;
  float* MC  = VM + S_VM;
  float* BCAT = MC + S_MC;
  float* P   = BCAT + S_BC;
  short* WP0 = (short*)(P + S_P);
  short* WP1 = WP0 + PLANE;
  short* WP2 = WP1 + PLANE;
  short* AP0 = (short*)((float*)(P + S_P) + S_WP);
  short* AP1 = AP0 + APLANE;
  short* AP2 = AP1 + APLANE;
  // FF1-output planes live in the (dead-after-attn) Q/K/V region: need
  // 3*NB shorts = 50 MB; Q..V span 3*g*NHB floats = 100 MB (g=8). Contiguous.
  short* FP0 = (short*)Q;
  short* FP1 = FP0 + APLANE;
  short* FP2 = FP1 + APLANE;

  // embed writes X f32 + X-planes (fused split for layer-0 QKV inputs)
  embed_kernel<<<B_ * LMAX * DM / 256, 256, 0, stream>>>(xe, tw, X, AP0, AP1, AP2);

  int L = LMAX;
  for (int i = 0; i < 3; ++i) {
    int U = (i == 0) ? 40 : 35;
    size_t wOff = (size_t)i * DM * DM;
    int ng = B_ / g;
    int nch = (U + 7) >> 3;
    const int NW = DM * DM;

    idx_kernel<<<(L * U + 255) / 256, 256, 0, stream>>>(IDX, L, U, i);
    // merged QKV weight split + bias concat
    wqkv_kernel<<<3 * NW / 256, 256, 0, stream>>>(Wq + wOff, Wk + wOff, Wv + wOff,
                                                  bq + i * DM, bk + i * DM, bv + i * DM,
                                                  WP0, WP1, WP2, BCAT);

    for (int gb = 0; gb < ng; ++gb) {
      size_t aoff = (size_t)gb * g * L * DM;
      dim3 gq3(1536 / 128, g * L / 128);
      mgemm<0, 1, 0, 0, 0, 0><<<gq3, 256, 0, stream>>>(
          AP0 + aoff, AP1 + aoff, AP2 + aoff, WP0, WP1, WP2, BCAT, nullptr, nullptr,
          nullptr, nullptr, nullptr, Q, (long)((size_t)g * NHB), L, DM);
      if (U == 40) qkM_t<40><<<g * H_ * L / 4, 256, 0, stream>>>(Q, K, IDX, Mv, L);
      else         qkM_t<35><<<g * H_ * L / 4, 256, 0, stream>>>(Q, K, IDX, Mv, L);
      topk_kernel<<<g * H_, 256, 0, stream>>>(Mv, TOP, L, U);
      vmean_kernel<<<g * H_, 256, 0, stream>>>(V, VM, L);
      fill_kernel<<<(unsigned)((size_t)g * L * DM / 256), 256, 0, stream>>>(
          VM, AP0 + aoff, AP1 + aoff, AP2 + aoff, L);
      attn_fused<<<g * H_ * nch, 512, 0, stream>>>(Q, K, V, TOP, AP0 + aoff,
                                                   AP1 + aoff, AP2 + aoff, L, U);
    }

    dim3 gf(DM / 128, B_ * L / 128);
    // Wo: A = ctx planes (fill/attn fused split)
    wsplit_kernel<<<NW / 256, 256, 0, stream>>>(Wo + wOff, WP0, WP1, WP2, NW);
    mgemm<0, 0, 1, 0, 0, 0><<<gf, 256, 0, stream>>>(AP0, AP1, AP2, WP0, WP1, WP2,
                                                    bo + i * DM, nullptr, nullptr,
                                                    nullptr, nullptr, nullptr, X, 0, L, DM);
    // ln1 fused: writes X + X-planes for FF1
    ln_kernel<<<B_ * L, 256, 0, stream>>>(X, ln1g + i * DM, ln1b + i * DM, AP0, AP1, AP2);
    wsplit_kernel<<<NW / 256, 256, 0, stream>>>(W1 + wOff, WP0, WP1, WP2, NW);
    // FF1: gelu output split directly into FP planes (no T f32, no wsplit(T))
    mgemm<1, 0, 0, 0, 0, 1><<<gf, 256, 0, stream>>>(AP0, AP1, AP2, WP0, WP1, WP2,
                                                    b1 + i * DM, nullptr, nullptr,
                                                    FP0, FP1, FP2, nullptr, 0, L, DM);
    wsplit_kernel<<<NW / 256, 256, 0, stream>>>(W2 + wOff, WP0, WP1, WP2, NW);
    mgemm<0, 0, 1, 0, 0, 0><<<gf, 256, 0, stream>>>(FP0, FP1, FP2, WP0, WP1, WP2,
                                                    b2 + i * DM, nullptr, nullptr,
                                                    nullptr, nullptr, nullptr, X, 0, L, DM);
    if (i < 2) {
      // ln2 fused: planes for conv input
      ln_kernel<<<B_ * L, 256, 0, stream>>>(X, ln2g + i * DM, ln2b + i * DM, AP0, AP1, AP2);
      wt3_kernel<<<DM * 1536 / 256, 256, 0, stream>>>(dcw + (size_t)i * DM * DM * 3,
                                                      WP0, WP1, WP2);
      // conv GEMM with fused BN+ELU epilogue (bias arg = conv bias)
      mgemm<0, 0, 0, 1, 1, 0><<<gf, 256, 0, stream>>>(AP0, AP1, AP2, WP0, WP1, WP2,
                                                      dcb + i * DM, bng + i * DM,
                                                      bnb + i * DM, nullptr, nullptr,
                                                      nullptr, T, 0, L, 1536);
      L >>= 1;
      // pool fused: writes X + X-planes for next layer's QKV
      pool_kernel<<<B_ * L * DM / 256, 256, 0, stream>>>(T, X, L, AP0, AP1, AP2);
    } else {
      ln_kernel<<<B_ * L, 256, 0, stream>>>(X, ln2g + i * DM, ln2b + i * DM,
                                            nullptr, nullptr, nullptr);
    }
  }

  ln_kernel<<<B_ * L, 256, 0, stream>>>(X, lnfg, lnfb, nullptr, nullptr, nullptr);
  colmax1_kernel<<<B_ * (L >> 6), 256, 0, stream>>>(X, P, L);
  colmax2_kernel<<<B_ * DM / 256, 256, 0, stream>>>(P, MC, L >> 6);
  proj_kernel<<<B_ * COUT, 256, 0, stream>>>(MC, pw, pb, out);
}

// Round 8
// 2131.764 us; speedup vs baseline: 1.1248x; 1.0013x over previous
//
#include <hip/hip_runtime.h>

#define B_ 8
#define H_ 8
#define DM 512
#define DH 64
#define LMAX 2048
#define COUT 2

typedef __attribute__((ext_vector_type(8))) short frag8;
typedef __attribute__((ext_vector_type(4))) float f32x4;

typedef __attribute__((address_space(1))) const unsigned int guint;
typedef __attribute__((address_space(3))) unsigned int luint;
__device__ __forceinline__ void dma16(const short* g, short* l) {
  __builtin_amdgcn_global_load_lds((guint*)g, (luint*)l, 16, 0, 0);
}

__device__ __forceinline__ short f2bf(float v) {
  unsigned u = __float_as_uint(v);
  unsigned r = (u + 0x7fffu + ((u >> 16) & 1u)) >> 16;   // RNE
  return (short)r;
}
__device__ __forceinline__ float bf2f(short s) {
  return __uint_as_float(((unsigned)(unsigned short)s) << 16);
}
// bf16x3 split of one f32 value — identical chain everywhere (bitwise-same planes)
__device__ __forceinline__ void split3(float v, short* p0, short* p1, short* p2, size_t i) {
  short h0 = f2bf(v);
  float r1 = v - bf2f(h0);
  short h1 = f2bf(r1);
  float r2 = r1 - bf2f(h1);
  p0[i] = h0; p1[i] = h1; p2[i] = f2bf(r2);
}

// ---------------- JAX threefry2x32 ----------------
__device__ __forceinline__ void tf2x32(unsigned k0, unsigned k1, unsigned x0, unsigned x1,
                                       unsigned& o0, unsigned& o1) {
  unsigned ks2 = k0 ^ k1 ^ 0x1BD11BDAu;
  x0 += k0; x1 += k1;
#define RND(r) { x0 += x1; x1 = (x1 << r) | (x1 >> (32 - r)); x1 ^= x0; }
  RND(13) RND(15) RND(26) RND(6)  x0 += k1;  x1 += ks2 + 1u;
  RND(17) RND(29) RND(16) RND(24) x0 += ks2; x1 += k0 + 2u;
  RND(13) RND(15) RND(26) RND(6)  x0 += k0;  x1 += k1 + 3u;
  RND(17) RND(29) RND(16) RND(24) x0 += k1;  x1 += ks2 + 4u;
  RND(13) RND(15) RND(26) RND(6)  x0 += ks2; x1 += k0 + 5u;
#undef RND
  o0 = x0; o1 = x1;
}

// VERIFIED (R7, absmax 0.0): Variant B partitionable. DO NOT TOUCH.
__global__ void idx_kernel(int* __restrict__ idxArr, int L, int U, int layer) {
  int p = blockIdx.x * 256 + threadIdx.x;
  int half = L * U;
  if (p >= half) return;
  unsigned fk0, fk1, k20, k21, o0, o1;
  tf2x32(0u, 42u, 0u, (unsigned)layer, fk0, fk1);
  tf2x32(fk0, fk1, 0u, 1u, k20, k21);
  tf2x32(k20, k21, 0u, (unsigned)p, o0, o1);
  idxArr[p] = (int)((o0 ^ o1) & (unsigned)(L - 1));
}

// ---------------- token embed + positional encoding (+fused X-plane split) ----------------
__global__ void embed_kernel(const float* __restrict__ xe, const float* __restrict__ tw,
                             float* __restrict__ X, short* __restrict__ P0,
                             short* __restrict__ P1, short* __restrict__ P2) {
  int i = blockIdx.x * 256 + threadIdx.x;
  int c = i % DM;
  int l = (i / DM) % LMAX;
  int b = i / (DM * LMAX);
  int lm = (l + LMAX - 1) & (LMAX - 1);
  int lp = (l + 1) & (LMAX - 1);
  const float* xb = xe + b * LMAX;
  float tok = tw[c * 3 + 0] * xb[lm] + tw[c * 3 + 1] * xb[l] + tw[c * 3 + 2] * xb[lp];
  float freq = expf(-(float)(c & ~1) * (9.210340371976184f / 512.0f));
  float ang = (float)l * freq;
  float pe = (c & 1) ? cosf(ang) : sinf(ang);
  float v = tok + pe;
  X[i] = v;
  split3(v, P0, P1, P2, (size_t)i);
}

// ---------------- split f32 -> 3 bf16 planes (Wo/W1/W2 weights) ----------------
__global__ void wsplit_kernel(const float* __restrict__ W, short* __restrict__ P0,
                              short* __restrict__ P1, short* __restrict__ P2, int n) {
  int i = blockIdx.x * 256 + threadIdx.x;
  if (i >= n) return;
  split3(W[i], P0, P1, P2, (size_t)i);
}

// merged QKV weight split + bias concat
__global__ void wqkv_kernel(const float* __restrict__ Wq, const float* __restrict__ Wk,
                            const float* __restrict__ Wv, const float* __restrict__ bq,
                            const float* __restrict__ bk, const float* __restrict__ bv,
                            short* __restrict__ P0, short* __restrict__ P1,
                            short* __restrict__ P2, float* __restrict__ bcat) {
  int i = blockIdx.x * 256 + threadIdx.x;   // 3*512*512
  int n = i >> 9, k = i & 511;              // n in [0,1536)
  int sel = n >> 9, nn = n & 511;
  const float* W = sel == 0 ? Wq : sel == 1 ? Wk : Wv;
  split3(W[(size_t)nn * 512 + k], P0, P1, P2, (size_t)i);
  if (i < 1536) {
    const float* bs = i < 512 ? bq : i < 1024 ? bk : bv;
    bcat[i] = bs[i & 511];
  }
}

// conv weight transpose + split: Pt[n][tap*512+k] = split(w[n][k][tap])
__global__ void wt3_kernel(const float* __restrict__ w, short* __restrict__ P0,
                           short* __restrict__ P1, short* __restrict__ P2) {
  int i = blockIdx.x * 256 + threadIdx.x;   // 512*1536
  int n = i / 1536, r = i - n * 1536, tap = r >> 9, k = r & 511;
  float v = w[((size_t)n * DM + k) * 3 + tap];
  split3(v, P0, P1, P2, (size_t)i);
}

// ---------------- bf16x3-split MFMA GEMM, DMA staging (m97-style) ----------------
// BM=128, BN=TJ*32, BK=32, 4 waves (2x2). 6 of 9 products. Per-acc MFMA chain
// order is FIXED (bitwise contract) — TJ only changes block/wave->tile mapping.
// R8: TJ=2 (BN=64) variant for small-M layer-2 dispatches (grid 128->256+).
template <int ACT, int QKV, int ACC, int CONV, int BN, int SOUT, int TJ>
__global__ __launch_bounds__(256) void mgemm(const short* __restrict__ A0g,
                                             const short* __restrict__ A1g,
                                             const short* __restrict__ A2g,
                                             const short* __restrict__ W0g,
                                             const short* __restrict__ W1g,
                                             const short* __restrict__ W2g,
                                             const float* __restrict__ bias,
                                             const float* __restrict__ bng,
                                             const float* __restrict__ bnbe,
                                             short* __restrict__ OP0,
                                             short* __restrict__ OP1,
                                             short* __restrict__ OP2,
                                             float* __restrict__ C, long qs,
                                             int L, int Ktot) {
  constexpr int BNCOL = TJ * 32;            // output cols per block
  constexpr int BCH = 3 * TJ / 2;           // B chunks per wave
  __shared__ short A0[128 * 32], A1[128 * 32], A2[128 * 32];
  __shared__ short B0[BNCOL * 32], B1[BNCOL * 32], B2[BNCOL * 32];
  int tid = threadIdx.x;
  int lane = tid & 63, wave = tid >> 6;
  int crow = lane >> 2, ckq = lane & 3;     // DMA: 16 rows x 4 k-groups per chunk
  // XCD-aware swizzle: each XCD gets one m-row phase, iterating n fastest.
  int gx = gridDim.x;
  int flat = blockIdx.y * gx + blockIdx.x;
  int mB, nB;
  if ((gridDim.y & 7) == 0) {
    int phase = flat & 7, sup = flat >> 3;
    nB = sup % gx;
    mB = phase + 8 * (sup / gx);
  } else {
    nB = blockIdx.x; mB = blockIdx.y;
  }
  int n0 = nB * BNCOL, m0 = mB * 128;
  int wm = (wave >> 1) * 64, wn = (wave & 1) * (TJ * 16);
  f32x4 acc[4][TJ] = {};
  int lrow = lane & 15, lq = lane >> 4;

  for (int k0 = 0; k0 < Ktot; k0 += 32) {
    int tap = 0, kcol = k0;
    if (CONV) { tap = k0 >> 9; kcol = k0 & 511; }
#pragma unroll
    for (int q = 0; q < 6; ++q) {
      int gc = wave * 6 + q;               // 0..23
      int pl = gc >> 3, c = gc & 7;
      int grow = m0 + c * 16 + crow;
      const short* gp;
      if (CONV) {
        int b = grow / L, l = grow - b * L;
        int le = l + tap - 1;
        le = (le < 0) ? le + L : (le >= L ? le - L : le);
        gp = ((size_t)(b * L + le) * DM + kcol + ckq * 8) +
             (pl == 0 ? A0g : pl == 1 ? A1g : A2g);
      } else {
        gp = ((size_t)grow * DM + k0 + ckq * 8) +
             (pl == 0 ? A0g : pl == 1 ? A1g : A2g);
      }
      short* lp = (pl == 0 ? A0 : pl == 1 ? A1 : A2) + c * 512;
      dma16(gp, lp);
    }
#pragma unroll
    for (int q = 0; q < BCH; ++q) {
      int gc = wave * BCH + q;             // 0..6*TJ-1
      int pl = gc / (2 * TJ), c = gc % (2 * TJ);
      int grow = n0 + c * 16 + crow;
      const short* gp = ((size_t)grow * Ktot + k0 + ckq * 8) +
                        (pl == 0 ? W0g : pl == 1 ? W1g : W2g);
      short* lp = (pl == 0 ? B0 : pl == 1 ? B1 : B2) + c * 512;
      dma16(gp, lp);
    }
    __syncthreads();
    frag8 a0f[4], a1f[4], a2f[4];
#pragma unroll
    for (int ti = 0; ti < 4; ++ti) {
      int off = (wm + ti * 16 + lrow) * 32 + lq * 8;
      a0f[ti] = *(const frag8*)&A0[off];
      a1f[ti] = *(const frag8*)&A1[off];
      a2f[ti] = *(const frag8*)&A2[off];
    }
#pragma unroll
    for (int tj = 0; tj < TJ; ++tj) {
      int off = (wn + tj * 16 + lrow) * 32 + lq * 8;
      frag8 b0 = *(const frag8*)&B0[off];
      frag8 b1 = *(const frag8*)&B1[off];
      frag8 b2 = *(const frag8*)&B2[off];
#pragma unroll
      for (int ti = 0; ti < 4; ++ti) {
        f32x4 ac = acc[ti][tj];
        ac = __builtin_amdgcn_mfma_f32_16x16x32_bf16(a1f[ti], b1, ac, 0, 0, 0);
        ac = __builtin_amdgcn_mfma_f32_16x16x32_bf16(a0f[ti], b2, ac, 0, 0, 0);
        ac = __builtin_amdgcn_mfma_f32_16x16x32_bf16(a2f[ti], b0, ac, 0, 0, 0);
        ac = __builtin_amdgcn_mfma_f32_16x16x32_bf16(a0f[ti], b1, ac, 0, 0, 0);
        ac = __builtin_amdgcn_mfma_f32_16x16x32_bf16(a1f[ti], b0, ac, 0, 0, 0);
        ac = __builtin_amdgcn_mfma_f32_16x16x32_bf16(a0f[ti], b0, ac, 0, 0, 0);
        acc[ti][tj] = ac;
      }
    }
    __syncthreads();
  }
  // epilogue: C/D map col=lane&15, row=(lane>>4)*4+reg
#pragma unroll
  for (int ti = 0; ti < 4; ++ti) {
#pragma unroll
    for (int tj = 0; tj < TJ; ++tj) {
#pragma unroll
      for (int r = 0; r < 4; ++r) {
        int row = m0 + wm + ti * 16 + lq * 4 + r;
        int col = n0 + wn + tj * 16 + lrow;
        float v = acc[ti][tj][r];
        if (!CONV) v += bias[col];
        if (ACT) v = 0.5f * v * (1.0f + erff(v * 0.70710678118654752f));
        if (BN) {   // fused bnelu (same chain as old bnelu_kernel)
          const float invs = 0.9999950000374997f;  // 1/sqrt(1+1e-5)
          float z = v + bias[col];
          z = z * invs * bng[col] + bnbe[col];
          v = z > 0.f ? z : expm1f(z);
        }
        if (SOUT) {  // fused wsplit of output (same v -> same chain)
          split3(v, OP0, OP1, OP2, (size_t)row * DM + col);
        } else if (QKV) {  // merged: col in [0,1536), sel 0/1/2 -> Q/K/V
          int sel = col >> 9, cc = col & 511;
          int b = row / L, l = row - b * L;
          int h = cc >> 6, d = cc & 63;
          C[(size_t)sel * qs + (((size_t)b * H_ + h) * L + l) * DH + d] = v;
        } else if (ACC) {
          C[(size_t)row * DM + col] += v;
        } else {
          C[(size_t)row * DM + col] = v;
        }
      }
    }
  }
}

// ---------------- qkM: lane=(dchunk,sample), 3 shuffles per 8-sample pass ----------------
// At lane-slot roofline for gathers (R1-R3). R8: XCD-affinity block remap —
// bh % 8 pins to one XCD so its L2 holds that bh's K (FETCH was 3x compulsory).
// Pure index bijection, same rows computed -> bitwise identical.
template <int U>
__global__ void qkM_t(const float* __restrict__ Q, const float* __restrict__ Kd,
                      const int* __restrict__ idxArr, float* __restrict__ Mout, int L) {
  int lane = threadIdx.x & 63, wv = threadIdx.x >> 6;
  int rbPerBh = L >> 2;
  int x = blockIdx.x & 7, s = blockIdx.x >> 3;
  int bh = x + 8 * (s / rbPerBh);
  int l = (s % rbPerBh) * 4 + wv;
  int row = bh * L + l;
  int u = lane & 7, dc = lane >> 3;       // sample slot, d-chunk
  const float* Qb = Q + ((size_t)bh * L + l) * DH + dc * 8;
  float4 q0 = *(const float4*)(Qb);
  float4 q1 = *(const float4*)(Qb + 4);
  const float* Kb = Kd + (size_t)bh * L * DH;
  const int* ip = idxArr + l * U;
  const int NP = (U + 7) / 8;
  float mx = -1e30f, sm = 0.f;
#pragma unroll
  for (int p = 0; p < NP; ++p) {
    int s2 = p * 8 + u;
    bool valid = (s2 < U);
    int ki = ip[valid ? s2 : 0];
    const float* kr = Kb + (size_t)ki * DH + dc * 8;
    float4 k0 = *(const float4*)(kr);
    float4 k1 = *(const float4*)(kr + 4);
    float d = q0.x * k0.x + q0.y * k0.y + q0.z * k0.z + q0.w * k0.w +
              q1.x * k1.x + q1.y * k1.y + q1.z * k1.z + q1.w * k1.w;
    d += __shfl_xor(d, 8, 64);
    d += __shfl_xor(d, 16, 64);
    d += __shfl_xor(d, 32, 64);
    if (valid) { mx = fmaxf(mx, d); sm += d; }
  }
#pragma unroll
  for (int o = 1; o <= 4; o <<= 1) {
    mx = fmaxf(mx, __shfl_xor(mx, o, 64));
    sm += __shfl_xor(sm, o, 64);
  }
  if (lane == 0) Mout[row] = mx - sm / (float)U;
}

// ---------------- top-U per bh (shfl argmax; order-independent operator) ----------------
__global__ void topk_kernel(const float* __restrict__ M, int* __restrict__ top, int L, int U) {
  __shared__ float vals[LMAX];
  __shared__ float wvv[4];
  __shared__ int wii[4];
  int bh = blockIdx.x, tid = threadIdx.x, lane = tid & 63, w = tid >> 6;
  for (int j = tid; j < L; j += 256) vals[j] = M[(size_t)bh * L + j];
  __syncthreads();
  for (int u = 0; u < U; ++u) {
    float bv = -1e30f; int bi = L;
    for (int j = tid; j < L; j += 256) {
      float v = vals[j];
      if (v > bv) { bv = v; bi = j; }
    }
#pragma unroll
    for (int o = 32; o >= 1; o >>= 1) {
      float ov = __shfl_xor(bv, o, 64);
      int oi = __shfl_xor(bi, o, 64);
      if (ov > bv || (ov == bv && oi < bi)) { bv = ov; bi = oi; }
    }
    if (lane == 0) { wvv[w] = bv; wii[w] = bi; }
    __syncthreads();
    if (tid == 0) {
#pragma unroll
      for (int k = 1; k < 4; ++k) {
        if (wvv[k] > bv || (wvv[k] == bv && wii[k] < bi)) { bv = wvv[k]; bi = wii[k]; }
      }
      top[bh * U + u] = bi;
      vals[bi] = -1e30f;
    }
    __syncthreads();
  }
}

// ---------------- v mean over L per (bh,d) ----------------
__global__ void vmean_kernel(const float* __restrict__ V, float* __restrict__ VM, int L) {
  __shared__ float red[256];
  int bh = blockIdx.x, tid = threadIdx.x, d = tid & 63, sq = tid >> 6;
  float s = 0.f;
  for (int l = sq; l < L; l += 4) s += V[((size_t)bh * L + l) * DH + d];
  red[tid] = s;
  __syncthreads();
  if (sq == 0) VM[bh * DH + d] = (red[d] + red[d + 64] + red[d + 128] + red[d + 192]) / (float)L;
}

// ---------------- fill ctx planes with v-mean (fused split) ----------------
__global__ void fill_kernel(const float* __restrict__ VM, short* __restrict__ P0,
                            short* __restrict__ P1, short* __restrict__ P2, int L) {
  size_t i = (size_t)blockIdx.x * 256 + threadIdx.x;
  int c = (int)(i % DM);
  int b = (int)(i / ((size_t)L * DM));
  split3(VM[b * DM + c], P0, P1, P2, i);
}

// ---------------- flash-style attention for selected queries ----------------
// R5 structure + R7 T14 register-prefetch. R8: XCD-affinity remap — the nch
// chunks of one bh are consecutive slots on one XCD (chunks 2..nch stage K/V
// from L2 instead of HBM/L3). Pure block-index bijection -> bitwise identical.
__global__ __launch_bounds__(512) void attn_fused(const float* __restrict__ Q,
                                                  const float* __restrict__ Kd,
                                                  const float* __restrict__ V,
                                                  const int* __restrict__ top,
                                                  short* __restrict__ OP0,
                                                  short* __restrict__ OP1,
                                                  short* __restrict__ OP2,
                                                  int L, int U) {
  __shared__ float Qs[8][64];
  __shared__ float Kt[64][65];
  __shared__ float Vs[64][68];
  __shared__ float ps[8][64];
  __shared__ int lst[8];
  int nch = (U + 7) >> 3;
  int x = blockIdx.x & 7, s = blockIdx.x >> 3;
  int bh = x + 8 * (s / nch);
  int ch = s % nch;
  int u0g = ch * 8;
  int qn = U - u0g; if (qn > 8) qn = 8;
  int tid = threadIdx.x, lane = tid & 63, wv = tid >> 6;
  if (tid < qn) lst[tid] = top[bh * U + u0g + tid];
  __syncthreads();
  if (tid < qn * 64) {
    int u = tid >> 6, d = tid & 63;
    Qs[u][d] = Q[((size_t)bh * L + lst[u]) * DH + d];
  }
  __syncthreads();
  int ua = wv;                       // one query per wave
  bool hasA = ua < qn;
  float m0 = -1e30f, l0 = 0.f, o0 = 0.f;
  const float* Kbase = Kd + (size_t)bh * L * DH;
  const float* Vbase = V + (size_t)bh * L * DH;
  int j0 = tid >> 4, d40 = (tid & 15) * 4;
  int j1 = j0 + 32;
  // prologue: prefetch tile 0 into registers
  float4 kra = *(const float4*)(Kbase + (size_t)j0 * DH + d40);
  float4 vra = *(const float4*)(Vbase + (size_t)j0 * DH + d40);
  float4 krb = *(const float4*)(Kbase + (size_t)j1 * DH + d40);
  float4 vrb = *(const float4*)(Vbase + (size_t)j1 * DH + d40);
  for (int t0 = 0; t0 < L; t0 += 64) {
    // write prefetched tile to LDS (prev compute finished at loop-end barrier)
    Kt[d40 + 0][j0] = kra.x; Kt[d40 + 1][j0] = kra.y;
    Kt[d40 + 2][j0] = kra.z; Kt[d40 + 3][j0] = kra.w;
    *(float4*)&Vs[j0][d40] = vra;
    Kt[d40 + 0][j1] = krb.x; Kt[d40 + 1][j1] = krb.y;
    Kt[d40 + 2][j1] = krb.z; Kt[d40 + 3][j1] = krb.w;
    *(float4*)&Vs[j1][d40] = vrb;
    __syncthreads();
    // issue next tile's loads (overlap with compute below)
    if (t0 + 64 < L) {
      kra = *(const float4*)(Kbase + (size_t)(t0 + 64 + j0) * DH + d40);
      vra = *(const float4*)(Vbase + (size_t)(t0 + 64 + j0) * DH + d40);
      krb = *(const float4*)(Kbase + (size_t)(t0 + 64 + j1) * DH + d40);
      vrb = *(const float4*)(Vbase + (size_t)(t0 + 64 + j1) * DH + d40);
    }
    __builtin_amdgcn_sched_barrier(0);
    float s0 = 0.f;
#pragma unroll 16
    for (int d = 0; d < 64; ++d) {
      float kd = Kt[d][lane];
      s0 += kd * Qs[ua & 7][d];
    }
    s0 *= 0.125f;
    if (hasA) {
      float tm = s0;
#pragma unroll
      for (int o = 32; o >= 1; o >>= 1) tm = fmaxf(tm, __shfl_xor(tm, o, 64));
      float nm = fmaxf(m0, tm);
      float alpha = expf(m0 - nm);
      float p = expf(s0 - nm);
      float tsum = p;
#pragma unroll
      for (int o = 32; o >= 1; o >>= 1) tsum += __shfl_xor(tsum, o, 64);
      l0 = l0 * alpha + tsum;
      m0 = nm;
      ps[ua][lane] = p;
      o0 *= alpha;
#pragma unroll 16
      for (int j = 0; j < 64; ++j) o0 += ps[ua][j] * Vs[j][lane];
    }
    __syncthreads();
  }
  int b = bh / H_, h = bh - b * H_;
  if (hasA) {
    size_t i = ((size_t)b * L + lst[ua]) * DM + h * DH + lane;
    split3(o0 / l0, OP0, OP1, OP2, i);
  }
}

// ---------------- x = LayerNorm(x) in place (+optional fused plane split) ----------------
__global__ void ln_kernel(float* __restrict__ X, const float* __restrict__ g,
                          const float* __restrict__ be, short* __restrict__ P0,
                          short* __restrict__ P1, short* __restrict__ P2) {
  __shared__ float red[256];
  int row = blockIdx.x, tid = threadIdx.x;
  size_t base = (size_t)row * DM;
  float t0 = X[base + tid];
  float t1 = X[base + tid + 256];
  red[tid] = t0 + t1;
  __syncthreads();
  for (int s = 128; s >= 1; s >>= 1) { if (tid < s) red[tid] += red[tid + s]; __syncthreads(); }
  float mu = red[0] / 512.0f;
  __syncthreads();
  float d0 = t0 - mu, d1 = t1 - mu;
  red[tid] = d0 * d0 + d1 * d1;
  __syncthreads();
  for (int s = 128; s >= 1; s >>= 1) { if (tid < s) red[tid] += red[tid + s]; __syncthreads(); }
  float rstd = 1.0f / sqrtf(red[0] / 512.0f + 1e-5f);
  float v0 = d0 * rstd * g[tid] + be[tid];
  float v1 = d1 * rstd * g[tid + 256] + be[tid + 256];
  X[base + tid] = v0;
  X[base + tid + 256] = v1;
  if (P0) {
    split3(v0, P0, P1, P2, base + tid);
    split3(v1, P0, P1, P2, base + tid + 256);
  }
}

// ---------------- maxpool k=3 s=2 pad=1 along L (+fused plane split) ----------------
__global__ void pool_kernel(const float* __restrict__ Y, float* __restrict__ X, int L2,
                            short* __restrict__ P0, short* __restrict__ P1,
                            short* __restrict__ P2) {
  int i = blockIdx.x * 256 + threadIdx.x;
  int c = i % DM;
  int t = (i / DM) % L2;
  int b = i / (DM * L2);
  int L = L2 * 2;
  const float* yb = Y + (size_t)b * L * DM + c;
  float m = fmaxf(yb[(size_t)(2 * t) * DM], yb[(size_t)(2 * t + 1) * DM]);
  if (t > 0) m = fmaxf(m, yb[(size_t)(2 * t - 1) * DM]);
  X[i] = m;
  split3(m, P0, P1, P2, (size_t)i);
}

// ---------------- column max, 2-stage ----------------
__global__ void colmax1_kernel(const float* __restrict__ X, float* __restrict__ P, int L) {
  int nlc = L >> 6;
  int bl = blockIdx.x;
  int b = bl / nlc, lc = bl % nlc;
  const float* xb = X + ((size_t)b * L + lc * 64) * DM;
  for (int c = threadIdx.x; c < DM; c += 256) {
    float m = -1e30f;
    for (int r = 0; r < 64; ++r) m = fmaxf(m, xb[(size_t)r * DM + c]);
    P[((size_t)b * nlc + lc) * DM + c] = m;
  }
}
__global__ void colmax2_kernel(const float* __restrict__ P, float* __restrict__ mc, int nlc) {
  int i = blockIdx.x * 256 + threadIdx.x;
  int b = i / DM, c = i % DM;
  float m = -1e30f;
  for (int lc = 0; lc < nlc; ++lc) m = fmaxf(m, P[((size_t)b * nlc + lc) * DM + c]);
  mc[i] = m;
}

// ---------------- final projection ----------------
__global__ void proj_kernel(const float* __restrict__ mc, const float* __restrict__ pw,
                            const float* __restrict__ pb, float* __restrict__ out) {
  __shared__ float red[256];
  int bo = blockIdx.x, b = bo / COUT, o = bo % COUT, tid = threadIdx.x;
  float s = mc[b * DM + tid] * pw[o * DM + tid] +
            mc[b * DM + tid + 256] * pw[o * DM + tid + 256];
  red[tid] = s;
  __syncthreads();
  for (int st = 128; st >= 1; st >>= 1) { if (tid < st) red[tid] += red[tid + st]; __syncthreads(); }
  if (tid == 0) out[bo] = red[0] + pb[o];
}

extern "C" void kernel_launch(void* const* d_in, const int* in_sizes, int n_in,
                              void* d_out, int out_size, void* d_ws, size_t ws_size,
                              hipStream_t stream) {
  (void)in_sizes; (void)n_in; (void)out_size;
  const float* xe   = (const float*)d_in[0];
  const float* tw   = (const float*)d_in[1];
  const float* Wq   = (const float*)d_in[2];
  const float* Wk   = (const float*)d_in[3];
  const float* Wv   = (const float*)d_in[4];
  const float* Wo   = (const float*)d_in[5];
  const float* bq   = (const float*)d_in[6];
  const float* bk   = (const float*)d_in[7];
  const float* bv   = (const float*)d_in[8];
  const float* bo   = (const float*)d_in[9];
  const float* W1   = (const float*)d_in[10];
  const float* b1   = (const float*)d_in[11];
  const float* W2   = (const float*)d_in[12];
  const float* b2   = (const float*)d_in[13];
  const float* ln1g = (const float*)d_in[14];
  const float* ln1b = (const float*)d_in[15];
  const float* ln2g = (const float*)d_in[16];
  const float* ln2b = (const float*)d_in[17];
  const float* dcw  = (const float*)d_in[18];
  const float* dcb  = (const float*)d_in[19];
  const float* bng  = (const float*)d_in[20];
  const float* bnb  = (const float*)d_in[21];
  const float* lnfg = (const float*)d_in[22];
  const float* lnfb = (const float*)d_in[23];
  const float* pw   = (const float*)d_in[24];
  const float* pb   = (const float*)d_in[25];
  float* out = (float*)d_out;

  float* Wf = (float*)d_ws;
  const size_t NB  = (size_t)B_ * LMAX * DM;             // 8,388,608 floats
  const size_t NHB = (size_t)H_ * LMAX * DH;             // 1,048,576 floats
  const size_t S_IDX = 81920, S_MV = 131072, S_TOP = 4096, S_VM = 4096,
               S_MC = 4096, S_BC = 2048, S_P = 32768;
  const size_t PLANE  = (size_t)512 * 1536;              // weight plane (shorts)
  const size_t APLANE = NB;                              // activation plane (shorts)
  const size_t S_WP = 3 * PLANE / 2 + 1024;              // floats
  const size_t S_AP = 3 * APLANE / 2 + 1024;             // floats
  const size_t SMALL = S_IDX + S_MV + S_TOP + S_VM + S_MC + S_BC + S_P + S_WP + S_AP + 1024;

  int g = 8;
  while (g > 1 && (2 * NB + 3 * (size_t)g * NHB + SMALL) * 4 > ws_size) g >>= 1;

  float* X  = Wf;
  float* T  = X + NB;
  float* Q  = T + NB;
  float* K  = Q + (size_t)g * NHB;
  float* V  = K + (size_t)g * NHB;
  float* SM = V + (size_t)g * NHB;
  int*   IDX = (int*)SM;
  float* Mv  = SM + S_IDX;
  int*   TOP = (int*)(Mv + S_MV);
  float* VM  = Mv + S_MV + S_TOP;
  float* MC  = VM + S_VM;
  float* BCAT = MC + S_MC;
  float* P   = BCAT + S_BC;
  short* WP0 = (short*)(P + S_P);
  short* WP1 = WP0 + PLANE;
  short* WP2 = WP1 + PLANE;
  short* AP0 = (short*)((float*)(P + S_P) + S_WP);
  short* AP1 = AP0 + APLANE;
  short* AP2 = AP1 + APLANE;
  // FF1-output planes live in the (dead-after-attn) Q/K/V region
  short* FP0 = (short*)Q;
  short* FP1 = FP0 + APLANE;
  short* FP2 = FP1 + APLANE;

  // embed writes X f32 + X-planes (fused split for layer-0 QKV inputs)
  embed_kernel<<<B_ * LMAX * DM / 256, 256, 0, stream>>>(xe, tw, X, AP0, AP1, AP2);

  int L = LMAX;
  for (int i = 0; i < 3; ++i) {
    int U = (i == 0) ? 40 : 35;
    size_t wOff = (size_t)i * DM * DM;
    int ng = B_ / g;
    int nch = (U + 7) >> 3;
    const int NW = DM * DM;
    bool small = (B_ * L / 128) < 192;   // layer-2: use BN=64 variant

    idx_kernel<<<(L * U + 255) / 256, 256, 0, stream>>>(IDX, L, U, i);
    // merged QKV weight split + bias concat
    wqkv_kernel<<<3 * NW / 256, 256, 0, stream>>>(Wq + wOff, Wk + wOff, Wv + wOff,
                                                  bq + i * DM, bk + i * DM, bv + i * DM,
                                                  WP0, WP1, WP2, BCAT);

    for (int gb = 0; gb < ng; ++gb) {
      size_t aoff = (size_t)gb * g * L * DM;
      if (small) {
        dim3 gq3(1536 / 64, g * L / 128);
        mgemm<0, 1, 0, 0, 0, 0, 2><<<gq3, 256, 0, stream>>>(
            AP0 + aoff, AP1 + aoff, AP2 + aoff, WP0, WP1, WP2, BCAT, nullptr, nullptr,
            nullptr, nullptr, nullptr, Q, (long)((size_t)g * NHB), L, DM);
      } else {
        dim3 gq3(1536 / 128, g * L / 128);
        mgemm<0, 1, 0, 0, 0, 0, 4><<<gq3, 256, 0, stream>>>(
            AP0 + aoff, AP1 + aoff, AP2 + aoff, WP0, WP1, WP2, BCAT, nullptr, nullptr,
            nullptr, nullptr, nullptr, Q, (long)((size_t)g * NHB), L, DM);
      }
      if (U == 40) qkM_t<40><<<g * H_ * L / 4, 256, 0, stream>>>(Q, K, IDX, Mv, L);
      else         qkM_t<35><<<g * H_ * L / 4, 256, 0, stream>>>(Q, K, IDX, Mv, L);
      topk_kernel<<<g * H_, 256, 0, stream>>>(Mv, TOP, L, U);
      vmean_kernel<<<g * H_, 256, 0, stream>>>(V, VM, L);
      fill_kernel<<<(unsigned)((size_t)g * L * DM / 256), 256, 0, stream>>>(
          VM, AP0 + aoff, AP1 + aoff, AP2 + aoff, L);
      attn_fused<<<g * H_ * nch, 512, 0, stream>>>(Q, K, V, TOP, AP0 + aoff,
                                                   AP1 + aoff, AP2 + aoff, L, U);
    }

    // Wo: A = ctx planes (fill/attn fused split)
    wsplit_kernel<<<NW / 256, 256, 0, stream>>>(Wo + wOff, WP0, WP1, WP2, NW);
    if (small) {
      dim3 gf(DM / 64, B_ * L / 128);
      mgemm<0, 0, 1, 0, 0, 0, 2><<<gf, 256, 0, stream>>>(
          AP0, AP1, AP2, WP0, WP1, WP2, bo + i * DM, nullptr, nullptr,
          nullptr, nullptr, nullptr, X, 0, L, DM);
      ln_kernel<<<B_ * L, 256, 0, stream>>>(X, ln1g + i * DM, ln1b + i * DM, AP0, AP1, AP2);
      wsplit_kernel<<<NW / 256, 256, 0, stream>>>(W1 + wOff, WP0, WP1, WP2, NW);
      mgemm<1, 0, 0, 0, 0, 1, 2><<<gf, 256, 0, stream>>>(
          AP0, AP1, AP2, WP0, WP1, WP2, b1 + i * DM, nullptr, nullptr,
          FP0, FP1, FP2, nullptr, 0, L, DM);
      wsplit_kernel<<<NW / 256, 256, 0, stream>>>(W2 + wOff, WP0, WP1, WP2, NW);
      mgemm<0, 0, 1, 0, 0, 0, 2><<<gf, 256, 0, stream>>>(
          FP0, FP1, FP2, WP0, WP1, WP2, b2 + i * DM, nullptr, nullptr,
          nullptr, nullptr, nullptr, X, 0, L, DM);
    } else {
      dim3 gf(DM / 128, B_ * L / 128);
      mgemm<0, 0, 1, 0, 0, 0, 4><<<gf, 256, 0, stream>>>(
          AP0, AP1, AP2, WP0, WP1, WP2, bo + i * DM, nullptr, nullptr,
          nullptr, nullptr, nullptr, X, 0, L, DM);
      ln_kernel<<<B_ * L, 256, 0, stream>>>(X, ln1g + i * DM, ln1b + i * DM, AP0, AP1, AP2);
      wsplit_kernel<<<NW / 256, 256, 0, stream>>>(W1 + wOff, WP0, WP1, WP2, NW);
      mgemm<1, 0, 0, 0, 0, 1, 4><<<gf, 256, 0, stream>>>(
          AP0, AP1, AP2, WP0, WP1, WP2, b1 + i * DM, nullptr, nullptr,
          FP0, FP1, FP2, nullptr, 0, L, DM);
      wsplit_kernel<<<NW / 256, 256, 0, stream>>>(W2 + wOff, WP0, WP1, WP2, NW);
      mgemm<0, 0, 1, 0, 0, 0, 4><<<gf, 256, 0, stream>>>(
          FP0, FP1, FP2, WP0, WP1, WP2, b2 + i * DM, nullptr, nullptr,
          nullptr, nullptr, nullptr, X, 0, L, DM);
    }
    if (i < 2) {
      // ln2 fused: planes for conv input
      ln_kernel<<<B_ * L, 256, 0, stream>>>(X, ln2g + i * DM, ln2b + i * DM, AP0, AP1, AP2);
      wt3_kernel<<<DM * 1536 / 256, 256, 0, stream>>>(dcw + (size_t)i * DM * DM * 3,
                                                      WP0, WP1, WP2);
      // conv GEMM with fused BN+ELU epilogue (bias arg = conv bias)
      dim3 gf(DM / 128, B_ * L / 128);
      mgemm<0, 0, 0, 1, 1, 0, 4><<<gf, 256, 0, stream>>>(
          AP0, AP1, AP2, WP0, WP1, WP2, dcb + i * DM, bng + i * DM, bnb + i * DM,
          nullptr, nullptr, nullptr, T, 0, L, 1536);
      L >>= 1;
      // pool fused: writes X + X-planes for next layer's QKV
      pool_kernel<<<B_ * L * DM / 256, 256, 0, stream>>>(T, X, L, AP0, AP1, AP2);
    } else {
      ln_kernel<<<B_ * L, 256, 0, stream>>>(X, ln2g + i * DM, ln2b + i * DM,
                                            nullptr, nullptr, nullptr);
    }
  }

  ln_kernel<<<B_ * L, 256, 0, stream>>>(X, lnfg, lnfb, nullptr, nullptr, nullptr);
  colmax1_kernel<<<B_ * (L >> 6), 256, 0, stream>>>(X, P, L);
  colmax2_kernel<<<B_ * DM / 256, 256, 0, stream>>>(P, MC, L >> 6);
  proj_kernel<<<B_ * COUT, 256, 0, stream>>>(MC, pw, pb, out);
}

// Round 9
// 2081.506 us; speedup vs baseline: 1.1520x; 1.0241x over previous
//
#include <hip/hip_runtime.h>

#define B_ 8
#define H_ 8
#define DM 512
#define DH 64
#define LMAX 2048
#define COUT 2

typedef __attribute__((ext_vector_type(8))) short frag8;
typedef __attribute__((ext_vector_type(4))) float f32x4;

typedef __attribute__((address_space(1))) const unsigned int guint;
typedef __attribute__((address_space(3))) unsigned int luint;
__device__ __forceinline__ void dma16(const short* g, short* l) {
  __builtin_amdgcn_global_load_lds((guint*)g, (luint*)l, 16, 0, 0);
}

__device__ __forceinline__ short f2bf(float v) {
  unsigned u = __float_as_uint(v);
  unsigned r = (u + 0x7fffu + ((u >> 16) & 1u)) >> 16;   // RNE
  return (short)r;
}
__device__ __forceinline__ float bf2f(short s) {
  return __uint_as_float(((unsigned)(unsigned short)s) << 16);
}
// bf16x3 split of one f32 value — identical chain everywhere (bitwise-same planes)
__device__ __forceinline__ void split3(float v, short* p0, short* p1, short* p2, size_t i) {
  short h0 = f2bf(v);
  float r1 = v - bf2f(h0);
  short h1 = f2bf(r1);
  float r2 = r1 - bf2f(h1);
  p0[i] = h0; p1[i] = h1; p2[i] = f2bf(r2);
}

// ---------------- JAX threefry2x32 ----------------
__device__ __forceinline__ void tf2x32(unsigned k0, unsigned k1, unsigned x0, unsigned x1,
                                       unsigned& o0, unsigned& o1) {
  unsigned ks2 = k0 ^ k1 ^ 0x1BD11BDAu;
  x0 += k0; x1 += k1;
#define RND(r) { x0 += x1; x1 = (x1 << r) | (x1 >> (32 - r)); x1 ^= x0; }
  RND(13) RND(15) RND(26) RND(6)  x0 += k1;  x1 += ks2 + 1u;
  RND(17) RND(29) RND(16) RND(24) x0 += ks2; x1 += k0 + 2u;
  RND(13) RND(15) RND(26) RND(6)  x0 += k0;  x1 += k1 + 3u;
  RND(17) RND(29) RND(16) RND(24) x0 += k1;  x1 += ks2 + 4u;
  RND(13) RND(15) RND(26) RND(6)  x0 += ks2; x1 += k0 + 5u;
#undef RND
  o0 = x0; o1 = x1;
}

// VERIFIED (R7, absmax 0.0): Variant B partitionable. DO NOT TOUCH.
__global__ void idx_kernel(int* __restrict__ idxArr, int L, int U, int layer) {
  int p = blockIdx.x * 256 + threadIdx.x;
  int half = L * U;
  if (p >= half) return;
  unsigned fk0, fk1, k20, k21, o0, o1;
  tf2x32(0u, 42u, 0u, (unsigned)layer, fk0, fk1);
  tf2x32(fk0, fk1, 0u, 1u, k20, k21);
  tf2x32(k20, k21, 0u, (unsigned)p, o0, o1);
  idxArr[p] = (int)((o0 ^ o1) & (unsigned)(L - 1));
}

// ---------------- token embed + positional encoding (+fused X-plane split) ----------------
__global__ void embed_kernel(const float* __restrict__ xe, const float* __restrict__ tw,
                             float* __restrict__ X, short* __restrict__ P0,
                             short* __restrict__ P1, short* __restrict__ P2) {
  int i = blockIdx.x * 256 + threadIdx.x;
  int c = i % DM;
  int l = (i / DM) % LMAX;
  int b = i / (DM * LMAX);
  int lm = (l + LMAX - 1) & (LMAX - 1);
  int lp = (l + 1) & (LMAX - 1);
  const float* xb = xe + b * LMAX;
  float tok = tw[c * 3 + 0] * xb[lm] + tw[c * 3 + 1] * xb[l] + tw[c * 3 + 2] * xb[lp];
  float freq = expf(-(float)(c & ~1) * (9.210340371976184f / 512.0f));
  float ang = (float)l * freq;
  float pe = (c & 1) ? cosf(ang) : sinf(ang);
  float v = tok + pe;
  X[i] = v;
  split3(v, P0, P1, P2, (size_t)i);
}

// ---------------- split f32 -> 3 bf16 planes (Wo/W1/W2 weights) ----------------
__global__ void wsplit_kernel(const float* __restrict__ W, short* __restrict__ P0,
                              short* __restrict__ P1, short* __restrict__ P2, int n) {
  int i = blockIdx.x * 256 + threadIdx.x;
  if (i >= n) return;
  split3(W[i], P0, P1, P2, (size_t)i);
}

// merged QKV weight split + bias concat
__global__ void wqkv_kernel(const float* __restrict__ Wq, const float* __restrict__ Wk,
                            const float* __restrict__ Wv, const float* __restrict__ bq,
                            const float* __restrict__ bk, const float* __restrict__ bv,
                            short* __restrict__ P0, short* __restrict__ P1,
                            short* __restrict__ P2, float* __restrict__ bcat) {
  int i = blockIdx.x * 256 + threadIdx.x;   // 3*512*512
  int n = i >> 9, k = i & 511;              // n in [0,1536)
  int sel = n >> 9, nn = n & 511;
  const float* W = sel == 0 ? Wq : sel == 1 ? Wk : Wv;
  split3(W[(size_t)nn * 512 + k], P0, P1, P2, (size_t)i);
  if (i < 1536) {
    const float* bs = i < 512 ? bq : i < 1024 ? bk : bv;
    bcat[i] = bs[i & 511];
  }
}

// conv weight transpose + split: Pt[n][tap*512+k] = split(w[n][k][tap])
__global__ void wt3_kernel(const float* __restrict__ w, short* __restrict__ P0,
                           short* __restrict__ P1, short* __restrict__ P2) {
  int i = blockIdx.x * 256 + threadIdx.x;   // 512*1536
  int n = i / 1536, r = i - n * 1536, tap = r >> 9, k = r & 511;
  float v = w[((size_t)n * DM + k) * 3 + tap];
  split3(v, P0, P1, P2, (size_t)i);
}

// ---------------- bf16x3-split MFMA GEMM, DMA staging (m97-style) ----------------
// BM=128, BN=TJ*32, BK=32, 4 waves (2x2). 6 of 9 products. Per-acc MFMA chain
// order is FIXED (bitwise contract) — TJ only changes block/wave->tile mapping.
// R9: TJ=2 restricted to truly small grids (layer-2 Wo/FF: 128 blocks @TJ=4).
// R8's blanket heuristic put QKV on TJ=2 (2x A-traffic) — reverted.
template <int ACT, int QKV, int ACC, int CONV, int BN, int SOUT, int TJ>
__global__ __launch_bounds__(256) void mgemm(const short* __restrict__ A0g,
                                             const short* __restrict__ A1g,
                                             const short* __restrict__ A2g,
                                             const short* __restrict__ W0g,
                                             const short* __restrict__ W1g,
                                             const short* __restrict__ W2g,
                                             const float* __restrict__ bias,
                                             const float* __restrict__ bng,
                                             const float* __restrict__ bnbe,
                                             short* __restrict__ OP0,
                                             short* __restrict__ OP1,
                                             short* __restrict__ OP2,
                                             float* __restrict__ C, long qs,
                                             int L, int Ktot) {
  constexpr int BNCOL = TJ * 32;            // output cols per block
  constexpr int BCH = 3 * TJ / 2;           // B chunks per wave
  __shared__ short A0[128 * 32], A1[128 * 32], A2[128 * 32];
  __shared__ short B0[BNCOL * 32], B1[BNCOL * 32], B2[BNCOL * 32];
  int tid = threadIdx.x;
  int lane = tid & 63, wave = tid >> 6;
  int crow = lane >> 2, ckq = lane & 3;     // DMA: 16 rows x 4 k-groups per chunk
  // XCD-aware swizzle: each XCD gets one m-row phase, iterating n fastest.
  int gx = gridDim.x;
  int flat = blockIdx.y * gx + blockIdx.x;
  int mB, nB;
  if ((gridDim.y & 7) == 0) {
    int phase = flat & 7, sup = flat >> 3;
    nB = sup % gx;
    mB = phase + 8 * (sup / gx);
  } else {
    nB = blockIdx.x; mB = blockIdx.y;
  }
  int n0 = nB * BNCOL, m0 = mB * 128;
  int wm = (wave >> 1) * 64, wn = (wave & 1) * (TJ * 16);
  f32x4 acc[4][TJ] = {};
  int lrow = lane & 15, lq = lane >> 4;

  for (int k0 = 0; k0 < Ktot; k0 += 32) {
    int tap = 0, kcol = k0;
    if (CONV) { tap = k0 >> 9; kcol = k0 & 511; }
#pragma unroll
    for (int q = 0; q < 6; ++q) {
      int gc = wave * 6 + q;               // 0..23
      int pl = gc >> 3, c = gc & 7;
      int grow = m0 + c * 16 + crow;
      const short* gp;
      if (CONV) {
        int b = grow / L, l = grow - b * L;
        int le = l + tap - 1;
        le = (le < 0) ? le + L : (le >= L ? le - L : le);
        gp = ((size_t)(b * L + le) * DM + kcol + ckq * 8) +
             (pl == 0 ? A0g : pl == 1 ? A1g : A2g);
      } else {
        gp = ((size_t)grow * DM + k0 + ckq * 8) +
             (pl == 0 ? A0g : pl == 1 ? A1g : A2g);
      }
      short* lp = (pl == 0 ? A0 : pl == 1 ? A1 : A2) + c * 512;
      dma16(gp, lp);
    }
#pragma unroll
    for (int q = 0; q < BCH; ++q) {
      int gc = wave * BCH + q;             // 0..6*TJ-1
      int pl = gc / (2 * TJ), c = gc % (2 * TJ);
      int grow = n0 + c * 16 + crow;
      const short* gp = ((size_t)grow * Ktot + k0 + ckq * 8) +
                        (pl == 0 ? W0g : pl == 1 ? W1g : W2g);
      short* lp = (pl == 0 ? B0 : pl == 1 ? B1 : B2) + c * 512;
      dma16(gp, lp);
    }
    __syncthreads();
    frag8 a0f[4], a1f[4], a2f[4];
#pragma unroll
    for (int ti = 0; ti < 4; ++ti) {
      int off = (wm + ti * 16 + lrow) * 32 + lq * 8;
      a0f[ti] = *(const frag8*)&A0[off];
      a1f[ti] = *(const frag8*)&A1[off];
      a2f[ti] = *(const frag8*)&A2[off];
    }
#pragma unroll
    for (int tj = 0; tj < TJ; ++tj) {
      int off = (wn + tj * 16 + lrow) * 32 + lq * 8;
      frag8 b0 = *(const frag8*)&B0[off];
      frag8 b1 = *(const frag8*)&B1[off];
      frag8 b2 = *(const frag8*)&B2[off];
#pragma unroll
      for (int ti = 0; ti < 4; ++ti) {
        f32x4 ac = acc[ti][tj];
        ac = __builtin_amdgcn_mfma_f32_16x16x32_bf16(a1f[ti], b1, ac, 0, 0, 0);
        ac = __builtin_amdgcn_mfma_f32_16x16x32_bf16(a0f[ti], b2, ac, 0, 0, 0);
        ac = __builtin_amdgcn_mfma_f32_16x16x32_bf16(a2f[ti], b0, ac, 0, 0, 0);
        ac = __builtin_amdgcn_mfma_f32_16x16x32_bf16(a0f[ti], b1, ac, 0, 0, 0);
        ac = __builtin_amdgcn_mfma_f32_16x16x32_bf16(a1f[ti], b0, ac, 0, 0, 0);
        ac = __builtin_amdgcn_mfma_f32_16x16x32_bf16(a0f[ti], b0, ac, 0, 0, 0);
        acc[ti][tj] = ac;
      }
    }
    __syncthreads();
  }
  // epilogue: C/D map col=lane&15, row=(lane>>4)*4+reg
#pragma unroll
  for (int ti = 0; ti < 4; ++ti) {
#pragma unroll
    for (int tj = 0; tj < TJ; ++tj) {
#pragma unroll
      for (int r = 0; r < 4; ++r) {
        int row = m0 + wm + ti * 16 + lq * 4 + r;
        int col = n0 + wn + tj * 16 + lrow;
        float v = acc[ti][tj][r];
        if (!CONV) v += bias[col];
        if (ACT) v = 0.5f * v * (1.0f + erff(v * 0.70710678118654752f));
        if (BN) {   // fused bnelu (same chain as old bnelu_kernel)
          const float invs = 0.9999950000374997f;  // 1/sqrt(1+1e-5)
          float z = v + bias[col];
          z = z * invs * bng[col] + bnbe[col];
          v = z > 0.f ? z : expm1f(z);
        }
        if (SOUT) {  // fused wsplit of output (same v -> same chain)
          split3(v, OP0, OP1, OP2, (size_t)row * DM + col);
        } else if (QKV) {  // merged: col in [0,1536), sel 0/1/2 -> Q/K/V
          int sel = col >> 9, cc = col & 511;
          int b = row / L, l = row - b * L;
          int h = cc >> 6, d = cc & 63;
          C[(size_t)sel * qs + (((size_t)b * H_ + h) * L + l) * DH + d] = v;
        } else if (ACC) {
          C[(size_t)row * DM + col] += v;
        } else {
          C[(size_t)row * DM + col] = v;
        }
      }
    }
  }
}

// ---------------- qkM: lane=(dchunk,sample), 3 shuffles per 8-sample pass ----------------
// At lane-slot roofline for gathers (R1-R3). R8 XCD-affinity remap kept
// (bh % 8 pins to one XCD -> its L2 holds that bh's K). Bitwise identical.
template <int U>
__global__ void qkM_t(const float* __restrict__ Q, const float* __restrict__ Kd,
                      const int* __restrict__ idxArr, float* __restrict__ Mout, int L) {
  int lane = threadIdx.x & 63, wv = threadIdx.x >> 6;
  int rbPerBh = L >> 2;
  int x = blockIdx.x & 7, s = blockIdx.x >> 3;
  int bh = x + 8 * (s / rbPerBh);
  int l = (s % rbPerBh) * 4 + wv;
  int row = bh * L + l;
  int u = lane & 7, dc = lane >> 3;       // sample slot, d-chunk
  const float* Qb = Q + ((size_t)bh * L + l) * DH + dc * 8;
  float4 q0 = *(const float4*)(Qb);
  float4 q1 = *(const float4*)(Qb + 4);
  const float* Kb = Kd + (size_t)bh * L * DH;
  const int* ip = idxArr + l * U;
  const int NP = (U + 7) / 8;
  float mx = -1e30f, sm = 0.f;
#pragma unroll
  for (int p = 0; p < NP; ++p) {
    int s2 = p * 8 + u;
    bool valid = (s2 < U);
    int ki = ip[valid ? s2 : 0];
    const float* kr = Kb + (size_t)ki * DH + dc * 8;
    float4 k0 = *(const float4*)(kr);
    float4 k1 = *(const float4*)(kr + 4);
    float d = q0.x * k0.x + q0.y * k0.y + q0.z * k0.z + q0.w * k0.w +
              q1.x * k1.x + q1.y * k1.y + q1.z * k1.z + q1.w * k1.w;
    d += __shfl_xor(d, 8, 64);
    d += __shfl_xor(d, 16, 64);
    d += __shfl_xor(d, 32, 64);
    if (valid) { mx = fmaxf(mx, d); sm += d; }
  }
#pragma unroll
  for (int o = 1; o <= 4; o <<= 1) {
    mx = fmaxf(mx, __shfl_xor(mx, o, 64));
    sm += __shfl_xor(sm, o, 64);
  }
  if (lane == 0) Mout[row] = mx - sm / (float)U;
}

// ---------------- top-U per bh (shfl argmax; order-independent operator) ----------------
__global__ void topk_kernel(const float* __restrict__ M, int* __restrict__ top, int L, int U) {
  __shared__ float vals[LMAX];
  __shared__ float wvv[4];
  __shared__ int wii[4];
  int bh = blockIdx.x, tid = threadIdx.x, lane = tid & 63, w = tid >> 6;
  for (int j = tid; j < L; j += 256) vals[j] = M[(size_t)bh * L + j];
  __syncthreads();
  for (int u = 0; u < U; ++u) {
    float bv = -1e30f; int bi = L;
    for (int j = tid; j < L; j += 256) {
      float v = vals[j];
      if (v > bv) { bv = v; bi = j; }
    }
#pragma unroll
    for (int o = 32; o >= 1; o >>= 1) {
      float ov = __shfl_xor(bv, o, 64);
      int oi = __shfl_xor(bi, o, 64);
      if (ov > bv || (ov == bv && oi < bi)) { bv = ov; bi = oi; }
    }
    if (lane == 0) { wvv[w] = bv; wii[w] = bi; }
    __syncthreads();
    if (tid == 0) {
#pragma unroll
      for (int k = 1; k < 4; ++k) {
        if (wvv[k] > bv || (wvv[k] == bv && wii[k] < bi)) { bv = wvv[k]; bi = wii[k]; }
      }
      top[bh * U + u] = bi;
      vals[bi] = -1e30f;
    }
    __syncthreads();
  }
}

// ---------------- v mean over L per (bh,d) ----------------
__global__ void vmean_kernel(const float* __restrict__ V, float* __restrict__ VM, int L) {
  __shared__ float red[256];
  int bh = blockIdx.x, tid = threadIdx.x, d = tid & 63, sq = tid >> 6;
  float s = 0.f;
  for (int l = sq; l < L; l += 4) s += V[((size_t)bh * L + l) * DH + d];
  red[tid] = s;
  __syncthreads();
  if (sq == 0) VM[bh * DH + d] = (red[d] + red[d + 64] + red[d + 128] + red[d + 192]) / (float)L;
}

// ---------------- fill ctx planes with v-mean (fused split) ----------------
__global__ void fill_kernel(const float* __restrict__ VM, short* __restrict__ P0,
                            short* __restrict__ P1, short* __restrict__ P2, int L) {
  size_t i = (size_t)blockIdx.x * 256 + threadIdx.x;
  int c = (int)(i % DM);
  int b = (int)(i / ((size_t)L * DM));
  split3(VM[b * DM + c], P0, P1, P2, i);
}

// ---------------- flash-style attention for selected queries ----------------
// R5 structure + R7 T14 register-prefetch + R8 XCD-affinity remap.
__global__ __launch_bounds__(512) void attn_fused(const float* __restrict__ Q,
                                                  const float* __restrict__ Kd,
                                                  const float* __restrict__ V,
                                                  const int* __restrict__ top,
                                                  short* __restrict__ OP0,
                                                  short* __restrict__ OP1,
                                                  short* __restrict__ OP2,
                                                  int L, int U) {
  __shared__ float Qs[8][64];
  __shared__ float Kt[64][65];
  __shared__ float Vs[64][68];
  __shared__ float ps[8][64];
  __shared__ int lst[8];
  int nch = (U + 7) >> 3;
  int x = blockIdx.x & 7, s = blockIdx.x >> 3;
  int bh = x + 8 * (s / nch);
  int ch = s % nch;
  int u0g = ch * 8;
  int qn = U - u0g; if (qn > 8) qn = 8;
  int tid = threadIdx.x, lane = tid & 63, wv = tid >> 6;
  if (tid < qn) lst[tid] = top[bh * U + u0g + tid];
  __syncthreads();
  if (tid < qn * 64) {
    int u = tid >> 6, d = tid & 63;
    Qs[u][d] = Q[((size_t)bh * L + lst[u]) * DH + d];
  }
  __syncthreads();
  int ua = wv;                       // one query per wave
  bool hasA = ua < qn;
  float m0 = -1e30f, l0 = 0.f, o0 = 0.f;
  const float* Kbase = Kd + (size_t)bh * L * DH;
  const float* Vbase = V + (size_t)bh * L * DH;
  int j0 = tid >> 4, d40 = (tid & 15) * 4;
  int j1 = j0 + 32;
  // prologue: prefetch tile 0 into registers
  float4 kra = *(const float4*)(Kbase + (size_t)j0 * DH + d40);
  float4 vra = *(const float4*)(Vbase + (size_t)j0 * DH + d40);
  float4 krb = *(const float4*)(Kbase + (size_t)j1 * DH + d40);
  float4 vrb = *(const float4*)(Vbase + (size_t)j1 * DH + d40);
  for (int t0 = 0; t0 < L; t0 += 64) {
    // write prefetched tile to LDS (prev compute finished at loop-end barrier)
    Kt[d40 + 0][j0] = kra.x; Kt[d40 + 1][j0] = kra.y;
    Kt[d40 + 2][j0] = kra.z; Kt[d40 + 3][j0] = kra.w;
    *(float4*)&Vs[j0][d40] = vra;
    Kt[d40 + 0][j1] = krb.x; Kt[d40 + 1][j1] = krb.y;
    Kt[d40 + 2][j1] = krb.z; Kt[d40 + 3][j1] = krb.w;
    *(float4*)&Vs[j1][d40] = vrb;
    __syncthreads();
    // issue next tile's loads (overlap with compute below)
    if (t0 + 64 < L) {
      kra = *(const float4*)(Kbase + (size_t)(t0 + 64 + j0) * DH + d40);
      vra = *(const float4*)(Vbase + (size_t)(t0 + 64 + j0) * DH + d40);
      krb = *(const float4*)(Kbase + (size_t)(t0 + 64 + j1) * DH + d40);
      vrb = *(const float4*)(Vbase + (size_t)(t0 + 64 + j1) * DH + d40);
    }
    __builtin_amdgcn_sched_barrier(0);
    float s0 = 0.f;
#pragma unroll 16
    for (int d = 0; d < 64; ++d) {
      float kd = Kt[d][lane];
      s0 += kd * Qs[ua & 7][d];
    }
    s0 *= 0.125f;
    if (hasA) {
      float tm = s0;
#pragma unroll
      for (int o = 32; o >= 1; o >>= 1) tm = fmaxf(tm, __shfl_xor(tm, o, 64));
      float nm = fmaxf(m0, tm);
      float alpha = expf(m0 - nm);
      float p = expf(s0 - nm);
      float tsum = p;
#pragma unroll
      for (int o = 32; o >= 1; o >>= 1) tsum += __shfl_xor(tsum, o, 64);
      l0 = l0 * alpha + tsum;
      m0 = nm;
      ps[ua][lane] = p;
      o0 *= alpha;
#pragma unroll 16
      for (int j = 0; j < 64; ++j) o0 += ps[ua][j] * Vs[j][lane];
    }
    __syncthreads();
  }
  int b = bh / H_, h = bh - b * H_;
  if (hasA) {
    size_t i = ((size_t)b * L + lst[ua]) * DM + h * DH + lane;
    split3(o0 / l0, OP0, OP1, OP2, i);
  }
}

// ---------------- x = LayerNorm(x) in place (+optional fused plane split) ----------------
__global__ void ln_kernel(float* __restrict__ X, const float* __restrict__ g,
                          const float* __restrict__ be, short* __restrict__ P0,
                          short* __restrict__ P1, short* __restrict__ P2) {
  __shared__ float red[256];
  int row = blockIdx.x, tid = threadIdx.x;
  size_t base = (size_t)row * DM;
  float t0 = X[base + tid];
  float t1 = X[base + tid + 256];
  red[tid] = t0 + t1;
  __syncthreads();
  for (int s = 128; s >= 1; s >>= 1) { if (tid < s) red[tid] += red[tid + s]; __syncthreads(); }
  float mu = red[0] / 512.0f;
  __syncthreads();
  float d0 = t0 - mu, d1 = t1 - mu;
  red[tid] = d0 * d0 + d1 * d1;
  __syncthreads();
  for (int s = 128; s >= 1; s >>= 1) { if (tid < s) red[tid] += red[tid + s]; __syncthreads(); }
  float rstd = 1.0f / sqrtf(red[0] / 512.0f + 1e-5f);
  float v0 = d0 * rstd * g[tid] + be[tid];
  float v1 = d1 * rstd * g[tid + 256] + be[tid + 256];
  X[base + tid] = v0;
  X[base + tid + 256] = v1;
  if (P0) {
    split3(v0, P0, P1, P2, base + tid);
    split3(v1, P0, P1, P2, base + tid + 256);
  }
}

// ---------------- maxpool k=3 s=2 pad=1 along L (+fused plane split) ----------------
__global__ void pool_kernel(const float* __restrict__ Y, float* __restrict__ X, int L2,
                            short* __restrict__ P0, short* __restrict__ P1,
                            short* __restrict__ P2) {
  int i = blockIdx.x * 256 + threadIdx.x;
  int c = i % DM;
  int t = (i / DM) % L2;
  int b = i / (DM * L2);
  int L = L2 * 2;
  const float* yb = Y + (size_t)b * L * DM + c;
  float m = fmaxf(yb[(size_t)(2 * t) * DM], yb[(size_t)(2 * t + 1) * DM]);
  if (t > 0) m = fmaxf(m, yb[(size_t)(2 * t - 1) * DM]);
  X[i] = m;
  split3(m, P0, P1, P2, (size_t)i);
}

// ---------------- column max, 2-stage ----------------
__global__ void colmax1_kernel(const float* __restrict__ X, float* __restrict__ P, int L) {
  int nlc = L >> 6;
  int bl = blockIdx.x;
  int b = bl / nlc, lc = bl % nlc;
  const float* xb = X + ((size_t)b * L + lc * 64) * DM;
  for (int c = threadIdx.x; c < DM; c += 256) {
    float m = -1e30f;
    for (int r = 0; r < 64; ++r) m = fmaxf(m, xb[(size_t)r * DM + c]);
    P[((size_t)b * nlc + lc) * DM + c] = m;
  }
}
__global__ void colmax2_kernel(const float* __restrict__ P, float* __restrict__ mc, int nlc) {
  int i = blockIdx.x * 256 + threadIdx.x;
  int b = i / DM, c = i % DM;
  float m = -1e30f;
  for (int lc = 0; lc < nlc; ++lc) m = fmaxf(m, P[((size_t)b * nlc + lc) * DM + c]);
  mc[i] = m;
}

// ---------------- final projection ----------------
__global__ void proj_kernel(const float* __restrict__ mc, const float* __restrict__ pw,
                            const float* __restrict__ pb, float* __restrict__ out) {
  __shared__ float red[256];
  int bo = blockIdx.x, b = bo / COUT, o = bo % COUT, tid = threadIdx.x;
  float s = mc[b * DM + tid] * pw[o * DM + tid] +
            mc[b * DM + tid + 256] * pw[o * DM + tid + 256];
  red[tid] = s;
  __syncthreads();
  for (int st = 128; st >= 1; st >>= 1) { if (tid < st) red[tid] += red[tid + st]; __syncthreads(); }
  if (tid == 0) out[bo] = red[0] + pb[o];
}

extern "C" void kernel_launch(void* const* d_in, const int* in_sizes, int n_in,
                              void* d_out, int out_size, void* d_ws, size_t ws_size,
                              hipStream_t stream) {
  (void)in_sizes; (void)n_in; (void)out_size;
  const float* xe   = (const float*)d_in[0];
  const float* tw   = (const float*)d_in[1];
  const float* Wq   = (const float*)d_in[2];
  const float* Wk   = (const float*)d_in[3];
  const float* Wv   = (const float*)d_in[4];
  const float* Wo   = (const float*)d_in[5];
  const float* bq   = (const float*)d_in[6];
  const float* bk   = (const float*)d_in[7];
  const float* bv   = (const float*)d_in[8];
  const float* bo   = (const float*)d_in[9];
  const float* W1   = (const float*)d_in[10];
  const float* b1   = (const float*)d_in[11];
  const float* W2   = (const float*)d_in[12];
  const float* b2   = (const float*)d_in[13];
  const float* ln1g = (const float*)d_in[14];
  const float* ln1b = (const float*)d_in[15];
  const float* ln2g = (const float*)d_in[16];
  const float* ln2b = (const float*)d_in[17];
  const float* dcw  = (const float*)d_in[18];
  const float* dcb  = (const float*)d_in[19];
  const float* bng  = (const float*)d_in[20];
  const float* bnb  = (const float*)d_in[21];
  const float* lnfg = (const float*)d_in[22];
  const float* lnfb = (const float*)d_in[23];
  const float* pw   = (const float*)d_in[24];
  const float* pb   = (const float*)d_in[25];
  float* out = (float*)d_out;

  float* Wf = (float*)d_ws;
  const size_t NB  = (size_t)B_ * LMAX * DM;             // 8,388,608 floats
  const size_t NHB = (size_t)H_ * LMAX * DH;             // 1,048,576 floats
  const size_t S_IDX = 81920, S_MV = 131072, S_TOP = 4096, S_VM = 4096,
               S_MC = 4096, S_BC = 2048, S_P = 32768;
  const size_t PLANE  = (size_t)512 * 1536;              // weight plane (shorts)
  const size_t APLANE = NB;                              // activation plane (shorts)
  const size_t S_WP = 3 * PLANE / 2 + 1024;              // floats
  const size_t S_AP = 3 * APLANE / 2 + 1024;             // floats
  const size_t SMALL = S_IDX + S_MV + S_TOP + S_VM + S_MC + S_BC + S_P + S_WP + S_AP + 1024;

  int g = 8;
  while (g > 1 && (2 * NB + 3 * (size_t)g * NHB + SMALL) * 4 > ws_size) g >>= 1;

  float* X  = Wf;
  float* T  = X + NB;
  float* Q  = T + NB;
  float* K  = Q + (size_t)g * NHB;
  float* V  = K + (size_t)g * NHB;
  float* SM = V + (size_t)g * NHB;
  int*   IDX = (int*)SM;
  float* Mv  = SM + S_IDX;
  int*   TOP = (int*)(Mv + S_MV);
  float* VM  = Mv + S_MV + S_TOP;
  float* MC  = VM + S_VM;
  float* BCAT = MC + S_MC;
  float* P   = BCAT + S_BC;
  short* WP0 = (short*)(P + S_P);
  short* WP1 = WP0 + PLANE;
  short* WP2 = WP1 + PLANE;
  short* AP0 = (short*)((float*)(P + S_P) + S_WP);
  short* AP1 = AP0 + APLANE;
  short* AP2 = AP1 + APLANE;
  // FF1-output planes live in the (dead-after-attn) Q/K/V region
  short* FP0 = (short*)Q;
  short* FP1 = FP0 + APLANE;
  short* FP2 = FP1 + APLANE;

  // embed writes X f32 + X-planes (fused split for layer-0 QKV inputs)
  embed_kernel<<<B_ * LMAX * DM / 256, 256, 0, stream>>>(xe, tw, X, AP0, AP1, AP2);

  int L = LMAX;
  for (int i = 0; i < 3; ++i) {
    int U = (i == 0) ? 40 : 35;
    size_t wOff = (size_t)i * DM * DM;
    int ng = B_ / g;
    int nch = (U + 7) >> 3;
    const int NW = DM * DM;
    // R9: TJ=2 only when the TJ=4 grid badly under-fills 256 CUs.
    // Applies to layer-2 Wo/FF (4 x 32 = 128 blocks); QKV/conv never.
    bool smallWo = (DM / 128) * (B_ * L / 128) < 192;

    idx_kernel<<<(L * U + 255) / 256, 256, 0, stream>>>(IDX, L, U, i);
    // merged QKV weight split + bias concat
    wqkv_kernel<<<3 * NW / 256, 256, 0, stream>>>(Wq + wOff, Wk + wOff, Wv + wOff,
                                                  bq + i * DM, bk + i * DM, bv + i * DM,
                                                  WP0, WP1, WP2, BCAT);

    for (int gb = 0; gb < ng; ++gb) {
      size_t aoff = (size_t)gb * g * L * DM;
      dim3 gq3(1536 / 128, g * L / 128);
      mgemm<0, 1, 0, 0, 0, 0, 4><<<gq3, 256, 0, stream>>>(
          AP0 + aoff, AP1 + aoff, AP2 + aoff, WP0, WP1, WP2, BCAT, nullptr, nullptr,
          nullptr, nullptr, nullptr, Q, (long)((size_t)g * NHB), L, DM);
      if (U == 40) qkM_t<40><<<g * H_ * L / 4, 256, 0, stream>>>(Q, K, IDX, Mv, L);
      else         qkM_t<35><<<g * H_ * L / 4, 256, 0, stream>>>(Q, K, IDX, Mv, L);
      topk_kernel<<<g * H_, 256, 0, stream>>>(Mv, TOP, L, U);
      vmean_kernel<<<g * H_, 256, 0, stream>>>(V, VM, L);
      fill_kernel<<<(unsigned)((size_t)g * L * DM / 256), 256, 0, stream>>>(
          VM, AP0 + aoff, AP1 + aoff, AP2 + aoff, L);
      attn_fused<<<g * H_ * nch, 512, 0, stream>>>(Q, K, V, TOP, AP0 + aoff,
                                                   AP1 + aoff, AP2 + aoff, L, U);
    }

    // Wo: A = ctx planes (fill/attn fused split)
    wsplit_kernel<<<NW / 256, 256, 0, stream>>>(Wo + wOff, WP0, WP1, WP2, NW);
    if (smallWo) {
      dim3 gf(DM / 64, B_ * L / 128);
      mgemm<0, 0, 1, 0, 0, 0, 2><<<gf, 256, 0, stream>>>(
          AP0, AP1, AP2, WP0, WP1, WP2, bo + i * DM, nullptr, nullptr,
          nullptr, nullptr, nullptr, X, 0, L, DM);
      ln_kernel<<<B_ * L, 256, 0, stream>>>(X, ln1g + i * DM, ln1b + i * DM, AP0, AP1, AP2);
      wsplit_kernel<<<NW / 256, 256, 0, stream>>>(W1 + wOff, WP0, WP1, WP2, NW);
      mgemm<1, 0, 0, 0, 0, 1, 2><<<gf, 256, 0, stream>>>(
          AP0, AP1, AP2, WP0, WP1, WP2, b1 + i * DM, nullptr, nullptr,
          FP0, FP1, FP2, nullptr, 0, L, DM);
      wsplit_kernel<<<NW / 256, 256, 0, stream>>>(W2 + wOff, WP0, WP1, WP2, NW);
      mgemm<0, 0, 1, 0, 0, 0, 2><<<gf, 256, 0, stream>>>(
          FP0, FP1, FP2, WP0, WP1, WP2, b2 + i * DM, nullptr, nullptr,
          nullptr, nullptr, nullptr, X, 0, L, DM);
    } else {
      dim3 gf(DM / 128, B_ * L / 128);
      mgemm<0, 0, 1, 0, 0, 0, 4><<<gf, 256, 0, stream>>>(
          AP0, AP1, AP2, WP0, WP1, WP2, bo + i * DM, nullptr, nullptr,
          nullptr, nullptr, nullptr, X, 0, L, DM);
      ln_kernel<<<B_ * L, 256, 0, stream>>>(X, ln1g + i * DM, ln1b + i * DM, AP0, AP1, AP2);
      wsplit_kernel<<<NW / 256, 256, 0, stream>>>(W1 + wOff, WP0, WP1, WP2, NW);
      mgemm<1, 0, 0, 0, 0, 1, 4><<<gf, 256, 0, stream>>>(
          AP0, AP1, AP2, WP0, WP1, WP2, b1 + i * DM, nullptr, nullptr,
          FP0, FP1, FP2, nullptr, 0, L, DM);
      wsplit_kernel<<<NW / 256, 256, 0, stream>>>(W2 + wOff, WP0, WP1, WP2, NW);
      mgemm<0, 0, 1, 0, 0, 0, 4><<<gf, 256, 0, stream>>>(
          FP0, FP1, FP2, WP0, WP1, WP2, b2 + i * DM, nullptr, nullptr,
          nullptr, nullptr, nullptr, X, 0, L, DM);
    }
    if (i < 2) {
      // ln2 fused: planes for conv input
      ln_kernel<<<B_ * L, 256, 0, stream>>>(X, ln2g + i * DM, ln2b + i * DM, AP0, AP1, AP2);
      wt3_kernel<<<DM * 1536 / 256, 256, 0, stream>>>(dcw + (size_t)i * DM * DM * 3,
                                                      WP0, WP1, WP2);
      // conv GEMM with fused BN+ELU epilogue (bias arg = conv bias)
      dim3 gf(DM / 128, B_ * L / 128);
      mgemm<0, 0, 0, 1, 1, 0, 4><<<gf, 256, 0, stream>>>(
          AP0, AP1, AP2, WP0, WP1, WP2, dcb + i * DM, bng + i * DM, bnb + i * DM,
          nullptr, nullptr, nullptr, T, 0, L, 1536);
      L >>= 1;
      // pool fused: writes X + X-planes for next layer's QKV
      pool_kernel<<<B_ * L * DM / 256, 256, 0, stream>>>(T, X, L, AP0, AP1, AP2);
    } else {
      ln_kernel<<<B_ * L, 256, 0, stream>>>(X, ln2g + i * DM, ln2b + i * DM,
                                            nullptr, nullptr, nullptr);
    }
  }

  ln_kernel<<<B_ * L, 256, 0, stream>>>(X, lnfg, lnfb, nullptr, nullptr, nullptr);
  colmax1_kernel<<<B_ * (L >> 6), 256, 0, stream>>>(X, P, L);
  colmax2_kernel<<<B_ * DM / 256, 256, 0, stream>>>(P, MC, L >> 6);
  proj_kernel<<<B_ * COUT, 256, 0, stream>>>(MC, pw, pb, out);
}